// Round 8
// baseline (2109.485 us; speedup 1.0000x reference)
//
#include <hip/hip_runtime.h>
#include <cstdint>

#define NN 8192
#define DD 512
#define CC 4
#define TT 8
#define EE 32768
#define TE (TT*EE)

typedef __attribute__((ext_vector_type(8))) short short8v;
typedef __attribute__((ext_vector_type(4))) float f32x4;
typedef unsigned int uint;

constexpr int FLAG_SILU = 1, FLAG_RES = 2, FLAG_WEPI = 4, FLAG_BIAS_T = 8;

__device__ __forceinline__ float silu_f(float x) { return x / (1.f + __expf(-x)); }

__device__ __forceinline__ unsigned short f2bf(float f) {
  uint u = __builtin_bit_cast(uint, f);
  u += 0x7fffu + ((u >> 16) & 1u);
  return (unsigned short)(u >> 16);
}
__device__ __forceinline__ float bf2f(unsigned short b) {
  uint u = ((uint)b) << 16;
  return __builtin_bit_cast(float, u);
}
__device__ __forceinline__ float bflo(uint u) { return __builtin_bit_cast(float, u << 16); }
__device__ __forceinline__ float bfhi(uint u) { return __builtin_bit_cast(float, u & 0xffff0000u); }
__device__ __forceinline__ uint packbf(float a, float b) {
  return (uint)f2bf(a) | ((uint)f2bf(b) << 16);
}

__device__ __forceinline__ float wave_sum(float v) {
#pragma unroll
  for (int off = 32; off; off >>= 1) v += __shfl_xor(v, off);
  return v;
}

__device__ __forceinline__ void gload16(const void* g, void* l) {
  __builtin_amdgcn_global_load_lds(
      (const __attribute__((address_space(1))) void*)g,
      (__attribute__((address_space(3))) void*)l, 16, 0, 0);
}

// ---------------- A/B-side gather functors: ptr(m,k,tt) -> 16B-aligned 8-elem chunk ----------------
struct AgDirect { const unsigned short* p; int K;
  __device__ const void* ptr(int m, int k, int) const { return p + (size_t)m * K + k; } };

struct AgHcat { const unsigned short* hb; const unsigned short* ab;
  __device__ const void* ptr(int m, int k, int) const {
    return (k < 512) ? (const void*)(hb + ((size_t)m << 9) + k)
                     : (const void*)(ab + ((size_t)m << 9) + (k - 512)); } };

struct AgSegG { const unsigned short* seg;     // [G][N][512], k = tloc*512+hh
  __device__ const void* ptr(int m, int k, int) const {
    return seg + (((size_t)(k >> 9) * NN + m) << 9) + (k & 511); } };

struct BgDirect { const unsigned short* p; int K;
  __device__ const void* ptr(int o, int k, int) const { return p + (size_t)o * K + k; } };

struct BgRelG { const unsigned short* w;       // [G][D][H] (pre-offset), o=d, k=tloc*512+hh
  __device__ const void* ptr(int o, int k, int) const {
    return w + (((size_t)(k >> 9) * 512 + o) << 9) + (k & 511); } };

struct BgPerT { const unsigned short* w;       // [T][512][512], global tt select
  __device__ const void* ptr(int o, int k, int tt) const {
    return w + (((size_t)tt << 18) + ((size_t)o << 9)) + k; } };

// ------- bf16 MFMA GEMM: out[m][o] = act(A[m,:].W[o,:] + b) (+res | w-epilogue) -------
template<class AG, class BG>
__global__ __launch_bounds__(256)
void mgemm_k(AG ag, BG bg, int K, int tbase,
             const float* __restrict__ bias, const float* __restrict__ res,
             float* __restrict__ outF, unsigned short* __restrict__ outB, int ldo, int flags,
             const float* __restrict__ cw2, float* __restrict__ wsum_out)
{
  __shared__ __align__(16) unsigned short As[128 * 64];
  __shared__ __align__(16) unsigned short Bs[128 * 64];
  const int m0 = blockIdx.x * 128, o0 = blockIdx.y * 128;
  const int tt = tbase + (m0 >> 15);
  const int tid = threadIdx.x, wave = tid >> 6, lane = tid & 63;
  const int wr = (wave >> 1) * 64, wc = (wave & 1) * 64;
  const int rs = lane >> 3, sl = lane & 7;

  f32x4 acc[4][4];
#pragma unroll
  for (int i = 0; i < 4; ++i)
#pragma unroll
    for (int j = 0; j < 4; ++j) acc[i][j] = (f32x4)0.f;

  for (int k0 = 0; k0 < K; k0 += 64) {
#pragma unroll
    for (int i = 0; i < 4; ++i) {
      int r = i * 32 + wave * 8 + rs;
      int slot = sl ^ (r & 7);
      gload16(ag.ptr(m0 + r, k0 + slot * 8, tt), &As[(i * 32 + wave * 8) * 64]);
    }
#pragma unroll
    for (int i = 0; i < 4; ++i) {
      int r = i * 32 + wave * 8 + rs;
      int slot = sl ^ (r & 7);
      gload16(bg.ptr(o0 + r, k0 + slot * 8, tt), &Bs[(i * 32 + wave * 8) * 64]);
    }
    __syncthreads();

    short8v a[4][2], b[4][2];
#pragma unroll
    for (int mi = 0; mi < 4; ++mi)
#pragma unroll
      for (int s = 0; s < 2; ++s) {
        int row = wr + mi * 16 + (lane & 15);
        int slot = (s * 4 + (lane >> 4)) ^ (row & 7);
        a[mi][s] = *(const short8v*)&As[row * 64 + slot * 8];
      }
#pragma unroll
    for (int ni = 0; ni < 4; ++ni)
#pragma unroll
      for (int s = 0; s < 2; ++s) {
        int row = wc + ni * 16 + (lane & 15);
        int slot = (s * 4 + (lane >> 4)) ^ (row & 7);
        b[ni][s] = *(const short8v*)&Bs[row * 64 + slot * 8];
      }
#pragma unroll
    for (int s = 0; s < 2; ++s)
#pragma unroll
      for (int mi = 0; mi < 4; ++mi)
#pragma unroll
        for (int ni = 0; ni < 4; ++ni)
          acc[mi][ni] = __builtin_amdgcn_mfma_f32_16x16x32_bf16(a[mi][s], b[ni][s], acc[mi][ni], 0, 0, 0);
    __syncthreads();
  }

  const int r4 = (lane >> 4) * 4, cl = lane & 15;
  if (flags & FLAG_WEPI) {
    // w[e][c] partials: silu(v+bias) dotted with cw2 rows; atomic-accumulated into wsumb
    const float* cw2t = cw2 + tt * 2048;
    const float* bt = bias + tt * 512;
#pragma unroll
    for (int mi = 0; mi < 4; ++mi) {
      float sc[4][4];
#pragma unroll
      for (int rg = 0; rg < 4; ++rg)
#pragma unroll
        for (int c = 0; c < 4; ++c) sc[rg][c] = 0.f;
#pragma unroll
      for (int ni = 0; ni < 4; ++ni) {
        int col = o0 + wc + ni * 16 + cl;
        float c0 = cw2t[col], c1 = cw2t[512 + col], c2 = cw2t[1024 + col], c3 = cw2t[1536 + col];
        float bb = bt[col];
#pragma unroll
        for (int rg = 0; rg < 4; ++rg) {
          float v = silu_f(acc[mi][ni][rg] + bb);
          sc[rg][0] += v * c0; sc[rg][1] += v * c1; sc[rg][2] += v * c2; sc[rg][3] += v * c3;
        }
      }
#pragma unroll
      for (int rg = 0; rg < 4; ++rg)
#pragma unroll
        for (int c = 0; c < 4; ++c) {
          float s = sc[rg][c];
          s += __shfl_xor(s, 1); s += __shfl_xor(s, 2);
          s += __shfl_xor(s, 4); s += __shfl_xor(s, 8);
          sc[rg][c] = s;
        }
      if (cl == 0) {
        size_t gp = ((size_t)tbase << 15) + m0 + wr + mi * 16 + r4;  // global sorted pos
#pragma unroll
        for (int rg = 0; rg < 4; ++rg)
#pragma unroll
          for (int c = 0; c < 4; ++c)
            atomicAdd(&wsum_out[(gp + rg) * 4 + c], sc[rg][c]);
      }
    }
    return;
  }
#pragma unroll
  for (int mi = 0; mi < 4; ++mi)
#pragma unroll
    for (int ni = 0; ni < 4; ++ni)
#pragma unroll
      for (int rg = 0; rg < 4; ++rg) {
        int row = m0 + wr + mi * 16 + r4 + rg;
        int col = o0 + wc + ni * 16 + cl;
        float v = acc[mi][ni][rg];
        if (bias) v += (flags & FLAG_BIAS_T) ? bias[tt * 512 + col] : bias[col];
        if (flags & FLAG_SILU) v = silu_f(v);
        if (flags & FLAG_RES) v += res[(size_t)row * ldo + col];
        if (outF) outF[(size_t)row * ldo + col] = v;
        if (outB) outB[(size_t)row * ldo + col] = f2bf(v);
      }
}

// ---------------- prep kernels ----------------
__global__ __launch_bounds__(256)
void cvt_k(const float* __restrict__ in, unsigned short* __restrict__ out, int n) {
  int i = blockIdx.x * 256 + threadIdx.x;
  if (i < n) out[i] = f2bf(in[i]);
}

__global__ __launch_bounds__(256)
void slicew_k(const float* __restrict__ w, unsigned short* __restrict__ o, int Kin, int col0) {
  int i = blockIdx.x * 256 + threadIdx.x;   // < 512*512
  int r = i >> 9, k = i & 511;
  o[i] = f2bf(w[(size_t)r * Kin + col0 + k]);
}

__global__ __launch_bounds__(256)
void tailw_k(const float* __restrict__ mW1, unsigned short* __restrict__ o) {
  int i = blockIdx.x * 256 + threadIdx.x;   // < 17*512
  if (i >= 17 * 512) return;
  int j = i >> 9, c = i & 511;
  o[i] = f2bf(mW1[(size_t)c * 1041 + 1024 + j]);
}

__global__ __launch_bounds__(256)
void weaw_k(const float* __restrict__ eW1, float* __restrict__ wea) {
  int i = blockIdx.x * 256 + threadIdx.x;   // < 512
  if (i < 512) wea[i] = eW1[(size_t)i * 1025 + 512];
}

__global__ __launch_bounds__(256)
void biasb_k(const float* __restrict__ mb1, const float* __restrict__ eb1,
             float* __restrict__ pqb, float* __restrict__ ggb) {
  int i = blockIdx.x * 256 + threadIdx.x;   // < 1024
  if (i < 1024) {
    pqb[i] = (i < 512) ? mb1[i] : 0.f;
    ggb[i] = (i < 512) ? eb1[i] : 0.f;
  }
}

// ---------------- counting sort of edges by destination node ----------------
__global__ __launch_bounds__(256)
void hist_k(const int* __restrict__ eidx, int* __restrict__ deg) {
  int id = blockIdx.x * 256 + threadIdx.x;         // < TE
  int t = id >> 15, e = id & (EE - 1);
  atomicAdd(&deg[(t << 13) + eidx[(t << 16) + e]], 1);
}

__global__ __launch_bounds__(256)
void scan_k(const int* __restrict__ deg, int* __restrict__ off, int* __restrict__ cursor) {
  int t = blockIdx.x, tid = threadIdx.x;
  __shared__ int lds[256];
  int base = 0;
  for (int ch = 0; ch < 32; ++ch) {
    int i = ch * 256 + tid;
    int v = deg[(t << 13) + i];
    __syncthreads();
    lds[tid] = v;
    __syncthreads();
    for (int s = 1; s < 256; s <<= 1) {
      int x = (tid >= s) ? lds[tid - s] : 0;
      __syncthreads();
      if (tid >= s) lds[tid] += x;
      __syncthreads();
    }
    int excl = base + lds[tid] - v;
    off[(t << 13) + i] = excl;
    cursor[(t << 13) + i] = excl;
    base += lds[255];
  }
}

__global__ __launch_bounds__(256)
void scat_k(const int* __restrict__ eidx, const float* __restrict__ ea, int* __restrict__ cursor,
            int* __restrict__ order, int* __restrict__ rank,
            int* __restrict__ rowS, int* __restrict__ colS, float* __restrict__ eaS) {
  int id = blockIdx.x * 256 + threadIdx.x;         // < TE
  int t = id >> 15, e = id & (EE - 1);
  int r = eidx[(t << 16) + e], c = eidx[(t << 16) + EE + e];
  int pos = atomicAdd(&cursor[(t << 13) + r], 1);
  size_t g = ((size_t)t << 15) + pos;
  order[g] = e; rank[id] = pos; rowS[g] = r; colS[g] = c; eaS[g] = ea[id];
}

// ---------------- cd / radial at SORTED positions + per-block sq partials ----------------
__global__ __launch_bounds__(256)
void cdrad_k(const float* __restrict__ coord, const int* __restrict__ eidx,
             const int* __restrict__ rank,
             float* __restrict__ cd, float* __restrict__ radial, float* __restrict__ pnrm)
{
  int m = blockIdx.x * 256 + threadIdx.x;          // < TE (original order)
  int t = m >> 15, e = m & (EE - 1);
  int r = eidx[(t << 16) + e], c = eidx[(t << 16) + EE + e];
  size_t s = ((size_t)t << 15) + rank[m];          // sorted pos
  const float4* cv4 = (const float4*)coord;
  float4 A0 = cv4[r * 3], A1 = cv4[r * 3 + 1], A2 = cv4[r * 3 + 2];
  float4 B0 = cv4[c * 3], B1 = cv4[c * 3 + 1], B2 = cv4[c * 3 + 2];
  float d[12] = {A0.x-B0.x, A0.y-B0.y, A0.z-B0.z, A0.w-B0.w,
                 A1.x-B1.x, A1.y-B1.y, A1.z-B1.z, A1.w-B1.w,
                 A2.x-B2.x, A2.y-B2.y, A2.z-B2.z, A2.w-B2.w};
  float4* cdv = (float4*)cd;
  cdv[s*3+0] = make_float4(d[0],d[1],d[2],d[3]);
  cdv[s*3+1] = make_float4(d[4],d[5],d[6],d[7]);
  cdv[s*3+2] = make_float4(d[8],d[9],d[10],d[11]);
  float rad[16], sq[16];
#pragma unroll
  for (int ci = 0; ci < 4; ++ci)
#pragma unroll
    for (int di = 0; di < 4; ++di) {
      float v = d[ci*3]*d[di*3] + d[ci*3+1]*d[di*3+1] + d[ci*3+2]*d[di*3+2];
      rad[ci*4+di] = v; sq[ci*4+di] = v * v;
    }
  float4* rv = (float4*)radial;
#pragma unroll
  for (int i = 0; i < 4; ++i)
    rv[s*4+i] = make_float4(rad[i*4], rad[i*4+1], rad[i*4+2], rad[i*4+3]);
#pragma unroll
  for (int i = 0; i < 16; ++i) sq[i] = wave_sum(sq[i]);
  __shared__ float red[4][16];
  int wv = threadIdx.x >> 6, lane = threadIdx.x & 63;
  if (lane == 0) {
#pragma unroll
    for (int i = 0; i < 16; ++i) red[wv][i] = sq[i];
  }
  __syncthreads();
  if (threadIdx.x < 16)
    pnrm[blockIdx.x * 16 + threadIdx.x] =
        red[0][threadIdx.x] + red[1][threadIdx.x] + red[2][threadIdx.x] + red[3][threadIdx.x];
}

__global__ __launch_bounds__(128)
void nrmred_k(const float* __restrict__ pnrm, float* __restrict__ nrm) {
  int t = threadIdx.x >> 4, j = threadIdx.x & 15;
  float s = 0.f;
  for (int b = 0; b < 128; ++b) s += pnrm[((t * 128 + b) << 4) + j];
  nrm[(t << 4) + j] = s;
}

// tail row (24): rad_norm(16)|ea|0*7  — sorted space
__global__ __launch_bounds__(256)
void tails_k(const float* __restrict__ radial, const float* __restrict__ nrm,
             const float* __restrict__ eaS, unsigned short* __restrict__ tailm)
{
  int m = blockIdx.x * 256 + threadIdx.x;          // < TE sorted
  int t = m >> 15;
  unsigned short tmp[24];
#pragma unroll
  for (int j = 0; j < 16; ++j) {
    float r = radial[(size_t)m * 16 + j] / fmaxf(sqrtf(nrm[(t << 4) + j]), 1e-12f);
    tmp[j] = f2bf(r);
  }
  tmp[16] = f2bf(eaS[m]);
#pragma unroll
  for (int j = 17; j < 24; ++j) tmp[j] = 0;
  uint4* dst = (uint4*)(tailm + (size_t)m * 24);
  dst[0] = ((const uint4*)tmp)[0];
  dst[1] = ((const uint4*)tmp)[1];
  dst[2] = ((const uint4*)tmp)[2];
}

// ---------------- fused msg1 (sorted, batched group): silu(P[row]+Q[col]+tail.Wt) ----------------
__global__ __launch_bounds__(256)
void msg1f_k(const unsigned short* __restrict__ PQ, const unsigned short* __restrict__ Wt,
             const unsigned short* __restrict__ tailm_g,
             const int* __restrict__ rowS_g, const int* __restrict__ colS_g,
             unsigned short* __restrict__ out)
{
  int tid = threadIdx.x;
  int e0 = blockIdx.x * 16;
  uint wreg[17];
#pragma unroll
  for (int j = 0; j < 17; ++j) wreg[j] = *(const uint*)(Wt + j * 512 + tid * 2);
  for (int i = 0; i < 16; ++i) {
    int p = e0 + i;
    int r = rowS_g[p], c = colS_g[p];
    uint pv = *(const uint*)(PQ + ((size_t)r << 10) + tid * 2);
    uint qv = *(const uint*)(PQ + ((size_t)c << 10) + 512 + tid * 2);
    float s0 = bflo(pv) + bflo(qv);
    float s1 = bfhi(pv) + bfhi(qv);
#pragma unroll
    for (int j = 0; j < 17; ++j) {
      float tj = bf2f(tailm_g[(size_t)p * 24 + j]);
      s0 += tj * bflo(wreg[j]); s1 += tj * bfhi(wreg[j]);
    }
    *(uint*)(out + ((size_t)p << 9) + tid * 2) = packbf(silu_f(s0), silu_f(s1));
  }
}

// gather-sum (sorted, sequential, batched group): segt[tloc][n] = sum msg rows
__global__ __launch_bounds__(256)
void gsum_k(const unsigned short* __restrict__ msg, const int* __restrict__ offb,
            const int* __restrict__ deg, int tbase, unsigned short* __restrict__ segt)
{
  int tloc = blockIdx.x >> 13, n = blockIdx.x & (NN - 1), tid = threadIdx.x;
  int t = tbase + tloc;
  int start = offb[(t << 13) + n], d = deg[(t << 13) + n];
  float s0 = 0.f, s1 = 0.f;
  const unsigned short* base = msg + (((size_t)tloc << 15) << 9);
  for (int j = 0; j < d; ++j) {
    uint v = *(const uint*)(base + ((size_t)(start + j) << 9) + tid * 2);
    s0 += bflo(v); s1 += bfhi(v);
  }
  *(uint*)(segt + (((size_t)tloc * NN + n) << 9) + tid * 2) = packbf(s0, s1);
}

// ---------------- fused trans-reduce + x_new (no atomics, CSR walk) ----------------
__global__ __launch_bounds__(256)
void trxn_k(const float* __restrict__ coord, const float* __restrict__ cd,
            const float* __restrict__ wsum, const int* __restrict__ offb,
            const int* __restrict__ deg, float* __restrict__ xout)
{
  int id = blockIdx.x * 256 + threadIdx.x;          // < NN*12
  int n = id / 12, j = id - n * 12, ci = j / 3;
  float s = 0.f; int cnt = 0;
#pragma unroll
  for (int t = 0; t < 8; ++t) {
    int o = offb[(t << 13) + n], d = deg[(t << 13) + n];
    size_t p = ((size_t)t << 15) + o;
    for (int k = 0; k < d; ++k)
      s += cd[(p + k) * 12 + j] * wsum[(p + k) * 4 + ci];
    cnt += d;
  }
  xout[id] = coord[id] + s / fmaxf((float)cnt, 1.f);
}

// ------ m output: one wave per (t,node) — r-half of GG loaded once per node ------
__global__ __launch_bounds__(256)
void mout_k(const unsigned short* __restrict__ GG,
            const float* __restrict__ eW2, const float* __restrict__ wea,
            const float* __restrict__ eb2, const float* __restrict__ eaS,
            const int* __restrict__ colS, const int* __restrict__ order,
            const int* __restrict__ offb, const int* __restrict__ deg,
            float* __restrict__ out_m)
{
  int wid = blockIdx.x * 4 + (threadIdx.x >> 6);   // < TT*NN
  int lane = threadIdx.x & 63;
  int d = deg[wid];
  if (d == 0) return;
  int t = wid >> 13, n = wid & (NN - 1);
  int o = offb[wid];
  short8v gv = *(const short8v*)(GG + ((size_t)n << 10) + lane * 8);
  const float4* w4 = (const float4*)(eW2 + lane * 8);
  const float4* a4 = (const float4*)(wea + lane * 8);
  float4 w0 = w4[0], w1 = w4[1], a0 = a4[0], a1 = a4[1];
  float wv8[8] = {w0.x,w0.y,w0.z,w0.w,w1.x,w1.y,w1.z,w1.w};
  float av8[8] = {a0.x,a0.y,a0.z,a0.w,a1.x,a1.y,a1.z,a1.w};
  float gr[8];
#pragma unroll
  for (int j = 0; j < 8; ++j) gr[j] = bf2f((unsigned short)gv[j]);
  size_t base = (size_t)t << 15;
  float eb = eb2[0];
  for (int k = 0; k < d; ++k) {
    size_t p = base + o + k;
    int c = colS[p];
    float eav = eaS[p];
    short8v gcv = *(const short8v*)(GG + ((size_t)c << 10) + 512 + lane * 8);
    float s = 0.f;
#pragma unroll
    for (int j = 0; j < 8; ++j)
      s += wv8[j] * silu_f(gr[j] + bf2f((unsigned short)gcv[j]) + eav * av8[j]);
    s = wave_sum(s);
    if (lane == 0) out_m[base + order[p]] = s + eb;
  }
}

// ---------------- launch ----------------
extern "C" void kernel_launch(void* const* d_in, const int* in_sizes, int n_in,
                              void* d_out, int out_size, void* d_ws, size_t ws_size,
                              hipStream_t stream)
{
  const float* h     = (const float*)d_in[0];
  const float* coord = (const float*)d_in[1];
  const float* ea    = (const float*)d_in[2];
  const int*   eidx  = (const int*)  d_in[3];
  const float* mW1   = (const float*)d_in[4];
  const float* mb1   = (const float*)d_in[5];
  const float* mW2   = (const float*)d_in[6];
  const float* mb2   = (const float*)d_in[7];
  const float* nW1   = (const float*)d_in[8];
  const float* nb1   = (const float*)d_in[9];
  const float* nW2   = (const float*)d_in[10];
  const float* nb2   = (const float*)d_in[11];
  const float* eW1   = (const float*)d_in[12];
  const float* eb1   = (const float*)d_in[13];
  const float* eW2   = (const float*)d_in[14];
  const float* eb2   = (const float*)d_in[15];
  const float* relW  = (const float*)d_in[16];
  const float* cW1   = (const float*)d_in[17];
  const float* cb1   = (const float*)d_in[18];
  const float* cW2   = (const float*)d_in[19];

  float* out   = (float*)d_out;
  float* out_h = out;
  float* out_x = out + (size_t)NN * DD;
  float* out_m = out_x + (size_t)NN * CC * 3;

  char* ws = (char*)d_ws;
  size_t off = 0;
  auto alloc = [&](size_t bytes) -> void* {
    void* p = ws + off; off += (bytes + 255) & ~(size_t)255; return p;
  };
  // ---- fixed buffers (~98 MB) ----
  float* cd     = (float*)alloc((size_t)TE * 12 * 4);                     // 12.6 MB
  unsigned short* tailm = (unsigned short*)alloc((size_t)TE * 24 * 2);    // 12.6 MB
  float* agg    = (float*)alloc((size_t)NN * 512 * 4);                    // 16.8 MB (f32, += over groups)
  unsigned short* h_bf  = (unsigned short*)alloc((size_t)NN * 512 * 2);
  unsigned short* hn_bf = (unsigned short*)alloc((size_t)NN * 512 * 2);
  unsigned short* PQb   = (unsigned short*)alloc((size_t)NN * 1024 * 2);  // 16.8 MB (GGb aliases)
  unsigned short* GGb   = PQb;                                            // pass-2 alias (PQ dead)
  unsigned short* mW1pq = (unsigned short*)alloc((size_t)1024 * 512 * 2);
  unsigned short* mW1t  = (unsigned short*)alloc((size_t)17 * 512 * 2);
  unsigned short* mW2b  = (unsigned short*)alloc((size_t)512 * 512 * 2);
  unsigned short* nW1b  = (unsigned short*)alloc((size_t)512 * 1024 * 2);
  unsigned short* nW2b  = (unsigned short*)alloc((size_t)512 * 512 * 2);
  unsigned short* eGc   = (unsigned short*)alloc((size_t)1024 * 512 * 2);
  float* weab   = (float*)alloc(512 * 4);
  float* pqbias = (float*)alloc(1024 * 4);
  float* ggbias = (float*)alloc(1024 * 4);
  unsigned short* relWb = (unsigned short*)alloc((size_t)TT * 512 * 512 * 2); // 4.2 MB
  unsigned short* cW1b  = (unsigned short*)alloc((size_t)TT * 512 * 512 * 2); // 4.2 MB
  int* deg     = (int*)alloc((size_t)TT * NN * 4);
  int* offb    = (int*)alloc((size_t)TT * NN * 4);
  int* cursor  = (int*)alloc((size_t)TT * NN * 4);
  int* order   = (int*)alloc((size_t)TE * 4);
  int* rank    = (int*)alloc((size_t)TE * 4);
  int* rowS    = (int*)alloc((size_t)TE * 4);
  int* colS    = (int*)alloc((size_t)TE * 4);
  float* eaS   = (float*)alloc((size_t)TE * 4);
  float* wsumb = (float*)alloc((size_t)TE * 4 * 4);                       // 4.2 MB
  float* pnrm  = (float*)alloc((size_t)(TE / 256) * 16 * 4);
  float* nrm   = (float*)alloc((size_t)TT * 16 * 4);

  // ---- choose group size G: per-G = bufA 33.6 + bufB 33.6 + segt 8.4 MB ----
  const size_t perG = (size_t)EE * 512 * 2 * 2 + (size_t)NN * 512 * 2;
  int G = 4;
  while (G > 1 && off + (size_t)G * perG + (1 << 20) > ws_size) G >>= 1;
  unsigned short* bufA = (unsigned short*)alloc((size_t)G * EE * 512 * 2);
  unsigned short* bufB = (unsigned short*)alloc((size_t)G * EE * 512 * 2);
  unsigned short* segt = (unsigned short*)alloc((size_t)G * NN * 512 * 2);
  unsigned short* aggb = segt;    // alias: bf16 agg written after segt is dead
  float* radial = (float*)bufA;   // alias: radial f32 (16.8 MB) consumed by tails_k before bufA use

  hipMemsetAsync(deg,   0, (size_t)TT * NN * 4, stream);
  hipMemsetAsync(agg,   0, (size_t)NN * 512 * 4, stream);
  hipMemsetAsync(wsumb, 0, (size_t)TE * 4 * 4, stream);

  auto cvt = [&](const float* in, unsigned short* o, int n) {
    cvt_k<<<(n + 255) / 256, 256, 0, stream>>>(in, o, n);
  };
  cvt(h,    h_bf,  NN * 512);
  cvt(mW2,  mW2b,  512 * 512);
  cvt(nW1,  nW1b,  512 * 1024);
  cvt(nW2,  nW2b,  512 * 512);
  cvt(relW, relWb, TT * 512 * 512);
  cvt(cW1,  cW1b,  TT * 512 * 512);
  slicew_k<<<1024, 256, 0, stream>>>(mW1, mW1pq, 1041, 0);
  slicew_k<<<1024, 256, 0, stream>>>(mW1, mW1pq + 512 * 512, 1041, 512);
  tailw_k<<<34, 256, 0, stream>>>(mW1, mW1t);
  slicew_k<<<1024, 256, 0, stream>>>(eW1, eGc, 1025, 0);
  slicew_k<<<1024, 256, 0, stream>>>(eW1, eGc + 512 * 512, 1025, 513);
  weaw_k<<<2, 256, 0, stream>>>(eW1, weab);
  biasb_k<<<4, 256, 0, stream>>>(mb1, eb1, pqbias, ggbias);

  // sort + geometry (sorted space)
  hist_k<<<TE / 256, 256, 0, stream>>>(eidx, deg);
  scan_k<<<TT, 256, 0, stream>>>(deg, offb, cursor);
  scat_k<<<TE / 256, 256, 0, stream>>>(eidx, ea, cursor, order, rank, rowS, colS, eaS);
  cdrad_k<<<TE / 256, 256, 0, stream>>>(coord, eidx, rank, cd, radial, pnrm);
  nrmred_k<<<1, 128, 0, stream>>>(pnrm, nrm);
  tails_k<<<TE / 256, 256, 0, stream>>>(radial, nrm, eaS, tailm);

  const dim3 gN4(NN / 128, 4), gN8(NN / 128, 8);

  // PQ = h @ [mW1a;mW1q]^T + [mb1;0]   (N x 1024)
  mgemm_k<<<gN8, 256, 0, stream>>>(AgDirect{h_bf, 512}, BgDirect{mW1pq, 512}, 512, 0,
      pqbias, nullptr, nullptr, PQb, 1024, 0, nullptr, nullptr);

  // -------- pass 1: batched groups of G relations --------
  for (int g = 0; g < TT / G; ++g) {
    const int tbase = g * G;
    const size_t gb = (size_t)tbase << 15;
    msg1f_k<<<(G * EE) / 16, 256, 0, stream>>>(PQb, mW1t, tailm + gb * 24,
        rowS + gb, colS + gb, bufA);
    mgemm_k<<<dim3(G * EE / 128, 4), 256, 0, stream>>>(AgDirect{bufA, 512},
        BgDirect{mW2b, 512}, 512, tbase,
        mb2, nullptr, nullptr, bufB, 512, FLAG_SILU, nullptr, nullptr);
    gsum_k<<<G * NN, 256, 0, stream>>>(bufB, offb, deg, tbase, segt);
    // agg += segt @ relW[tbase..tbase+G)^T  (K = G*512, f32 accumulate)
    mgemm_k<<<gN4, 256, 0, stream>>>(AgSegG{segt},
        BgRelG{relWb + ((size_t)tbase << 18)}, G * 512, 0,
        nullptr, agg, agg, nullptr, 512, FLAG_RES, nullptr, nullptr);
    // hid = silu(msg @ cW1[t]^T + cb1[t]) -> fused w-partials (atomic into wsumb)
    mgemm_k<<<dim3(G * EE / 128, 4), 256, 0, stream>>>(AgDirect{bufB, 512},
        BgPerT{cW1b}, 512, tbase,
        cb1, nullptr, nullptr, nullptr, 512, FLAG_SILU | FLAG_WEPI | FLAG_BIAS_T,
        cW2, wsumb);
  }

  // fused trans-reduce + x_new (no atomics)
  trxn_k<<<(NN * 12) / 256, 256, 0, stream>>>(coord, cd, wsumb, offb, deg, out_x);

  // -------- node MLP + residual -> h_new --------
  cvt(agg, aggb, NN * 512);
  mgemm_k<<<gN4, 256, 0, stream>>>(AgHcat{h_bf, aggb}, BgDirect{nW1b, 1024}, 1024, 0,
      nb1, nullptr, nullptr, bufA, 512, FLAG_SILU, nullptr, nullptr);
  mgemm_k<<<gN4, 256, 0, stream>>>(AgDirect{bufA, 512}, BgDirect{nW2b, 512}, 512, 0,
      nb2, h, out_h, hn_bf, 512, FLAG_RES, nullptr, nullptr);

  // -------- pass 2: GG = hn @ [eW1a;eW1c]^T + [eb1;0] ; fused m (per-node) --------
  mgemm_k<<<gN8, 256, 0, stream>>>(AgDirect{hn_bf, 512}, BgDirect{eGc, 512}, 512, 0,
      ggbias, nullptr, nullptr, GGb, 1024, 0, nullptr, nullptr);
  mout_k<<<(TT * NN) / 4, 256, 0, stream>>>(GGb, eW2, weab, eb2, eaS,
      colS, order, offb, deg, out_m);

  (void)in_sizes; (void)n_in; (void)out_size; (void)ws_size;
}

// Round 9
// 1703.745 us; speedup vs baseline: 1.2381x; 1.2381x over previous
//
#include <hip/hip_runtime.h>
#include <cstdint>

#define NN 8192
#define DD 512
#define CC 4
#define TT 8
#define EE 32768
#define TE (TT*EE)

typedef __attribute__((ext_vector_type(8))) short short8v;
typedef __attribute__((ext_vector_type(4))) float f32x4;
typedef unsigned int uint;

constexpr int FLAG_SILU = 1, FLAG_RES = 2, FLAG_WEPI = 4, FLAG_BIAS_T = 8;

__device__ __forceinline__ float silu_f(float x) { return x / (1.f + __expf(-x)); }

__device__ __forceinline__ unsigned short f2bf(float f) {
  uint u = __builtin_bit_cast(uint, f);
  u += 0x7fffu + ((u >> 16) & 1u);
  return (unsigned short)(u >> 16);
}
__device__ __forceinline__ float bf2f(unsigned short b) {
  uint u = ((uint)b) << 16;
  return __builtin_bit_cast(float, u);
}
__device__ __forceinline__ float bflo(uint u) { return __builtin_bit_cast(float, u << 16); }
__device__ __forceinline__ float bfhi(uint u) { return __builtin_bit_cast(float, u & 0xffff0000u); }
__device__ __forceinline__ uint packbf(float a, float b) {
  return (uint)f2bf(a) | ((uint)f2bf(b) << 16);
}

__device__ __forceinline__ float wave_sum(float v) {
#pragma unroll
  for (int off = 32; off; off >>= 1) v += __shfl_xor(v, off);
  return v;
}

__device__ __forceinline__ void gload16(const void* g, void* l) {
  __builtin_amdgcn_global_load_lds(
      (const __attribute__((address_space(1))) void*)g,
      (__attribute__((address_space(3))) void*)l, 16, 0, 0);
}

// ---------------- A/B-side gather functors: ptr(m,k,tt) -> 16B-aligned 8-elem chunk ----------------
struct AgDirect { const unsigned short* p; int K;
  __device__ const void* ptr(int m, int k, int) const { return p + (size_t)m * K + k; } };

struct AgHcat { const unsigned short* hb; const unsigned short* ab;
  __device__ const void* ptr(int m, int k, int) const {
    return (k < 512) ? (const void*)(hb + ((size_t)m << 9) + k)
                     : (const void*)(ab + ((size_t)m << 9) + (k - 512)); } };

struct AgSegG { const unsigned short* seg;     // [G][N][512], k = tloc*512+hh
  __device__ const void* ptr(int m, int k, int) const {
    return seg + (((size_t)(k >> 9) * NN + m) << 9) + (k & 511); } };

struct BgDirect { const unsigned short* p; int K;
  __device__ const void* ptr(int o, int k, int) const { return p + (size_t)o * K + k; } };

struct BgRelG { const unsigned short* w;       // [G][D][H] (pre-offset), o=d, k=tloc*512+hh
  __device__ const void* ptr(int o, int k, int) const {
    return w + (((size_t)(k >> 9) * 512 + o) << 9) + (k & 511); } };

struct BgPerT { const unsigned short* w;       // [T][512][512], global tt select
  __device__ const void* ptr(int o, int k, int tt) const {
    return w + (((size_t)tt << 18) + ((size_t)o << 9)) + k; } };

// ------- bf16 MFMA GEMM. GRID: x = col-block (O/128), y = row-block (M/128) so the
// col-blocks sharing one A-tile are consecutive -> A fetched once, L2-hit 3x. -------
template<class AG, class BG>
__global__ __launch_bounds__(256)
void mgemm_k(AG ag, BG bg, int K, int tbase,
             const float* __restrict__ bias, const float* __restrict__ res,
             float* __restrict__ outF, unsigned short* __restrict__ outB, int ldo, int flags,
             const float* __restrict__ cw2, float* __restrict__ wpart, int wstride)
{
  __shared__ __align__(16) unsigned short As[128 * 64];
  __shared__ __align__(16) unsigned short Bs[128 * 64];
  const int m0 = blockIdx.y * 128, o0 = blockIdx.x * 128;
  const int tt = tbase + (m0 >> 15);
  const int tid = threadIdx.x, wave = tid >> 6, lane = tid & 63;
  const int wr = (wave >> 1) * 64, wc = (wave & 1) * 64;
  const int rs = lane >> 3, sl = lane & 7;

  f32x4 acc[4][4];
#pragma unroll
  for (int i = 0; i < 4; ++i)
#pragma unroll
    for (int j = 0; j < 4; ++j) acc[i][j] = (f32x4)0.f;

  for (int k0 = 0; k0 < K; k0 += 64) {
#pragma unroll
    for (int i = 0; i < 4; ++i) {
      int r = i * 32 + wave * 8 + rs;
      int slot = sl ^ (r & 7);
      gload16(ag.ptr(m0 + r, k0 + slot * 8, tt), &As[(i * 32 + wave * 8) * 64]);
    }
#pragma unroll
    for (int i = 0; i < 4; ++i) {
      int r = i * 32 + wave * 8 + rs;
      int slot = sl ^ (r & 7);
      gload16(bg.ptr(o0 + r, k0 + slot * 8, tt), &Bs[(i * 32 + wave * 8) * 64]);
    }
    __syncthreads();

    short8v a[4][2], b[4][2];
#pragma unroll
    for (int mi = 0; mi < 4; ++mi)
#pragma unroll
      for (int s = 0; s < 2; ++s) {
        int row = wr + mi * 16 + (lane & 15);
        int slot = (s * 4 + (lane >> 4)) ^ (row & 7);
        a[mi][s] = *(const short8v*)&As[row * 64 + slot * 8];
      }
#pragma unroll
    for (int ni = 0; ni < 4; ++ni)
#pragma unroll
      for (int s = 0; s < 2; ++s) {
        int row = wc + ni * 16 + (lane & 15);
        int slot = (s * 4 + (lane >> 4)) ^ (row & 7);
        b[ni][s] = *(const short8v*)&Bs[row * 64 + slot * 8];
      }
#pragma unroll
    for (int s = 0; s < 2; ++s)
#pragma unroll
      for (int mi = 0; mi < 4; ++mi)
#pragma unroll
        for (int ni = 0; ni < 4; ++ni)
          acc[mi][ni] = __builtin_amdgcn_mfma_f32_16x16x32_bf16(a[mi][s], b[ni][s], acc[mi][ni], 0, 0, 0);
    __syncthreads();
  }

  const int r4 = (lane >> 4) * 4, cl = lane & 15;
  if (flags & FLAG_WEPI) {
    // w[e][c] partial = sum_{cols of this block} silu(v+bias) * cw2[c][col], 8 slices
    const int slice = blockIdx.x * 2 + (wave & 1);
    const float* cw2t = cw2 + tt * 2048;
    const float* bt = bias + tt * 512;
#pragma unroll
    for (int mi = 0; mi < 4; ++mi) {
      float sc[4][4];
#pragma unroll
      for (int rg = 0; rg < 4; ++rg)
#pragma unroll
        for (int c = 0; c < 4; ++c) sc[rg][c] = 0.f;
#pragma unroll
      for (int ni = 0; ni < 4; ++ni) {
        int col = o0 + wc + ni * 16 + cl;
        float c0 = cw2t[col], c1 = cw2t[512 + col], c2 = cw2t[1024 + col], c3 = cw2t[1536 + col];
        float bb = bt[col];
#pragma unroll
        for (int rg = 0; rg < 4; ++rg) {
          float v = silu_f(acc[mi][ni][rg] + bb);
          sc[rg][0] += v * c0; sc[rg][1] += v * c1; sc[rg][2] += v * c2; sc[rg][3] += v * c3;
        }
      }
#pragma unroll
      for (int rg = 0; rg < 4; ++rg)
#pragma unroll
        for (int c = 0; c < 4; ++c) {
          float s = sc[rg][c];
          s += __shfl_xor(s, 1); s += __shfl_xor(s, 2);
          s += __shfl_xor(s, 4); s += __shfl_xor(s, 8);
          sc[rg][c] = s;
        }
      if (cl == 0) {
        int p = m0 + wr + mi * 16 + r4;              // group-local sorted pos
#pragma unroll
        for (int rg = 0; rg < 4; ++rg) {
          float4 o = make_float4(sc[rg][0], sc[rg][1], sc[rg][2], sc[rg][3]);
          *(float4*)&wpart[(((size_t)slice * wstride) + p + rg) * 4] = o;
        }
      }
    }
    return;
  }
#pragma unroll
  for (int mi = 0; mi < 4; ++mi)
#pragma unroll
    for (int ni = 0; ni < 4; ++ni)
#pragma unroll
      for (int rg = 0; rg < 4; ++rg) {
        int row = m0 + wr + mi * 16 + r4 + rg;
        int col = o0 + wc + ni * 16 + cl;
        float v = acc[mi][ni][rg];
        if (bias) v += (flags & FLAG_BIAS_T) ? bias[tt * 512 + col] : bias[col];
        if (flags & FLAG_SILU) v = silu_f(v);
        if (flags & FLAG_RES) v += res[(size_t)row * ldo + col];
        if (outF) outF[(size_t)row * ldo + col] = v;
        if (outB) outB[(size_t)row * ldo + col] = f2bf(v);
      }
}

// ---------------- prep kernels ----------------
__global__ __launch_bounds__(256)
void cvt_k(const float* __restrict__ in, unsigned short* __restrict__ out, int n) {
  int i = blockIdx.x * 256 + threadIdx.x;
  if (i < n) out[i] = f2bf(in[i]);
}

__global__ __launch_bounds__(256)
void slicew_k(const float* __restrict__ w, unsigned short* __restrict__ o, int Kin, int col0) {
  int i = blockIdx.x * 256 + threadIdx.x;   // < 512*512
  int r = i >> 9, k = i & 511;
  o[i] = f2bf(w[(size_t)r * Kin + col0 + k]);
}

__global__ __launch_bounds__(256)
void tailw_k(const float* __restrict__ mW1, unsigned short* __restrict__ o) {
  int i = blockIdx.x * 256 + threadIdx.x;   // < 17*512
  if (i >= 17 * 512) return;
  int j = i >> 9, c = i & 511;
  o[i] = f2bf(mW1[(size_t)c * 1041 + 1024 + j]);
}

__global__ __launch_bounds__(256)
void weaw_k(const float* __restrict__ eW1, float* __restrict__ wea) {
  int i = blockIdx.x * 256 + threadIdx.x;   // < 512
  if (i < 512) wea[i] = eW1[(size_t)i * 1025 + 512];
}

__global__ __launch_bounds__(256)
void biasb_k(const float* __restrict__ mb1, const float* __restrict__ eb1,
             float* __restrict__ pqb, float* __restrict__ ggb) {
  int i = blockIdx.x * 256 + threadIdx.x;   // < 1024
  if (i < 1024) {
    pqb[i] = (i < 512) ? mb1[i] : 0.f;
    ggb[i] = (i < 512) ? eb1[i] : 0.f;
  }
}

// ---------------- counting sort of edges by destination node ----------------
__global__ __launch_bounds__(256)
void hist_k(const int* __restrict__ eidx, int* __restrict__ deg) {
  int id = blockIdx.x * 256 + threadIdx.x;         // < TE
  int t = id >> 15, e = id & (EE - 1);
  atomicAdd(&deg[(t << 13) + eidx[(t << 16) + e]], 1);
}

__global__ __launch_bounds__(256)
void scan_k(const int* __restrict__ deg, int* __restrict__ off, int* __restrict__ cursor) {
  int t = blockIdx.x, tid = threadIdx.x;
  __shared__ int lds[256];
  int base = 0;
  for (int ch = 0; ch < 32; ++ch) {
    int i = ch * 256 + tid;
    int v = deg[(t << 13) + i];
    __syncthreads();
    lds[tid] = v;
    __syncthreads();
    for (int s = 1; s < 256; s <<= 1) {
      int x = (tid >= s) ? lds[tid - s] : 0;
      __syncthreads();
      if (tid >= s) lds[tid] += x;
      __syncthreads();
    }
    int excl = base + lds[tid] - v;
    off[(t << 13) + i] = excl;
    cursor[(t << 13) + i] = excl;
    base += lds[255];
  }
}

__global__ __launch_bounds__(256)
void scat_k(const int* __restrict__ eidx, const float* __restrict__ ea, int* __restrict__ cursor,
            int* __restrict__ order, int* __restrict__ rank,
            int* __restrict__ rowS, int* __restrict__ colS, float* __restrict__ eaS) {
  int id = blockIdx.x * 256 + threadIdx.x;         // < TE
  int t = id >> 15, e = id & (EE - 1);
  int r = eidx[(t << 16) + e], c = eidx[(t << 16) + EE + e];
  int pos = atomicAdd(&cursor[(t << 13) + r], 1);
  size_t g = ((size_t)t << 15) + pos;
  order[g] = e; rank[id] = pos; rowS[g] = r; colS[g] = c; eaS[g] = ea[id];
}

// ---------------- cd / radial at SORTED positions + per-block sq partials ----------------
__global__ __launch_bounds__(256)
void cdrad_k(const float* __restrict__ coord, const int* __restrict__ eidx,
             const int* __restrict__ rank,
             float* __restrict__ cd, float* __restrict__ radial, float* __restrict__ pnrm)
{
  int m = blockIdx.x * 256 + threadIdx.x;          // < TE (original order)
  int t = m >> 15, e = m & (EE - 1);
  int r = eidx[(t << 16) + e], c = eidx[(t << 16) + EE + e];
  size_t s = ((size_t)t << 15) + rank[m];          // sorted pos
  const float4* cv4 = (const float4*)coord;
  float4 A0 = cv4[r * 3], A1 = cv4[r * 3 + 1], A2 = cv4[r * 3 + 2];
  float4 B0 = cv4[c * 3], B1 = cv4[c * 3 + 1], B2 = cv4[c * 3 + 2];
  float d[12] = {A0.x-B0.x, A0.y-B0.y, A0.z-B0.z, A0.w-B0.w,
                 A1.x-B1.x, A1.y-B1.y, A1.z-B1.z, A1.w-B1.w,
                 A2.x-B2.x, A2.y-B2.y, A2.z-B2.z, A2.w-B2.w};
  float4* cdv = (float4*)cd;
  cdv[s*3+0] = make_float4(d[0],d[1],d[2],d[3]);
  cdv[s*3+1] = make_float4(d[4],d[5],d[6],d[7]);
  cdv[s*3+2] = make_float4(d[8],d[9],d[10],d[11]);
  float rad[16], sq[16];
#pragma unroll
  for (int ci = 0; ci < 4; ++ci)
#pragma unroll
    for (int di = 0; di < 4; ++di) {
      float v = d[ci*3]*d[di*3] + d[ci*3+1]*d[di*3+1] + d[ci*3+2]*d[di*3+2];
      rad[ci*4+di] = v; sq[ci*4+di] = v * v;
    }
  float4* rv = (float4*)radial;
#pragma unroll
  for (int i = 0; i < 4; ++i)
    rv[s*4+i] = make_float4(rad[i*4], rad[i*4+1], rad[i*4+2], rad[i*4+3]);
#pragma unroll
  for (int i = 0; i < 16; ++i) sq[i] = wave_sum(sq[i]);
  __shared__ float red[4][16];
  int wv = threadIdx.x >> 6, lane = threadIdx.x & 63;
  if (lane == 0) {
#pragma unroll
    for (int i = 0; i < 16; ++i) red[wv][i] = sq[i];
  }
  __syncthreads();
  if (threadIdx.x < 16)
    pnrm[blockIdx.x * 16 + threadIdx.x] =
        red[0][threadIdx.x] + red[1][threadIdx.x] + red[2][threadIdx.x] + red[3][threadIdx.x];
}

__global__ __launch_bounds__(128)
void nrmred_k(const float* __restrict__ pnrm, float* __restrict__ nrm) {
  int t = threadIdx.x >> 4, j = threadIdx.x & 15;
  float s = 0.f;
  for (int b = 0; b < 128; ++b) s += pnrm[((t * 128 + b) << 4) + j];
  nrm[(t << 4) + j] = s;
}

// tail row (24): rad_norm(16)|ea|0*7  — sorted space
__global__ __launch_bounds__(256)
void tails_k(const float* __restrict__ radial, const float* __restrict__ nrm,
             const float* __restrict__ eaS, unsigned short* __restrict__ tailm)
{
  int m = blockIdx.x * 256 + threadIdx.x;          // < TE sorted
  int t = m >> 15;
  unsigned short tmp[24];
#pragma unroll
  for (int j = 0; j < 16; ++j) {
    float r = radial[(size_t)m * 16 + j] / fmaxf(sqrtf(nrm[(t << 4) + j]), 1e-12f);
    tmp[j] = f2bf(r);
  }
  tmp[16] = f2bf(eaS[m]);
#pragma unroll
  for (int j = 17; j < 24; ++j) tmp[j] = 0;
  uint4* dst = (uint4*)(tailm + (size_t)m * 24);
  dst[0] = ((const uint4*)tmp)[0];
  dst[1] = ((const uint4*)tmp)[1];
  dst[2] = ((const uint4*)tmp)[2];
}

// ---------------- fused msg1 (sorted, batched group): silu(P[row]+Q[col]+tail.Wt) ----------------
__global__ __launch_bounds__(256)
void msg1f_k(const unsigned short* __restrict__ PQ, const unsigned short* __restrict__ Wt,
             const unsigned short* __restrict__ tailm_g,
             const int* __restrict__ rowS_g, const int* __restrict__ colS_g,
             unsigned short* __restrict__ out)
{
  int tid = threadIdx.x;
  int e0 = blockIdx.x * 16;
  uint wreg[17];
#pragma unroll
  for (int j = 0; j < 17; ++j) wreg[j] = *(const uint*)(Wt + j * 512 + tid * 2);
  for (int i = 0; i < 16; ++i) {
    int p = e0 + i;
    int r = rowS_g[p], c = colS_g[p];
    uint pv = *(const uint*)(PQ + ((size_t)r << 10) + tid * 2);
    uint qv = *(const uint*)(PQ + ((size_t)c << 10) + 512 + tid * 2);
    float s0 = bflo(pv) + bflo(qv);
    float s1 = bfhi(pv) + bfhi(qv);
#pragma unroll
    for (int j = 0; j < 17; ++j) {
      float tj = bf2f(tailm_g[(size_t)p * 24 + j]);
      s0 += tj * bflo(wreg[j]); s1 += tj * bfhi(wreg[j]);
    }
    *(uint*)(out + ((size_t)p << 9) + tid * 2) = packbf(silu_f(s0), silu_f(s1));
  }
}

// gather-sum (sorted, sequential, batched group): segt[tloc][n] = sum msg rows
__global__ __launch_bounds__(256)
void gsum_k(const unsigned short* __restrict__ msg, const int* __restrict__ offb,
            const int* __restrict__ deg, int tbase, unsigned short* __restrict__ segt)
{
  int tloc = blockIdx.x >> 13, n = blockIdx.x & (NN - 1), tid = threadIdx.x;
  int t = tbase + tloc;
  int start = offb[(t << 13) + n], d = deg[(t << 13) + n];
  float s0 = 0.f, s1 = 0.f;
  const unsigned short* base = msg + (((size_t)tloc << 15) << 9);
  for (int j = 0; j < d; ++j) {
    uint v = *(const uint*)(base + ((size_t)(start + j) << 9) + tid * 2);
    s0 += bflo(v); s1 += bfhi(v);
  }
  *(uint*)(segt + (((size_t)tloc * NN + n) << 9) + tid * 2) = packbf(s0, s1);
}

// ---------------- wsum: collapse 8 group-local wpart slices into global wsumb ----------------
__global__ __launch_bounds__(256)
void wsum_k(const float* __restrict__ wpart, float* __restrict__ wsum_out, int wstride) {
  int id = blockIdx.x * 256 + threadIdx.x;          // < wstride
  float4 a = (float4){0.f, 0.f, 0.f, 0.f};
#pragma unroll
  for (int s = 0; s < 8; ++s) {
    float4 v = *(const float4*)&wpart[(((size_t)s * wstride) + id) * 4];
    a.x += v.x; a.y += v.y; a.z += v.z; a.w += v.w;
  }
  *(float4*)&wsum_out[(size_t)id * 4] = a;
}

// ---------------- fused trans-reduce + x_new (no atomics, CSR walk) ----------------
__global__ __launch_bounds__(256)
void trxn_k(const float* __restrict__ coord, const float* __restrict__ cd,
            const float* __restrict__ wsum, const int* __restrict__ offb,
            const int* __restrict__ deg, float* __restrict__ xout)
{
  int id = blockIdx.x * 256 + threadIdx.x;          // < NN*12
  int n = id / 12, j = id - n * 12, ci = j / 3;
  float s = 0.f; int cnt = 0;
#pragma unroll
  for (int t = 0; t < 8; ++t) {
    int o = offb[(t << 13) + n], d = deg[(t << 13) + n];
    size_t p = ((size_t)t << 15) + o;
    for (int k = 0; k < d; ++k)
      s += cd[(p + k) * 12 + j] * wsum[(p + k) * 4 + ci];
    cnt += d;
  }
  xout[id] = coord[id] + s / fmaxf((float)cnt, 1.f);
}

// ------ batched m output (sorted, per-edge wave) ------
__global__ __launch_bounds__(256)
void mout_k(const unsigned short* __restrict__ GG,
            const float* __restrict__ eW2, const float* __restrict__ wea,
            const float* __restrict__ eb2, const float* __restrict__ eaS,
            const int* __restrict__ rowS, const int* __restrict__ colS,
            const int* __restrict__ order, float* __restrict__ out_m)
{
  int wid = blockIdx.x * 4 + (threadIdx.x >> 6);   // < TE sorted
  int lane = threadIdx.x & 63;
  int t = wid >> 15;
  int r = rowS[wid], c = colS[wid];
  float eav = eaS[wid];
  short8v gv  = *(const short8v*)(GG + ((size_t)r << 10) + lane * 8);
  short8v gcv = *(const short8v*)(GG + ((size_t)c << 10) + 512 + lane * 8);
  const float4* w4 = (const float4*)(eW2 + lane * 8);
  const float4* a4 = (const float4*)(wea + lane * 8);
  float4 w0 = w4[0], w1 = w4[1], a0 = a4[0], a1 = a4[1];
  float wv8[8] = {w0.x,w0.y,w0.z,w0.w,w1.x,w1.y,w1.z,w1.w};
  float av8[8] = {a0.x,a0.y,a0.z,a0.w,a1.x,a1.y,a1.z,a1.w};
  float s = 0.f;
#pragma unroll
  for (int j = 0; j < 8; ++j)
    s += wv8[j] * silu_f(bf2f((unsigned short)gv[j]) + bf2f((unsigned short)gcv[j]) + eav * av8[j]);
  s = wave_sum(s);
  if (lane == 0) out_m[((size_t)t << 15) + order[wid]] = s + eb2[0];
}

// ---------------- launch ----------------
extern "C" void kernel_launch(void* const* d_in, const int* in_sizes, int n_in,
                              void* d_out, int out_size, void* d_ws, size_t ws_size,
                              hipStream_t stream)
{
  const float* h     = (const float*)d_in[0];
  const float* coord = (const float*)d_in[1];
  const float* ea    = (const float*)d_in[2];
  const int*   eidx  = (const int*)  d_in[3];
  const float* mW1   = (const float*)d_in[4];
  const float* mb1   = (const float*)d_in[5];
  const float* mW2   = (const float*)d_in[6];
  const float* mb2   = (const float*)d_in[7];
  const float* nW1   = (const float*)d_in[8];
  const float* nb1   = (const float*)d_in[9];
  const float* nW2   = (const float*)d_in[10];
  const float* nb2   = (const float*)d_in[11];
  const float* eW1   = (const float*)d_in[12];
  const float* eb1   = (const float*)d_in[13];
  const float* eW2   = (const float*)d_in[14];
  const float* eb2   = (const float*)d_in[15];
  const float* relW  = (const float*)d_in[16];
  const float* cW1   = (const float*)d_in[17];
  const float* cb1   = (const float*)d_in[18];
  const float* cW2   = (const float*)d_in[19];

  float* out   = (float*)d_out;
  float* out_h = out;
  float* out_x = out + (size_t)NN * DD;
  float* out_m = out_x + (size_t)NN * CC * 3;

  char* ws = (char*)d_ws;
  size_t off = 0;
  auto alloc = [&](size_t bytes) -> void* {
    void* p = ws + off; off += (bytes + 255) & ~(size_t)255; return p;
  };
  // ---- fixed buffers (~98 MB) ----
  float* cd     = (float*)alloc((size_t)TE * 12 * 4);                     // 12.6 MB
  unsigned short* tailm = (unsigned short*)alloc((size_t)TE * 24 * 2);    // 12.6 MB
  float* agg    = (float*)alloc((size_t)NN * 512 * 4);                    // 16.8 MB (f32, += over groups)
  unsigned short* h_bf  = (unsigned short*)alloc((size_t)NN * 512 * 2);
  unsigned short* hn_bf = (unsigned short*)alloc((size_t)NN * 512 * 2);
  unsigned short* PQb   = (unsigned short*)alloc((size_t)NN * 1024 * 2);  // 16.8 MB (GGb aliases)
  unsigned short* GGb   = PQb;                                            // pass-2 alias (PQ dead)
  unsigned short* mW1pq = (unsigned short*)alloc((size_t)1024 * 512 * 2);
  unsigned short* mW1t  = (unsigned short*)alloc((size_t)17 * 512 * 2);
  unsigned short* mW2b  = (unsigned short*)alloc((size_t)512 * 512 * 2);
  unsigned short* nW1b  = (unsigned short*)alloc((size_t)512 * 1024 * 2);
  unsigned short* nW2b  = (unsigned short*)alloc((size_t)512 * 512 * 2);
  unsigned short* eGc   = (unsigned short*)alloc((size_t)1024 * 512 * 2);
  float* weab   = (float*)alloc(512 * 4);
  float* pqbias = (float*)alloc(1024 * 4);
  float* ggbias = (float*)alloc(1024 * 4);
  unsigned short* relWb = (unsigned short*)alloc((size_t)TT * 512 * 512 * 2); // 4.2 MB
  unsigned short* cW1b  = (unsigned short*)alloc((size_t)TT * 512 * 512 * 2); // 4.2 MB
  int* deg     = (int*)alloc((size_t)TT * NN * 4);
  int* offb    = (int*)alloc((size_t)TT * NN * 4);
  int* cursor  = (int*)alloc((size_t)TT * NN * 4);
  int* order   = (int*)alloc((size_t)TE * 4);
  int* rank    = (int*)alloc((size_t)TE * 4);
  int* rowS    = (int*)alloc((size_t)TE * 4);
  int* colS    = (int*)alloc((size_t)TE * 4);
  float* eaS   = (float*)alloc((size_t)TE * 4);
  float* wsumb = (float*)alloc((size_t)TE * 4 * 4);                       // 4.2 MB
  float* pnrm  = (float*)alloc((size_t)(TE / 256) * 16 * 4);
  float* nrm   = (float*)alloc((size_t)TT * 16 * 4);

  // ---- choose group size G: per-G = bufA 33.6 + bufB 33.6 + segt 8.4 + wpart 4.2 MB ----
  const size_t perG = (size_t)EE * 512 * 2 * 2 + (size_t)NN * 512 * 2 + (size_t)8 * EE * 16;
  int G = 4;
  while (G > 1 && off + (size_t)G * perG + (1 << 20) > ws_size) G >>= 1;
  unsigned short* bufA = (unsigned short*)alloc((size_t)G * EE * 512 * 2);
  unsigned short* bufB = (unsigned short*)alloc((size_t)G * EE * 512 * 2);
  unsigned short* segt = (unsigned short*)alloc((size_t)G * NN * 512 * 2);
  float* wpart = (float*)alloc((size_t)8 * G * EE * 4 * 4);               // group-local
  unsigned short* aggb = segt;    // alias: bf16 agg written after segt is dead
  float* radial = (float*)bufA;   // alias: radial f32 (16.8 MB) consumed by tails_k before bufA use

  hipMemsetAsync(deg, 0, (size_t)TT * NN * 4, stream);
  hipMemsetAsync(agg, 0, (size_t)NN * 512 * 4, stream);

  auto cvt = [&](const float* in, unsigned short* o, int n) {
    cvt_k<<<(n + 255) / 256, 256, 0, stream>>>(in, o, n);
  };
  cvt(h,    h_bf,  NN * 512);
  cvt(mW2,  mW2b,  512 * 512);
  cvt(nW1,  nW1b,  512 * 1024);
  cvt(nW2,  nW2b,  512 * 512);
  cvt(relW, relWb, TT * 512 * 512);
  cvt(cW1,  cW1b,  TT * 512 * 512);
  slicew_k<<<1024, 256, 0, stream>>>(mW1, mW1pq, 1041, 0);
  slicew_k<<<1024, 256, 0, stream>>>(mW1, mW1pq + 512 * 512, 1041, 512);
  tailw_k<<<34, 256, 0, stream>>>(mW1, mW1t);
  slicew_k<<<1024, 256, 0, stream>>>(eW1, eGc, 1025, 0);
  slicew_k<<<1024, 256, 0, stream>>>(eW1, eGc + 512 * 512, 1025, 513);
  weaw_k<<<2, 256, 0, stream>>>(eW1, weab);
  biasb_k<<<4, 256, 0, stream>>>(mb1, eb1, pqbias, ggbias);

  // sort + geometry (sorted space)
  hist_k<<<TE / 256, 256, 0, stream>>>(eidx, deg);
  scan_k<<<TT, 256, 0, stream>>>(deg, offb, cursor);
  scat_k<<<TE / 256, 256, 0, stream>>>(eidx, ea, cursor, order, rank, rowS, colS, eaS);
  cdrad_k<<<TE / 256, 256, 0, stream>>>(coord, eidx, rank, cd, radial, pnrm);
  nrmred_k<<<1, 128, 0, stream>>>(pnrm, nrm);
  tails_k<<<TE / 256, 256, 0, stream>>>(radial, nrm, eaS, tailm);

  // grids: x = col-blocks (consecutive -> share A row-tile), y = row-blocks
  const dim3 gN4(4, NN / 128), gN8(8, NN / 128);

  // PQ = h @ [mW1a;mW1q]^T + [mb1;0]   (N x 1024)
  mgemm_k<<<gN8, 256, 0, stream>>>(AgDirect{h_bf, 512}, BgDirect{mW1pq, 512}, 512, 0,
      pqbias, nullptr, nullptr, PQb, 1024, 0, nullptr, nullptr, 0);

  // -------- pass 1: batched groups of G relations --------
  for (int g = 0; g < TT / G; ++g) {
    const int tbase = g * G;
    const size_t gb = (size_t)tbase << 15;
    msg1f_k<<<(G * EE) / 16, 256, 0, stream>>>(PQb, mW1t, tailm + gb * 24,
        rowS + gb, colS + gb, bufA);
    mgemm_k<<<dim3(4, G * EE / 128), 256, 0, stream>>>(AgDirect{bufA, 512},
        BgDirect{mW2b, 512}, 512, tbase,
        mb2, nullptr, nullptr, bufB, 512, FLAG_SILU, nullptr, nullptr, 0);
    gsum_k<<<G * NN, 256, 0, stream>>>(bufB, offb, deg, tbase, segt);
    // agg += segt @ relW[tbase..tbase+G)^T  (K = G*512, f32 accumulate)
    mgemm_k<<<gN4, 256, 0, stream>>>(AgSegG{segt},
        BgRelG{relWb + ((size_t)tbase << 18)}, G * 512, 0,
        nullptr, agg, agg, nullptr, 512, FLAG_RES, nullptr, nullptr, 0);
    // hid = silu(msg @ cW1[t]^T + cb1[t]) -> fused w-partials into wpart
    mgemm_k<<<dim3(4, G * EE / 128), 256, 0, stream>>>(AgDirect{bufB, 512},
        BgPerT{cW1b}, 512, tbase,
        cb1, nullptr, nullptr, nullptr, 512, FLAG_SILU | FLAG_WEPI | FLAG_BIAS_T,
        cW2, wpart, G * EE);
    wsum_k<<<(G * EE) / 256, 256, 0, stream>>>(wpart, wsumb + gb * 4, G * EE);
  }

  // fused trans-reduce + x_new (no atomics)
  trxn_k<<<(NN * 12) / 256, 256, 0, stream>>>(coord, cd, wsumb, offb, deg, out_x);

  // -------- node MLP + residual -> h_new --------
  cvt(agg, aggb, NN * 512);
  mgemm_k<<<gN4, 256, 0, stream>>>(AgHcat{h_bf, aggb}, BgDirect{nW1b, 1024}, 1024, 0,
      nb1, nullptr, nullptr, bufA, 512, FLAG_SILU, nullptr, nullptr, 0);
  mgemm_k<<<gN4, 256, 0, stream>>>(AgDirect{bufA, 512}, BgDirect{nW2b, 512}, 512, 0,
      nb2, h, out_h, hn_bf, 512, FLAG_RES, nullptr, nullptr, 0);

  // -------- pass 2: GG = hn @ [eW1a;eW1c]^T + [eb1;0] ; fused m (per-edge) --------
  mgemm_k<<<gN8, 256, 0, stream>>>(AgDirect{hn_bf, 512}, BgDirect{eGc, 512}, 512, 0,
      ggbias, nullptr, nullptr, GGb, 1024, 0, nullptr, nullptr, 0);
  mout_k<<<TE / 4, 256, 0, stream>>>(GGb, eW2, weab, eb2, eaS, rowS, colS, order, out_m);

  (void)in_sizes; (void)n_in; (void)out_size; (void)ws_size;
}

// Round 10
// 1622.556 us; speedup vs baseline: 1.3001x; 1.0500x over previous
//
#include <hip/hip_runtime.h>
#include <cstdint>

#define NN 8192
#define DD 512
#define CC 4
#define TT 8
#define EE 32768
#define TE (TT*EE)

typedef __attribute__((ext_vector_type(8))) short short8v;
typedef __attribute__((ext_vector_type(4))) float f32x4;
typedef unsigned int uint;

constexpr int FLAG_SILU = 1, FLAG_RES = 2, FLAG_WEPI = 4, FLAG_BIAS_T = 8;

__device__ __forceinline__ float silu_f(float x) { return x / (1.f + __expf(-x)); }

__device__ __forceinline__ unsigned short f2bf(float f) {
  uint u = __builtin_bit_cast(uint, f);
  u += 0x7fffu + ((u >> 16) & 1u);
  return (unsigned short)(u >> 16);
}
__device__ __forceinline__ float bf2f(unsigned short b) {
  uint u = ((uint)b) << 16;
  return __builtin_bit_cast(float, u);
}
__device__ __forceinline__ float bflo(uint u) { return __builtin_bit_cast(float, u << 16); }
__device__ __forceinline__ float bfhi(uint u) { return __builtin_bit_cast(float, u & 0xffff0000u); }
__device__ __forceinline__ uint packbf(float a, float b) {
  return (uint)f2bf(a) | ((uint)f2bf(b) << 16);
}

__device__ __forceinline__ float wave_sum(float v) {
#pragma unroll
  for (int off = 32; off; off >>= 1) v += __shfl_xor(v, off);
  return v;
}

__device__ __forceinline__ void gload16(const void* g, void* l) {
  __builtin_amdgcn_global_load_lds(
      (const __attribute__((address_space(1))) void*)g,
      (__attribute__((address_space(3))) void*)l, 16, 0, 0);
}

// ---------------- A/B-side gather functors: ptr(m,k,tt) -> 16B-aligned 8-elem chunk ----------------
struct AgDirect { const unsigned short* p; int K;
  __device__ const void* ptr(int m, int k, int) const { return p + (size_t)m * K + k; } };

struct AgHcat { const unsigned short* hb; const unsigned short* ab;
  __device__ const void* ptr(int m, int k, int) const {
    return (k < 512) ? (const void*)(hb + ((size_t)m << 9) + k)
                     : (const void*)(ab + ((size_t)m << 9) + (k - 512)); } };

struct AgSegG { const unsigned short* seg;     // [G][N][512], k = tloc*512+hh
  __device__ const void* ptr(int m, int k, int) const {
    return seg + (((size_t)(k >> 9) * NN + m) << 9) + (k & 511); } };

struct BgDirect { const unsigned short* p; int K;
  __device__ const void* ptr(int o, int k, int) const { return p + (size_t)o * K + k; } };

struct BgRelG { const unsigned short* w;       // [G][D][H] (pre-offset), o=d, k=tloc*512+hh
  __device__ const void* ptr(int o, int k, int) const {
    return w + (((size_t)(k >> 9) * 512 + o) << 9) + (k & 511); } };

struct BgPerT { const unsigned short* w;       // [T][512][512], global tt select
  __device__ const void* ptr(int o, int k, int tt) const {
    return w + (((size_t)tt << 18) + ((size_t)o << 9)) + k; } };

// ------- bf16 MFMA GEMM, 1D grid + XCD-chunked swizzle so the col-blocks sharing an
// A row-tile run on the SAME XCD (private L2) -> A fetched from HBM once. -------
template<class AG, class BG>
__global__ __launch_bounds__(256)
void mgemm_k(AG ag, BG bg, int K, int tbase, int lognx,
             const float* __restrict__ bias, const float* __restrict__ res,
             float* __restrict__ outF, unsigned short* __restrict__ outB, int ldo, int flags,
             const float* __restrict__ cw2, float* __restrict__ wpart, int wstride)
{
  __shared__ __align__(16) unsigned short As[128 * 64];
  __shared__ __align__(16) unsigned short Bs[128 * 64];
  // XCD-chunked swizzle (nwg is always a multiple of 8 here)
  const int nwg = gridDim.x;
  const int id = blockIdx.x;
  const int swz = (id & 7) * (nwg >> 3) + (id >> 3);
  const int xb = swz & ((1 << lognx) - 1), yb = swz >> lognx;
  const int m0 = yb * 128, o0 = xb * 128;
  const int tt = tbase + (m0 >> 15);
  const int tid = threadIdx.x, wave = tid >> 6, lane = tid & 63;
  const int wr = (wave >> 1) * 64, wc = (wave & 1) * 64;
  const int rs = lane >> 3, sl = lane & 7;

  f32x4 acc[4][4];
#pragma unroll
  for (int i = 0; i < 4; ++i)
#pragma unroll
    for (int j = 0; j < 4; ++j) acc[i][j] = (f32x4)0.f;

  for (int k0 = 0; k0 < K; k0 += 64) {
#pragma unroll
    for (int i = 0; i < 4; ++i) {
      int r = i * 32 + wave * 8 + rs;
      int slot = sl ^ (r & 7);
      gload16(ag.ptr(m0 + r, k0 + slot * 8, tt), &As[(i * 32 + wave * 8) * 64]);
    }
#pragma unroll
    for (int i = 0; i < 4; ++i) {
      int r = i * 32 + wave * 8 + rs;
      int slot = sl ^ (r & 7);
      gload16(bg.ptr(o0 + r, k0 + slot * 8, tt), &Bs[(i * 32 + wave * 8) * 64]);
    }
    __syncthreads();

    short8v a[4][2], b[4][2];
#pragma unroll
    for (int mi = 0; mi < 4; ++mi)
#pragma unroll
      for (int s = 0; s < 2; ++s) {
        int row = wr + mi * 16 + (lane & 15);
        int slot = (s * 4 + (lane >> 4)) ^ (row & 7);
        a[mi][s] = *(const short8v*)&As[row * 64 + slot * 8];
      }
#pragma unroll
    for (int ni = 0; ni < 4; ++ni)
#pragma unroll
      for (int s = 0; s < 2; ++s) {
        int row = wc + ni * 16 + (lane & 15);
        int slot = (s * 4 + (lane >> 4)) ^ (row & 7);
        b[ni][s] = *(const short8v*)&Bs[row * 64 + slot * 8];
      }
#pragma unroll
    for (int s = 0; s < 2; ++s)
#pragma unroll
      for (int mi = 0; mi < 4; ++mi)
#pragma unroll
        for (int ni = 0; ni < 4; ++ni)
          acc[mi][ni] = __builtin_amdgcn_mfma_f32_16x16x32_bf16(a[mi][s], b[ni][s], acc[mi][ni], 0, 0, 0);
    __syncthreads();
  }

  const int r4 = (lane >> 4) * 4, cl = lane & 15;
  if (flags & FLAG_WEPI) {
    // w[e][c] partial = sum_{cols of this block} silu(v+bias) * cw2[c][col], 8 slices
    const int slice = xb * 2 + (wave & 1);
    const float* cw2t = cw2 + tt * 2048;
    const float* bt = bias + tt * 512;
#pragma unroll
    for (int mi = 0; mi < 4; ++mi) {
      float sc[4][4];
#pragma unroll
      for (int rg = 0; rg < 4; ++rg)
#pragma unroll
        for (int c = 0; c < 4; ++c) sc[rg][c] = 0.f;
#pragma unroll
      for (int ni = 0; ni < 4; ++ni) {
        int col = o0 + wc + ni * 16 + cl;
        float c0 = cw2t[col], c1 = cw2t[512 + col], c2 = cw2t[1024 + col], c3 = cw2t[1536 + col];
        float bb = bt[col];
#pragma unroll
        for (int rg = 0; rg < 4; ++rg) {
          float v = silu_f(acc[mi][ni][rg] + bb);
          sc[rg][0] += v * c0; sc[rg][1] += v * c1; sc[rg][2] += v * c2; sc[rg][3] += v * c3;
        }
      }
#pragma unroll
      for (int rg = 0; rg < 4; ++rg)
#pragma unroll
        for (int c = 0; c < 4; ++c) {
          float s = sc[rg][c];
          s += __shfl_xor(s, 1); s += __shfl_xor(s, 2);
          s += __shfl_xor(s, 4); s += __shfl_xor(s, 8);
          sc[rg][c] = s;
        }
      if (cl == 0) {
        int p = m0 + wr + mi * 16 + r4;              // group-local sorted pos
#pragma unroll
        for (int rg = 0; rg < 4; ++rg) {
          float4 o = make_float4(sc[rg][0], sc[rg][1], sc[rg][2], sc[rg][3]);
          *(float4*)&wpart[(((size_t)slice * wstride) + p + rg) * 4] = o;
        }
      }
    }
    return;
  }
#pragma unroll
  for (int mi = 0; mi < 4; ++mi)
#pragma unroll
    for (int ni = 0; ni < 4; ++ni)
#pragma unroll
      for (int rg = 0; rg < 4; ++rg) {
        int row = m0 + wr + mi * 16 + r4 + rg;
        int col = o0 + wc + ni * 16 + cl;
        float v = acc[mi][ni][rg];
        if (bias) v += (flags & FLAG_BIAS_T) ? bias[tt * 512 + col] : bias[col];
        if (flags & FLAG_SILU) v = silu_f(v);
        if (flags & FLAG_RES) v += res[(size_t)row * ldo + col];
        if (outF) outF[(size_t)row * ldo + col] = v;
        if (outB) outB[(size_t)row * ldo + col] = f2bf(v);
      }
}

// ---------------- prep kernels ----------------
__global__ __launch_bounds__(256)
void cvt_k(const float* __restrict__ in, unsigned short* __restrict__ out, int n) {
  int i = blockIdx.x * 256 + threadIdx.x;
  if (i < n) out[i] = f2bf(in[i]);
}

__global__ __launch_bounds__(256)
void slicew_k(const float* __restrict__ w, unsigned short* __restrict__ o, int Kin, int col0) {
  int i = blockIdx.x * 256 + threadIdx.x;   // < 512*512
  int r = i >> 9, k = i & 511;
  o[i] = f2bf(w[(size_t)r * Kin + col0 + k]);
}

__global__ __launch_bounds__(256)
void tailw_k(const float* __restrict__ mW1, unsigned short* __restrict__ o) {
  int i = blockIdx.x * 256 + threadIdx.x;   // < 17*512
  if (i >= 17 * 512) return;
  int j = i >> 9, c = i & 511;
  o[i] = f2bf(mW1[(size_t)c * 1041 + 1024 + j]);
}

__global__ __launch_bounds__(256)
void weaw_k(const float* __restrict__ eW1, float* __restrict__ wea) {
  int i = blockIdx.x * 256 + threadIdx.x;   // < 512
  if (i < 512) wea[i] = eW1[(size_t)i * 1025 + 512];
}

__global__ __launch_bounds__(256)
void biasb_k(const float* __restrict__ mb1, const float* __restrict__ eb1,
             float* __restrict__ pqb, float* __restrict__ ggb) {
  int i = blockIdx.x * 256 + threadIdx.x;   // < 1024
  if (i < 1024) {
    pqb[i] = (i < 512) ? mb1[i] : 0.f;
    ggb[i] = (i < 512) ? eb1[i] : 0.f;
  }
}

// ---------------- counting sort of edges by destination node ----------------
__global__ __launch_bounds__(256)
void hist_k(const int* __restrict__ eidx, int* __restrict__ deg) {
  int id = blockIdx.x * 256 + threadIdx.x;         // < TE
  int t = id >> 15, e = id & (EE - 1);
  atomicAdd(&deg[(t << 13) + eidx[(t << 16) + e]], 1);
}

__global__ __launch_bounds__(256)
void scan_k(const int* __restrict__ deg, int* __restrict__ off, int* __restrict__ cursor) {
  int t = blockIdx.x, tid = threadIdx.x;
  __shared__ int lds[256];
  int base = 0;
  for (int ch = 0; ch < 32; ++ch) {
    int i = ch * 256 + tid;
    int v = deg[(t << 13) + i];
    __syncthreads();
    lds[tid] = v;
    __syncthreads();
    for (int s = 1; s < 256; s <<= 1) {
      int x = (tid >= s) ? lds[tid - s] : 0;
      __syncthreads();
      if (tid >= s) lds[tid] += x;
      __syncthreads();
    }
    int excl = base + lds[tid] - v;
    off[(t << 13) + i] = excl;
    cursor[(t << 13) + i] = excl;
    base += lds[255];
  }
}

__global__ __launch_bounds__(256)
void scat_k(const int* __restrict__ eidx, const float* __restrict__ ea, int* __restrict__ cursor,
            int* __restrict__ order, int* __restrict__ rank,
            int* __restrict__ rowS, int* __restrict__ colS, float* __restrict__ eaS) {
  int id = blockIdx.x * 256 + threadIdx.x;         // < TE
  int t = id >> 15, e = id & (EE - 1);
  int r = eidx[(t << 16) + e], c = eidx[(t << 16) + EE + e];
  int pos = atomicAdd(&cursor[(t << 13) + r], 1);
  size_t g = ((size_t)t << 15) + pos;
  order[g] = e; rank[id] = pos; rowS[g] = r; colS[g] = c; eaS[g] = ea[id];
}

// ---------------- cd / radial at SORTED positions + per-block sq partials ----------------
__global__ __launch_bounds__(256)
void cdrad_k(const float* __restrict__ coord, const int* __restrict__ eidx,
             const int* __restrict__ rank,
             float* __restrict__ cd, float* __restrict__ radial, float* __restrict__ pnrm)
{
  int m = blockIdx.x * 256 + threadIdx.x;          // < TE (original order)
  int t = m >> 15, e = m & (EE - 1);
  int r = eidx[(t << 16) + e], c = eidx[(t << 16) + EE + e];
  size_t s = ((size_t)t << 15) + rank[m];          // sorted pos
  const float4* cv4 = (const float4*)coord;
  float4 A0 = cv4[r * 3], A1 = cv4[r * 3 + 1], A2 = cv4[r * 3 + 2];
  float4 B0 = cv4[c * 3], B1 = cv4[c * 3 + 1], B2 = cv4[c * 3 + 2];
  float d[12] = {A0.x-B0.x, A0.y-B0.y, A0.z-B0.z, A0.w-B0.w,
                 A1.x-B1.x, A1.y-B1.y, A1.z-B1.z, A1.w-B1.w,
                 A2.x-B2.x, A2.y-B2.y, A2.z-B2.z, A2.w-B2.w};
  float4* cdv = (float4*)cd;
  cdv[s*3+0] = make_float4(d[0],d[1],d[2],d[3]);
  cdv[s*3+1] = make_float4(d[4],d[5],d[6],d[7]);
  cdv[s*3+2] = make_float4(d[8],d[9],d[10],d[11]);
  float rad[16], sq[16];
#pragma unroll
  for (int ci = 0; ci < 4; ++ci)
#pragma unroll
    for (int di = 0; di < 4; ++di) {
      float v = d[ci*3]*d[di*3] + d[ci*3+1]*d[di*3+1] + d[ci*3+2]*d[di*3+2];
      rad[ci*4+di] = v; sq[ci*4+di] = v * v;
    }
  float4* rv = (float4*)radial;
#pragma unroll
  for (int i = 0; i < 4; ++i)
    rv[s*4+i] = make_float4(rad[i*4], rad[i*4+1], rad[i*4+2], rad[i*4+3]);
#pragma unroll
  for (int i = 0; i < 16; ++i) sq[i] = wave_sum(sq[i]);
  __shared__ float red[4][16];
  int wv = threadIdx.x >> 6, lane = threadIdx.x & 63;
  if (lane == 0) {
#pragma unroll
    for (int i = 0; i < 16; ++i) red[wv][i] = sq[i];
  }
  __syncthreads();
  if (threadIdx.x < 16)
    pnrm[blockIdx.x * 16 + threadIdx.x] =
        red[0][threadIdx.x] + red[1][threadIdx.x] + red[2][threadIdx.x] + red[3][threadIdx.x];
}

__global__ __launch_bounds__(128)
void nrmred_k(const float* __restrict__ pnrm, float* __restrict__ nrm) {
  int t = threadIdx.x >> 4, j = threadIdx.x & 15;
  float s = 0.f;
  for (int b = 0; b < 128; ++b) s += pnrm[((t * 128 + b) << 4) + j];
  nrm[(t << 4) + j] = s;
}

// tail row (24): rad_norm(16)|ea|0*7  — sorted space
__global__ __launch_bounds__(256)
void tails_k(const float* __restrict__ radial, const float* __restrict__ nrm,
             const float* __restrict__ eaS, unsigned short* __restrict__ tailm)
{
  int m = blockIdx.x * 256 + threadIdx.x;          // < TE sorted
  int t = m >> 15;
  unsigned short tmp[24];
#pragma unroll
  for (int j = 0; j < 16; ++j) {
    float r = radial[(size_t)m * 16 + j] / fmaxf(sqrtf(nrm[(t << 4) + j]), 1e-12f);
    tmp[j] = f2bf(r);
  }
  tmp[16] = f2bf(eaS[m]);
#pragma unroll
  for (int j = 17; j < 24; ++j) tmp[j] = 0;
  uint4* dst = (uint4*)(tailm + (size_t)m * 24);
  dst[0] = ((const uint4*)tmp)[0];
  dst[1] = ((const uint4*)tmp)[1];
  dst[2] = ((const uint4*)tmp)[2];
}

// ---------------- fused msg1 (sorted, batched group): silu(P[row]+Q[col]+tail.Wt) ----------------
__global__ __launch_bounds__(256)
void msg1f_k(const unsigned short* __restrict__ PQ, const unsigned short* __restrict__ Wt,
             const unsigned short* __restrict__ tailm_g,
             const int* __restrict__ rowS_g, const int* __restrict__ colS_g,
             unsigned short* __restrict__ out)
{
  int tid = threadIdx.x;
  int e0 = blockIdx.x * 16;
  uint wreg[17];
#pragma unroll
  for (int j = 0; j < 17; ++j) wreg[j] = *(const uint*)(Wt + j * 512 + tid * 2);
  for (int i = 0; i < 16; ++i) {
    int p = e0 + i;
    int r = rowS_g[p], c = colS_g[p];
    uint pv = *(const uint*)(PQ + ((size_t)r << 10) + tid * 2);
    uint qv = *(const uint*)(PQ + ((size_t)c << 10) + 512 + tid * 2);
    float s0 = bflo(pv) + bflo(qv);
    float s1 = bfhi(pv) + bfhi(qv);
#pragma unroll
    for (int j = 0; j < 17; ++j) {
      float tj = bf2f(tailm_g[(size_t)p * 24 + j]);
      s0 += tj * bflo(wreg[j]); s1 += tj * bfhi(wreg[j]);
    }
    *(uint*)(out + ((size_t)p << 9) + tid * 2) = packbf(silu_f(s0), silu_f(s1));
  }
}

// gather-sum (sorted, sequential, batched group): segt[tloc][n] = sum msg rows
__global__ __launch_bounds__(256)
void gsum_k(const unsigned short* __restrict__ msg, const int* __restrict__ offb,
            const int* __restrict__ deg, int tbase, unsigned short* __restrict__ segt)
{
  int tloc = blockIdx.x >> 13, n = blockIdx.x & (NN - 1), tid = threadIdx.x;
  int t = tbase + tloc;
  int start = offb[(t << 13) + n], d = deg[(t << 13) + n];
  float s0 = 0.f, s1 = 0.f;
  const unsigned short* base = msg + (((size_t)tloc << 15) << 9);
  for (int j = 0; j < d; ++j) {
    uint v = *(const uint*)(base + ((size_t)(start + j) << 9) + tid * 2);
    s0 += bflo(v); s1 += bfhi(v);
  }
  *(uint*)(segt + (((size_t)tloc * NN + n) << 9) + tid * 2) = packbf(s0, s1);
}

// ---------------- wsum: collapse 8 group-local wpart slices into global wsumb ----------------
__global__ __launch_bounds__(256)
void wsum_k(const float* __restrict__ wpart, float* __restrict__ wsum_out, int wstride) {
  int id = blockIdx.x * 256 + threadIdx.x;          // < wstride
  float4 a = (float4){0.f, 0.f, 0.f, 0.f};
#pragma unroll
  for (int s = 0; s < 8; ++s) {
    float4 v = *(const float4*)&wpart[(((size_t)s * wstride) + id) * 4];
    a.x += v.x; a.y += v.y; a.z += v.z; a.w += v.w;
  }
  *(float4*)&wsum_out[(size_t)id * 4] = a;
}

// ---------------- fused trans-reduce + x_new (no atomics, CSR walk) ----------------
__global__ __launch_bounds__(256)
void trxn_k(const float* __restrict__ coord, const float* __restrict__ cd,
            const float* __restrict__ wsum, const int* __restrict__ offb,
            const int* __restrict__ deg, float* __restrict__ xout)
{
  int id = blockIdx.x * 256 + threadIdx.x;          // < NN*12
  int n = id / 12, j = id - n * 12, ci = j / 3;
  float s = 0.f; int cnt = 0;
#pragma unroll
  for (int t = 0; t < 8; ++t) {
    int o = offb[(t << 13) + n], d = deg[(t << 13) + n];
    size_t p = ((size_t)t << 15) + o;
    for (int k = 0; k < d; ++k)
      s += cd[(p + k) * 12 + j] * wsum[(p + k) * 4 + ci];
    cnt += d;
  }
  xout[id] = coord[id] + s / fmaxf((float)cnt, 1.f);
}

// ------ batched m output (sorted, per-edge wave) ------
__global__ __launch_bounds__(256)
void mout_k(const unsigned short* __restrict__ GG,
            const float* __restrict__ eW2, const float* __restrict__ wea,
            const float* __restrict__ eb2, const float* __restrict__ eaS,
            const int* __restrict__ rowS, const int* __restrict__ colS,
            const int* __restrict__ order, float* __restrict__ out_m)
{
  int wid = blockIdx.x * 4 + (threadIdx.x >> 6);   // < TE sorted
  int lane = threadIdx.x & 63;
  int t = wid >> 15;
  int r = rowS[wid], c = colS[wid];
  float eav = eaS[wid];
  short8v gv  = *(const short8v*)(GG + ((size_t)r << 10) + lane * 8);
  short8v gcv = *(const short8v*)(GG + ((size_t)c << 10) + 512 + lane * 8);
  const float4* w4 = (const float4*)(eW2 + lane * 8);
  const float4* a4 = (const float4*)(wea + lane * 8);
  float4 w0 = w4[0], w1 = w4[1], a0 = a4[0], a1 = a4[1];
  float wv8[8] = {w0.x,w0.y,w0.z,w0.w,w1.x,w1.y,w1.z,w1.w};
  float av8[8] = {a0.x,a0.y,a0.z,a0.w,a1.x,a1.y,a1.z,a1.w};
  float s = 0.f;
#pragma unroll
  for (int j = 0; j < 8; ++j)
    s += wv8[j] * silu_f(bf2f((unsigned short)gv[j]) + bf2f((unsigned short)gcv[j]) + eav * av8[j]);
  s = wave_sum(s);
  if (lane == 0) out_m[((size_t)t << 15) + order[wid]] = s + eb2[0];
}

// ---------------- launch ----------------
extern "C" void kernel_launch(void* const* d_in, const int* in_sizes, int n_in,
                              void* d_out, int out_size, void* d_ws, size_t ws_size,
                              hipStream_t stream)
{
  const float* h     = (const float*)d_in[0];
  const float* coord = (const float*)d_in[1];
  const float* ea    = (const float*)d_in[2];
  const int*   eidx  = (const int*)  d_in[3];
  const float* mW1   = (const float*)d_in[4];
  const float* mb1   = (const float*)d_in[5];
  const float* mW2   = (const float*)d_in[6];
  const float* mb2   = (const float*)d_in[7];
  const float* nW1   = (const float*)d_in[8];
  const float* nb1   = (const float*)d_in[9];
  const float* nW2   = (const float*)d_in[10];
  const float* nb2   = (const float*)d_in[11];
  const float* eW1   = (const float*)d_in[12];
  const float* eb1   = (const float*)d_in[13];
  const float* eW2   = (const float*)d_in[14];
  const float* eb2   = (const float*)d_in[15];
  const float* relW  = (const float*)d_in[16];
  const float* cW1   = (const float*)d_in[17];
  const float* cb1   = (const float*)d_in[18];
  const float* cW2   = (const float*)d_in[19];

  float* out   = (float*)d_out;
  float* out_h = out;
  float* out_x = out + (size_t)NN * DD;
  float* out_m = out_x + (size_t)NN * CC * 3;

  char* ws = (char*)d_ws;
  size_t off = 0;
  auto alloc = [&](size_t bytes) -> void* {
    void* p = ws + off; off += (bytes + 255) & ~(size_t)255; return p;
  };
  // ---- fixed buffers (~98 MB) ----
  float* cd     = (float*)alloc((size_t)TE * 12 * 4);                     // 12.6 MB
  unsigned short* tailm = (unsigned short*)alloc((size_t)TE * 24 * 2);    // 12.6 MB
  float* agg    = (float*)alloc((size_t)NN * 512 * 4);                    // 16.8 MB (f32, += over groups)
  unsigned short* h_bf  = (unsigned short*)alloc((size_t)NN * 512 * 2);
  unsigned short* hn_bf = (unsigned short*)alloc((size_t)NN * 512 * 2);
  unsigned short* PQb   = (unsigned short*)alloc((size_t)NN * 1024 * 2);  // 16.8 MB (GGb aliases)
  unsigned short* GGb   = PQb;                                            // pass-2 alias (PQ dead)
  unsigned short* mW1pq = (unsigned short*)alloc((size_t)1024 * 512 * 2);
  unsigned short* mW1t  = (unsigned short*)alloc((size_t)17 * 512 * 2);
  unsigned short* mW2b  = (unsigned short*)alloc((size_t)512 * 512 * 2);
  unsigned short* nW1b  = (unsigned short*)alloc((size_t)512 * 1024 * 2);
  unsigned short* nW2b  = (unsigned short*)alloc((size_t)512 * 512 * 2);
  unsigned short* eGc   = (unsigned short*)alloc((size_t)1024 * 512 * 2);
  float* weab   = (float*)alloc(512 * 4);
  float* pqbias = (float*)alloc(1024 * 4);
  float* ggbias = (float*)alloc(1024 * 4);
  unsigned short* relWb = (unsigned short*)alloc((size_t)TT * 512 * 512 * 2); // 4.2 MB
  unsigned short* cW1b  = (unsigned short*)alloc((size_t)TT * 512 * 512 * 2); // 4.2 MB
  int* deg     = (int*)alloc((size_t)TT * NN * 4);
  int* offb    = (int*)alloc((size_t)TT * NN * 4);
  int* cursor  = (int*)alloc((size_t)TT * NN * 4);
  int* order   = (int*)alloc((size_t)TE * 4);
  int* rank    = (int*)alloc((size_t)TE * 4);
  int* rowS    = (int*)alloc((size_t)TE * 4);
  int* colS    = (int*)alloc((size_t)TE * 4);
  float* eaS   = (float*)alloc((size_t)TE * 4);
  float* wsumb = (float*)alloc((size_t)TE * 4 * 4);                       // 4.2 MB
  float* pnrm  = (float*)alloc((size_t)(TE / 256) * 16 * 4);
  float* nrm   = (float*)alloc((size_t)TT * 16 * 4);

  // ---- choose group size G: per-G = bufA 33.6 + bufB 33.6 + segt 8.4 + wpart 4.2 MB ----
  const size_t perG = (size_t)EE * 512 * 2 * 2 + (size_t)NN * 512 * 2 + (size_t)8 * EE * 16;
  int G = 4;
  while (G > 1 && off + (size_t)G * perG + (1 << 20) > ws_size) G >>= 1;
  unsigned short* bufA = (unsigned short*)alloc((size_t)G * EE * 512 * 2);
  unsigned short* bufB = (unsigned short*)alloc((size_t)G * EE * 512 * 2);
  unsigned short* segt = (unsigned short*)alloc((size_t)G * NN * 512 * 2);
  float* wpart = (float*)alloc((size_t)8 * G * EE * 4 * 4);               // group-local
  unsigned short* aggb = segt;    // alias: bf16 agg written after segt is dead
  float* radial = (float*)bufA;   // alias: radial f32 (16.8 MB) consumed by tails_k before bufA use

  hipMemsetAsync(deg, 0, (size_t)TT * NN * 4, stream);
  hipMemsetAsync(agg, 0, (size_t)NN * 512 * 4, stream);

  auto cvt = [&](const float* in, unsigned short* o, int n) {
    cvt_k<<<(n + 255) / 256, 256, 0, stream>>>(in, o, n);
  };
  cvt(h,    h_bf,  NN * 512);
  cvt(mW2,  mW2b,  512 * 512);
  cvt(nW1,  nW1b,  512 * 1024);
  cvt(nW2,  nW2b,  512 * 512);
  cvt(relW, relWb, TT * 512 * 512);
  cvt(cW1,  cW1b,  TT * 512 * 512);
  slicew_k<<<1024, 256, 0, stream>>>(mW1, mW1pq, 1041, 0);
  slicew_k<<<1024, 256, 0, stream>>>(mW1, mW1pq + 512 * 512, 1041, 512);
  tailw_k<<<34, 256, 0, stream>>>(mW1, mW1t);
  slicew_k<<<1024, 256, 0, stream>>>(eW1, eGc, 1025, 0);
  slicew_k<<<1024, 256, 0, stream>>>(eW1, eGc + 512 * 512, 1025, 513);
  weaw_k<<<2, 256, 0, stream>>>(eW1, weab);
  biasb_k<<<4, 256, 0, stream>>>(mb1, eb1, pqbias, ggbias);

  // sort + geometry (sorted space)
  hist_k<<<TE / 256, 256, 0, stream>>>(eidx, deg);
  scan_k<<<TT, 256, 0, stream>>>(deg, offb, cursor);
  scat_k<<<TE / 256, 256, 0, stream>>>(eidx, ea, cursor, order, rank, rowS, colS, eaS);
  cdrad_k<<<TE / 256, 256, 0, stream>>>(coord, eidx, rank, cd, radial, pnrm);
  nrmred_k<<<1, 128, 0, stream>>>(pnrm, nrm);
  tails_k<<<TE / 256, 256, 0, stream>>>(radial, nrm, eaS, tailm);

  // PQ = h @ [mW1a;mW1q]^T + [mb1;0]   (N x 1024): 8*64=512 blocks, lognx=3
  mgemm_k<<<512, 256, 0, stream>>>(AgDirect{h_bf, 512}, BgDirect{mW1pq, 512}, 512, 0, 3,
      pqbias, nullptr, nullptr, PQb, 1024, 0, nullptr, nullptr, 0);

  // -------- pass 1: batched groups of G relations --------
  for (int g = 0; g < TT / G; ++g) {
    const int tbase = g * G;
    const size_t gb = (size_t)tbase << 15;
    msg1f_k<<<(G * EE) / 16, 256, 0, stream>>>(PQb, mW1t, tailm + gb * 24,
        rowS + gb, colS + gb, bufA);
    mgemm_k<<<4 * (G * EE / 128), 256, 0, stream>>>(AgDirect{bufA, 512},
        BgDirect{mW2b, 512}, 512, tbase, 2,
        mb2, nullptr, nullptr, bufB, 512, FLAG_SILU, nullptr, nullptr, 0);
    gsum_k<<<G * NN, 256, 0, stream>>>(bufB, offb, deg, tbase, segt);
    // agg += segt @ relW[tbase..tbase+G)^T  (K = G*512, f32 accumulate): 256 blocks
    mgemm_k<<<4 * (NN / 128), 256, 0, stream>>>(AgSegG{segt},
        BgRelG{relWb + ((size_t)tbase << 18)}, G * 512, 0, 2,
        nullptr, agg, agg, nullptr, 512, FLAG_RES, nullptr, nullptr, 0);
    // hid = silu(msg @ cW1[t]^T + cb1[t]) -> fused w-partials into wpart
    mgemm_k<<<4 * (G * EE / 128), 256, 0, stream>>>(AgDirect{bufB, 512},
        BgPerT{cW1b}, 512, tbase, 2,
        cb1, nullptr, nullptr, nullptr, 512, FLAG_SILU | FLAG_WEPI | FLAG_BIAS_T,
        cW2, wpart, G * EE);
    wsum_k<<<(G * EE) / 256, 256, 0, stream>>>(wpart, wsumb + gb * 4, G * EE);
  }

  // fused trans-reduce + x_new (no atomics)
  trxn_k<<<(NN * 12) / 256, 256, 0, stream>>>(coord, cd, wsumb, offb, deg, out_x);

  // -------- node MLP + residual -> h_new --------
  cvt(agg, aggb, NN * 512);
  mgemm_k<<<4 * (NN / 128), 256, 0, stream>>>(AgHcat{h_bf, aggb}, BgDirect{nW1b, 1024}, 1024, 0, 2,
      nb1, nullptr, nullptr, bufA, 512, FLAG_SILU, nullptr, nullptr, 0);
  mgemm_k<<<4 * (NN / 128), 256, 0, stream>>>(AgDirect{bufA, 512}, BgDirect{nW2b, 512}, 512, 0, 2,
      nb2, h, out_h, hn_bf, 512, FLAG_RES, nullptr, nullptr, 0);

  // -------- pass 2: GG = hn @ [eW1a;eW1c]^T + [eb1;0] ; fused m (per-edge) --------
  mgemm_k<<<512, 256, 0, stream>>>(AgDirect{hn_bf, 512}, BgDirect{eGc, 512}, 512, 0, 3,
      ggbias, nullptr, nullptr, GGb, 1024, 0, nullptr, nullptr, 0);
  mout_k<<<TE / 4, 256, 0, stream>>>(GGb, eW2, weab, eb2, eaS, rowS, colS, order, out_m);

  (void)in_sizes; (void)n_in; (void)out_size; (void)ws_size;
}

// Round 11
// 1432.923 us; speedup vs baseline: 1.4722x; 1.1323x over previous
//
#include <hip/hip_runtime.h>
#include <cstdint>

#define NN 8192
#define DD 512
#define CC 4
#define TT 8
#define EE 32768
#define TE (TT*EE)

typedef __attribute__((ext_vector_type(8))) short short8v;
typedef __attribute__((ext_vector_type(4))) float f32x4;
typedef unsigned int uint;

constexpr int FLAG_SILU = 1, FLAG_RES = 2, FLAG_WEPI = 4, FLAG_BIAS_T = 8;

__device__ __forceinline__ float silu_f(float x) { return x / (1.f + __expf(-x)); }

__device__ __forceinline__ unsigned short f2bf(float f) {
  uint u = __builtin_bit_cast(uint, f);
  u += 0x7fffu + ((u >> 16) & 1u);
  return (unsigned short)(u >> 16);
}
__device__ __forceinline__ float bf2f(unsigned short b) {
  uint u = ((uint)b) << 16;
  return __builtin_bit_cast(float, u);
}
__device__ __forceinline__ float bflo(uint u) { return __builtin_bit_cast(float, u << 16); }
__device__ __forceinline__ float bfhi(uint u) { return __builtin_bit_cast(float, u & 0xffff0000u); }
__device__ __forceinline__ uint packbf(float a, float b) {
  return (uint)f2bf(a) | ((uint)f2bf(b) << 16);
}

__device__ __forceinline__ float wave_sum(float v) {
#pragma unroll
  for (int off = 32; off; off >>= 1) v += __shfl_xor(v, off);
  return v;
}

__device__ __forceinline__ void gload16(const void* g, void* l) {
  __builtin_amdgcn_global_load_lds(
      (const __attribute__((address_space(1))) void*)g,
      (__attribute__((address_space(3))) void*)l, 16, 0, 0);
}

// chunked XCD swizzle: logical index l from launched blockIdx i (nwg % 8 == 0)
__device__ __forceinline__ int xcd_swz(int i, int nwg) {
  return (i & 7) * (nwg >> 3) + (i >> 3);
}

// ---------------- A/B-side gather functors: ptr(m,k,tt) -> 16B-aligned 8-elem chunk ----------------
struct AgDirect { const unsigned short* p; int K;
  __device__ const void* ptr(int m, int k, int) const { return p + (size_t)m * K + k; } };

struct AgHcat { const unsigned short* hb; const unsigned short* ab;
  __device__ const void* ptr(int m, int k, int) const {
    return (k < 512) ? (const void*)(hb + ((size_t)m << 9) + k)
                     : (const void*)(ab + ((size_t)m << 9) + (k - 512)); } };

struct AgSegG { const unsigned short* seg;     // [G][N][512], k = tloc*512+hh
  __device__ const void* ptr(int m, int k, int) const {
    return seg + (((size_t)(k >> 9) * NN + m) << 9) + (k & 511); } };

struct BgDirect { const unsigned short* p; int K;
  __device__ const void* ptr(int o, int k, int) const { return p + (size_t)o * K + k; } };

struct BgRelG { const unsigned short* w;       // [G][D][H] (pre-offset), o=d, k=tloc*512+hh
  __device__ const void* ptr(int o, int k, int) const {
    return w + (((size_t)(k >> 9) * 512 + o) << 9) + (k & 511); } };

struct BgPerT { const unsigned short* w;       // [T][512][512], global tt select
  __device__ const void* ptr(int o, int k, int tt) const {
    return w + (((size_t)tt << 18) + ((size_t)o << 9)) + k; } };

// ------- bf16 MFMA GEMM, 1D grid + XCD-chunked swizzle; vectorized bf16 epilogue -------
template<class AG, class BG>
__global__ __launch_bounds__(256)
void mgemm_k(AG ag, BG bg, int K, int tbase, int lognx,
             const float* __restrict__ bias, const float* __restrict__ res,
             float* __restrict__ outF, unsigned short* __restrict__ outB, int ldo, int flags,
             const float* __restrict__ cw2, float* __restrict__ wpart, int wstride)
{
  __shared__ __align__(16) unsigned short SM[128 * 136];   // As|Bs (16384) / epilogue tile (17408)
  unsigned short* As = SM;
  unsigned short* Bs = SM + 128 * 64;
  const int nwg = gridDim.x;
  const int swz = xcd_swz(blockIdx.x, nwg);
  const int xb = swz & ((1 << lognx) - 1), yb = swz >> lognx;
  const int m0 = yb * 128, o0 = xb * 128;
  const int tt = tbase + (m0 >> 15);
  const int tid = threadIdx.x, wave = tid >> 6, lane = tid & 63;
  const int wr = (wave >> 1) * 64, wc = (wave & 1) * 64;
  const int rs = lane >> 3, sl = lane & 7;

  f32x4 acc[4][4];
#pragma unroll
  for (int i = 0; i < 4; ++i)
#pragma unroll
    for (int j = 0; j < 4; ++j) acc[i][j] = (f32x4)0.f;

  for (int k0 = 0; k0 < K; k0 += 64) {
#pragma unroll
    for (int i = 0; i < 4; ++i) {
      int r = i * 32 + wave * 8 + rs;
      int slot = sl ^ (r & 7);
      gload16(ag.ptr(m0 + r, k0 + slot * 8, tt), &As[(i * 32 + wave * 8) * 64]);
    }
#pragma unroll
    for (int i = 0; i < 4; ++i) {
      int r = i * 32 + wave * 8 + rs;
      int slot = sl ^ (r & 7);
      gload16(bg.ptr(o0 + r, k0 + slot * 8, tt), &Bs[(i * 32 + wave * 8) * 64]);
    }
    __syncthreads();

    short8v a[4][2], b[4][2];
#pragma unroll
    for (int mi = 0; mi < 4; ++mi)
#pragma unroll
      for (int s = 0; s < 2; ++s) {
        int row = wr + mi * 16 + (lane & 15);
        int slot = (s * 4 + (lane >> 4)) ^ (row & 7);
        a[mi][s] = *(const short8v*)&As[row * 64 + slot * 8];
      }
#pragma unroll
    for (int ni = 0; ni < 4; ++ni)
#pragma unroll
      for (int s = 0; s < 2; ++s) {
        int row = wc + ni * 16 + (lane & 15);
        int slot = (s * 4 + (lane >> 4)) ^ (row & 7);
        b[ni][s] = *(const short8v*)&Bs[row * 64 + slot * 8];
      }
#pragma unroll
    for (int s = 0; s < 2; ++s)
#pragma unroll
      for (int mi = 0; mi < 4; ++mi)
#pragma unroll
        for (int ni = 0; ni < 4; ++ni)
          acc[mi][ni] = __builtin_amdgcn_mfma_f32_16x16x32_bf16(a[mi][s], b[ni][s], acc[mi][ni], 0, 0, 0);
    __syncthreads();
  }

  const int r4 = (lane >> 4) * 4, cl = lane & 15;
  if (flags & FLAG_WEPI) {
    // w[e][c] partial = sum_{cols of this block} silu(v+bias) * cw2[c][col], 8 slices
    const int slice = xb * 2 + (wave & 1);
    const float* cw2t = cw2 + tt * 2048;
    const float* bt = bias + tt * 512;
#pragma unroll
    for (int mi = 0; mi < 4; ++mi) {
      float sc[4][4];
#pragma unroll
      for (int rg = 0; rg < 4; ++rg)
#pragma unroll
        for (int c = 0; c < 4; ++c) sc[rg][c] = 0.f;
#pragma unroll
      for (int ni = 0; ni < 4; ++ni) {
        int col = o0 + wc + ni * 16 + cl;
        float c0 = cw2t[col], c1 = cw2t[512 + col], c2 = cw2t[1024 + col], c3 = cw2t[1536 + col];
        float bb = bt[col];
#pragma unroll
        for (int rg = 0; rg < 4; ++rg) {
          float v = silu_f(acc[mi][ni][rg] + bb);
          sc[rg][0] += v * c0; sc[rg][1] += v * c1; sc[rg][2] += v * c2; sc[rg][3] += v * c3;
        }
      }
#pragma unroll
      for (int rg = 0; rg < 4; ++rg)
#pragma unroll
        for (int c = 0; c < 4; ++c) {
          float s = sc[rg][c];
          s += __shfl_xor(s, 1); s += __shfl_xor(s, 2);
          s += __shfl_xor(s, 4); s += __shfl_xor(s, 8);
          sc[rg][c] = s;
        }
      if (cl == 0) {
        int p = m0 + wr + mi * 16 + r4;              // group-local sorted pos
#pragma unroll
        for (int rg = 0; rg < 4; ++rg) {
          float4 o = make_float4(sc[rg][0], sc[rg][1], sc[rg][2], sc[rg][3]);
          *(float4*)&wpart[(((size_t)slice * wstride) + p + rg) * 4] = o;
        }
      }
    }
    return;
  }
  if (outB && !outF) {
    // vectorized epilogue: stage bf16 tile in LDS (stride 136), then 16B stores
    unsigned short* Ep = SM;
#pragma unroll
    for (int mi = 0; mi < 4; ++mi)
#pragma unroll
      for (int ni = 0; ni < 4; ++ni)
#pragma unroll
        for (int rg = 0; rg < 4; ++rg) {
          int row = wr + mi * 16 + r4 + rg;
          int col = wc + ni * 16 + cl;
          float v = acc[mi][ni][rg];
          if (bias) v += (flags & FLAG_BIAS_T) ? bias[tt * 512 + o0 + col] : bias[o0 + col];
          if (flags & FLAG_SILU) v = silu_f(v);
          Ep[row * 136 + col] = f2bf(v);
        }
    __syncthreads();
#pragma unroll
    for (int p = 0; p < 8; ++p) {
      int idx = p * 256 + tid;
      int row = idx >> 4, ch = idx & 15;
      short8v vv = *(const short8v*)&Ep[row * 136 + ch * 8];
      *(short8v*)(outB + (size_t)(m0 + row) * ldo + o0 + ch * 8) = vv;
    }
    return;
  }
#pragma unroll
  for (int mi = 0; mi < 4; ++mi)
#pragma unroll
    for (int ni = 0; ni < 4; ++ni)
#pragma unroll
      for (int rg = 0; rg < 4; ++rg) {
        int row = m0 + wr + mi * 16 + r4 + rg;
        int col = o0 + wc + ni * 16 + cl;
        float v = acc[mi][ni][rg];
        if (bias) v += (flags & FLAG_BIAS_T) ? bias[tt * 512 + col] : bias[col];
        if (flags & FLAG_SILU) v = silu_f(v);
        if (flags & FLAG_RES) v += res[(size_t)row * ldo + col];
        if (outF) outF[(size_t)row * ldo + col] = v;
        if (outB) outB[(size_t)row * ldo + col] = f2bf(v);
      }
}

// ---------------- prep kernels ----------------
__global__ __launch_bounds__(256)
void cvt_k(const float* __restrict__ in, unsigned short* __restrict__ out, int n) {
  int i = blockIdx.x * 256 + threadIdx.x;
  if (i < n) out[i] = f2bf(in[i]);
}

__global__ __launch_bounds__(256)
void slicew_k(const float* __restrict__ w, unsigned short* __restrict__ o, int Kin, int col0) {
  int i = blockIdx.x * 256 + threadIdx.x;   // < 512*512
  int r = i >> 9, k = i & 511;
  o[i] = f2bf(w[(size_t)r * Kin + col0 + k]);
}

__global__ __launch_bounds__(256)
void tailw_k(const float* __restrict__ mW1, unsigned short* __restrict__ o) {
  int i = blockIdx.x * 256 + threadIdx.x;   // < 17*512
  if (i >= 17 * 512) return;
  int j = i >> 9, c = i & 511;
  o[i] = f2bf(mW1[(size_t)c * 1041 + 1024 + j]);
}

__global__ __launch_bounds__(256)
void weaw_k(const float* __restrict__ eW1, float* __restrict__ wea) {
  int i = blockIdx.x * 256 + threadIdx.x;   // < 512
  if (i < 512) wea[i] = eW1[(size_t)i * 1025 + 512];
}

__global__ __launch_bounds__(256)
void biasb_k(const float* __restrict__ mb1, const float* __restrict__ eb1,
             float* __restrict__ pqb, float* __restrict__ ggb) {
  int i = blockIdx.x * 256 + threadIdx.x;   // < 1024
  if (i < 1024) {
    pqb[i] = (i < 512) ? mb1[i] : 0.f;
    ggb[i] = (i < 512) ? eb1[i] : 0.f;
  }
}

// ---------------- counting sort of edges by destination node ----------------
__global__ __launch_bounds__(256)
void hist_k(const int* __restrict__ eidx, int* __restrict__ deg) {
  int id = blockIdx.x * 256 + threadIdx.x;         // < TE
  int t = id >> 15, e = id & (EE - 1);
  atomicAdd(&deg[(t << 13) + eidx[(t << 16) + e]], 1);
}

__global__ __launch_bounds__(256)
void scan_k(const int* __restrict__ deg, int* __restrict__ off, int* __restrict__ cursor) {
  int t = blockIdx.x, tid = threadIdx.x;
  __shared__ int lds[256];
  int base = 0;
  for (int ch = 0; ch < 32; ++ch) {
    int i = ch * 256 + tid;
    int v = deg[(t << 13) + i];
    __syncthreads();
    lds[tid] = v;
    __syncthreads();
    for (int s = 1; s < 256; s <<= 1) {
      int x = (tid >= s) ? lds[tid - s] : 0;
      __syncthreads();
      if (tid >= s) lds[tid] += x;
      __syncthreads();
    }
    int excl = base + lds[tid] - v;
    off[(t << 13) + i] = excl;
    cursor[(t << 13) + i] = excl;
    base += lds[255];
  }
}

__global__ __launch_bounds__(256)
void scat_k(const int* __restrict__ eidx, const float* __restrict__ ea, int* __restrict__ cursor,
            int* __restrict__ order, int* __restrict__ rank,
            int* __restrict__ rowS, int* __restrict__ colS, float* __restrict__ eaS) {
  int id = blockIdx.x * 256 + threadIdx.x;         // < TE
  int t = id >> 15, e = id & (EE - 1);
  int r = eidx[(t << 16) + e], c = eidx[(t << 16) + EE + e];
  int pos = atomicAdd(&cursor[(t << 13) + r], 1);
  size_t g = ((size_t)t << 15) + pos;
  order[g] = e; rank[id] = pos; rowS[g] = r; colS[g] = c; eaS[g] = ea[id];
}

// ---------------- cd / radial at SORTED positions + per-block sq partials ----------------
__global__ __launch_bounds__(256)
void cdrad_k(const float* __restrict__ coord, const int* __restrict__ eidx,
             const int* __restrict__ rank,
             float* __restrict__ cd, float* __restrict__ radial, float* __restrict__ pnrm)
{
  int m = blockIdx.x * 256 + threadIdx.x;          // < TE (original order)
  int t = m >> 15, e = m & (EE - 1);
  int r = eidx[(t << 16) + e], c = eidx[(t << 16) + EE + e];
  size_t s = ((size_t)t << 15) + rank[m];          // sorted pos
  const float4* cv4 = (const float4*)coord;
  float4 A0 = cv4[r * 3], A1 = cv4[r * 3 + 1], A2 = cv4[r * 3 + 2];
  float4 B0 = cv4[c * 3], B1 = cv4[c * 3 + 1], B2 = cv4[c * 3 + 2];
  float d[12] = {A0.x-B0.x, A0.y-B0.y, A0.z-B0.z, A0.w-B0.w,
                 A1.x-B1.x, A1.y-B1.y, A1.z-B1.z, A1.w-B1.w,
                 A2.x-B2.x, A2.y-B2.y, A2.z-B2.z, A2.w-B2.w};
  float4* cdv = (float4*)cd;
  cdv[s*3+0] = make_float4(d[0],d[1],d[2],d[3]);
  cdv[s*3+1] = make_float4(d[4],d[5],d[6],d[7]);
  cdv[s*3+2] = make_float4(d[8],d[9],d[10],d[11]);
  float rad[16], sq[16];
#pragma unroll
  for (int ci = 0; ci < 4; ++ci)
#pragma unroll
    for (int di = 0; di < 4; ++di) {
      float v = d[ci*3]*d[di*3] + d[ci*3+1]*d[di*3+1] + d[ci*3+2]*d[di*3+2];
      rad[ci*4+di] = v; sq[ci*4+di] = v * v;
    }
  float4* rv = (float4*)radial;
#pragma unroll
  for (int i = 0; i < 4; ++i)
    rv[s*4+i] = make_float4(rad[i*4], rad[i*4+1], rad[i*4+2], rad[i*4+3]);
#pragma unroll
  for (int i = 0; i < 16; ++i) sq[i] = wave_sum(sq[i]);
  __shared__ float red[4][16];
  int wv = threadIdx.x >> 6, lane = threadIdx.x & 63;
  if (lane == 0) {
#pragma unroll
    for (int i = 0; i < 16; ++i) red[wv][i] = sq[i];
  }
  __syncthreads();
  if (threadIdx.x < 16)
    pnrm[blockIdx.x * 16 + threadIdx.x] =
        red[0][threadIdx.x] + red[1][threadIdx.x] + red[2][threadIdx.x] + red[3][threadIdx.x];
}

__global__ __launch_bounds__(128)
void nrmred_k(const float* __restrict__ pnrm, float* __restrict__ nrm) {
  int t = threadIdx.x >> 4, j = threadIdx.x & 15;
  float s = 0.f;
  for (int b = 0; b < 128; ++b) s += pnrm[((t * 128 + b) << 4) + j];
  nrm[(t << 4) + j] = s;
}

// tail row (24): rad_norm(16)|ea|0*7  — sorted space
__global__ __launch_bounds__(256)
void tails_k(const float* __restrict__ radial, const float* __restrict__ nrm,
             const float* __restrict__ eaS, unsigned short* __restrict__ tailm)
{
  int m = blockIdx.x * 256 + threadIdx.x;          // < TE sorted
  int t = m >> 15;
  unsigned short tmp[24];
#pragma unroll
  for (int j = 0; j < 16; ++j) {
    float r = radial[(size_t)m * 16 + j] / fmaxf(sqrtf(nrm[(t << 4) + j]), 1e-12f);
    tmp[j] = f2bf(r);
  }
  tmp[16] = f2bf(eaS[m]);
#pragma unroll
  for (int j = 17; j < 24; ++j) tmp[j] = 0;
  uint4* dst = (uint4*)(tailm + (size_t)m * 24);
  dst[0] = ((const uint4*)tmp)[0];
  dst[1] = ((const uint4*)tmp)[1];
  dst[2] = ((const uint4*)tmp)[2];
}

// ---------------- fused msg1 (sorted, XCD-swizzled): silu(P[row]+Q[col]+tail.Wt) ----------------
__global__ __launch_bounds__(256)
void msg1f_k(const unsigned short* __restrict__ PQ, const unsigned short* __restrict__ Wt,
             const unsigned short* __restrict__ tailm_g,
             const int* __restrict__ rowS_g, const int* __restrict__ colS_g,
             unsigned short* __restrict__ out)
{
  int tid = threadIdx.x;
  int e0 = xcd_swz(blockIdx.x, gridDim.x) * 16;
  uint wreg[17];
#pragma unroll
  for (int j = 0; j < 17; ++j) wreg[j] = *(const uint*)(Wt + j * 512 + tid * 2);
  for (int i = 0; i < 16; ++i) {
    int p = e0 + i;
    int r = rowS_g[p], c = colS_g[p];
    uint pv = *(const uint*)(PQ + ((size_t)r << 10) + tid * 2);
    uint qv = *(const uint*)(PQ + ((size_t)c << 10) + 512 + tid * 2);
    uint4 t0 = *(const uint4*)(tailm_g + (size_t)p * 24);
    uint4 t1 = *(const uint4*)(tailm_g + (size_t)p * 24 + 8);
    uint  t2 = *(const uint*)(tailm_g + (size_t)p * 24 + 16);
    float tl[17] = {bflo(t0.x), bfhi(t0.x), bflo(t0.y), bfhi(t0.y),
                    bflo(t0.z), bfhi(t0.z), bflo(t0.w), bfhi(t0.w),
                    bflo(t1.x), bfhi(t1.x), bflo(t1.y), bfhi(t1.y),
                    bflo(t1.z), bfhi(t1.z), bflo(t1.w), bfhi(t1.w),
                    bflo(t2)};
    float s0 = bflo(pv) + bflo(qv);
    float s1 = bfhi(pv) + bfhi(qv);
#pragma unroll
    for (int j = 0; j < 17; ++j) {
      s0 += tl[j] * bflo(wreg[j]); s1 += tl[j] * bfhi(wreg[j]);
    }
    *(uint*)(out + ((size_t)p << 9) + tid * 2) = packbf(silu_f(s0), silu_f(s1));
  }
}

// gather-sum (sorted, sequential, XCD-swizzled): segt[tloc][n] = sum msg rows
__global__ __launch_bounds__(256)
void gsum_k(const unsigned short* __restrict__ msg, const int* __restrict__ offb,
            const int* __restrict__ deg, int tbase, unsigned short* __restrict__ segt)
{
  int l = xcd_swz(blockIdx.x, gridDim.x);
  int tloc = l >> 13, n = l & (NN - 1), tid = threadIdx.x;
  int t = tbase + tloc;
  int start = offb[(t << 13) + n], d = deg[(t << 13) + n];
  float s0 = 0.f, s1 = 0.f;
  const unsigned short* base = msg + (((size_t)tloc << 15) << 9);
  for (int j = 0; j < d; ++j) {
    uint v = *(const uint*)(base + ((size_t)(start + j) << 9) + tid * 2);
    s0 += bflo(v); s1 += bfhi(v);
  }
  *(uint*)(segt + (((size_t)tloc * NN + n) << 9) + tid * 2) = packbf(s0, s1);
}

// ---------------- wsum: collapse 8 group-local wpart slices into global wsumb ----------------
__global__ __launch_bounds__(256)
void wsum_k(const float* __restrict__ wpart, float* __restrict__ wsum_out, int wstride) {
  int id = xcd_swz(blockIdx.x, gridDim.x) * 256 + threadIdx.x;   // < wstride
  float4 a = (float4){0.f, 0.f, 0.f, 0.f};
#pragma unroll
  for (int s = 0; s < 8; ++s) {
    float4 v = *(const float4*)&wpart[(((size_t)s * wstride) + id) * 4];
    a.x += v.x; a.y += v.y; a.z += v.z; a.w += v.w;
  }
  *(float4*)&wsum_out[(size_t)id * 4] = a;
}

// ---------------- fused trans-reduce + x_new (no atomics, CSR walk) ----------------
__global__ __launch_bounds__(256)
void trxn_k(const float* __restrict__ coord, const float* __restrict__ cd,
            const float* __restrict__ wsum, const int* __restrict__ offb,
            const int* __restrict__ deg, float* __restrict__ xout)
{
  int id = blockIdx.x * 256 + threadIdx.x;          // < NN*12
  int n = id / 12, j = id - n * 12, ci = j / 3;
  float s = 0.f; int cnt = 0;
#pragma unroll
  for (int t = 0; t < 8; ++t) {
    int o = offb[(t << 13) + n], d = deg[(t << 13) + n];
    size_t p = ((size_t)t << 15) + o;
    for (int k = 0; k < d; ++k)
      s += cd[(p + k) * 12 + j] * wsum[(p + k) * 4 + ci];
    cnt += d;
  }
  xout[id] = coord[id] + s / fmaxf((float)cnt, 1.f);
}

// ------ batched m output (sorted, per-edge wave) ------
__global__ __launch_bounds__(256)
void mout_k(const unsigned short* __restrict__ GG,
            const float* __restrict__ eW2, const float* __restrict__ wea,
            const float* __restrict__ eb2, const float* __restrict__ eaS,
            const int* __restrict__ rowS, const int* __restrict__ colS,
            const int* __restrict__ order, float* __restrict__ out_m)
{
  int wid = blockIdx.x * 4 + (threadIdx.x >> 6);   // < TE sorted
  int lane = threadIdx.x & 63;
  int t = wid >> 15;
  int r = rowS[wid], c = colS[wid];
  float eav = eaS[wid];
  short8v gv  = *(const short8v*)(GG + ((size_t)r << 10) + lane * 8);
  short8v gcv = *(const short8v*)(GG + ((size_t)c << 10) + 512 + lane * 8);
  const float4* w4 = (const float4*)(eW2 + lane * 8);
  const float4* a4 = (const float4*)(wea + lane * 8);
  float4 w0 = w4[0], w1 = w4[1], a0 = a4[0], a1 = a4[1];
  float wv8[8] = {w0.x,w0.y,w0.z,w0.w,w1.x,w1.y,w1.z,w1.w};
  float av8[8] = {a0.x,a0.y,a0.z,a0.w,a1.x,a1.y,a1.z,a1.w};
  float s = 0.f;
#pragma unroll
  for (int j = 0; j < 8; ++j)
    s += wv8[j] * silu_f(bf2f((unsigned short)gv[j]) + bf2f((unsigned short)gcv[j]) + eav * av8[j]);
  s = wave_sum(s);
  if (lane == 0) out_m[((size_t)t << 15) + order[wid]] = s + eb2[0];
}

// ---------------- launch ----------------
extern "C" void kernel_launch(void* const* d_in, const int* in_sizes, int n_in,
                              void* d_out, int out_size, void* d_ws, size_t ws_size,
                              hipStream_t stream)
{
  const float* h     = (const float*)d_in[0];
  const float* coord = (const float*)d_in[1];
  const float* ea    = (const float*)d_in[2];
  const int*   eidx  = (const int*)  d_in[3];
  const float* mW1   = (const float*)d_in[4];
  const float* mb1   = (const float*)d_in[5];
  const float* mW2   = (const float*)d_in[6];
  const float* mb2   = (const float*)d_in[7];
  const float* nW1   = (const float*)d_in[8];
  const float* nb1   = (const float*)d_in[9];
  const float* nW2   = (const float*)d_in[10];
  const float* nb2   = (const float*)d_in[11];
  const float* eW1   = (const float*)d_in[12];
  const float* eb1   = (const float*)d_in[13];
  const float* eW2   = (const float*)d_in[14];
  const float* eb2   = (const float*)d_in[15];
  const float* relW  = (const float*)d_in[16];
  const float* cW1   = (const float*)d_in[17];
  const float* cb1   = (const float*)d_in[18];
  const float* cW2   = (const float*)d_in[19];

  float* out   = (float*)d_out;
  float* out_h = out;
  float* out_x = out + (size_t)NN * DD;
  float* out_m = out_x + (size_t)NN * CC * 3;

  char* ws = (char*)d_ws;
  size_t off = 0;
  auto alloc = [&](size_t bytes) -> void* {
    void* p = ws + off; off += (bytes + 255) & ~(size_t)255; return p;
  };
  // ---- fixed buffers (~98 MB) ----
  float* cd     = (float*)alloc((size_t)TE * 12 * 4);                     // 12.6 MB
  unsigned short* tailm = (unsigned short*)alloc((size_t)TE * 24 * 2);    // 12.6 MB
  float* agg    = (float*)alloc((size_t)NN * 512 * 4);                    // 16.8 MB (f32, += over groups)
  unsigned short* h_bf  = (unsigned short*)alloc((size_t)NN * 512 * 2);
  unsigned short* hn_bf = (unsigned short*)alloc((size_t)NN * 512 * 2);
  unsigned short* PQb   = (unsigned short*)alloc((size_t)NN * 1024 * 2);  // 16.8 MB (GGb aliases)
  unsigned short* GGb   = PQb;                                            // pass-2 alias (PQ dead)
  unsigned short* mW1pq = (unsigned short*)alloc((size_t)1024 * 512 * 2);
  unsigned short* mW1t  = (unsigned short*)alloc((size_t)17 * 512 * 2);
  unsigned short* mW2b  = (unsigned short*)alloc((size_t)512 * 512 * 2);
  unsigned short* nW1b  = (unsigned short*)alloc((size_t)512 * 1024 * 2);
  unsigned short* nW2b  = (unsigned short*)alloc((size_t)512 * 512 * 2);
  unsigned short* eGc   = (unsigned short*)alloc((size_t)1024 * 512 * 2);
  float* weab   = (float*)alloc(512 * 4);
  float* pqbias = (float*)alloc(1024 * 4);
  float* ggbias = (float*)alloc(1024 * 4);
  unsigned short* relWb = (unsigned short*)alloc((size_t)TT * 512 * 512 * 2); // 4.2 MB
  unsigned short* cW1b  = (unsigned short*)alloc((size_t)TT * 512 * 512 * 2); // 4.2 MB
  int* deg     = (int*)alloc((size_t)TT * NN * 4);
  int* offb    = (int*)alloc((size_t)TT * NN * 4);
  int* cursor  = (int*)alloc((size_t)TT * NN * 4);
  int* order   = (int*)alloc((size_t)TE * 4);
  int* rank    = (int*)alloc((size_t)TE * 4);
  int* rowS    = (int*)alloc((size_t)TE * 4);
  int* colS    = (int*)alloc((size_t)TE * 4);
  float* eaS   = (float*)alloc((size_t)TE * 4);
  float* wsumb = (float*)alloc((size_t)TE * 4 * 4);                       // 4.2 MB
  float* pnrm  = (float*)alloc((size_t)(TE / 256) * 16 * 4);
  float* nrm   = (float*)alloc((size_t)TT * 16 * 4);

  // ---- choose group size G: per-G = bufA 33.6 + bufB 33.6 + segt 8.4 + wpart 4.2 MB ----
  const size_t perG = (size_t)EE * 512 * 2 * 2 + (size_t)NN * 512 * 2 + (size_t)8 * EE * 16;
  int G = 4;
  while (G > 1 && off + (size_t)G * perG + (1 << 20) > ws_size) G >>= 1;
  unsigned short* bufA = (unsigned short*)alloc((size_t)G * EE * 512 * 2);
  unsigned short* bufB = (unsigned short*)alloc((size_t)G * EE * 512 * 2);
  unsigned short* segt = (unsigned short*)alloc((size_t)G * NN * 512 * 2);
  float* wpart = (float*)alloc((size_t)8 * G * EE * 4 * 4);               // group-local
  unsigned short* aggb = segt;    // alias: bf16 agg written after segt is dead
  float* radial = (float*)bufA;   // alias: radial f32 (16.8 MB) consumed by tails_k before bufA use

  hipMemsetAsync(deg, 0, (size_t)TT * NN * 4, stream);
  hipMemsetAsync(agg, 0, (size_t)NN * 512 * 4, stream);

  auto cvt = [&](const float* in, unsigned short* o, int n) {
    cvt_k<<<(n + 255) / 256, 256, 0, stream>>>(in, o, n);
  };
  cvt(h,    h_bf,  NN * 512);
  cvt(mW2,  mW2b,  512 * 512);
  cvt(nW1,  nW1b,  512 * 1024);
  cvt(nW2,  nW2b,  512 * 512);
  cvt(relW, relWb, TT * 512 * 512);
  cvt(cW1,  cW1b,  TT * 512 * 512);
  slicew_k<<<1024, 256, 0, stream>>>(mW1, mW1pq, 1041, 0);
  slicew_k<<<1024, 256, 0, stream>>>(mW1, mW1pq + 512 * 512, 1041, 512);
  tailw_k<<<34, 256, 0, stream>>>(mW1, mW1t);
  slicew_k<<<1024, 256, 0, stream>>>(eW1, eGc, 1025, 0);
  slicew_k<<<1024, 256, 0, stream>>>(eW1, eGc + 512 * 512, 1025, 513);
  weaw_k<<<2, 256, 0, stream>>>(eW1, weab);
  biasb_k<<<4, 256, 0, stream>>>(mb1, eb1, pqbias, ggbias);

  // sort + geometry (sorted space)
  hist_k<<<TE / 256, 256, 0, stream>>>(eidx, deg);
  scan_k<<<TT, 256, 0, stream>>>(deg, offb, cursor);
  scat_k<<<TE / 256, 256, 0, stream>>>(eidx, ea, cursor, order, rank, rowS, colS, eaS);
  cdrad_k<<<TE / 256, 256, 0, stream>>>(coord, eidx, rank, cd, radial, pnrm);
  nrmred_k<<<1, 128, 0, stream>>>(pnrm, nrm);
  tails_k<<<TE / 256, 256, 0, stream>>>(radial, nrm, eaS, tailm);

  // PQ = h @ [mW1a;mW1q]^T + [mb1;0]   (N x 1024): 512 blocks, lognx=3
  mgemm_k<<<512, 256, 0, stream>>>(AgDirect{h_bf, 512}, BgDirect{mW1pq, 512}, 512, 0, 3,
      pqbias, nullptr, nullptr, PQb, 1024, 0, nullptr, nullptr, 0);

  // -------- pass 1: batched groups of G relations --------
  for (int g = 0; g < TT / G; ++g) {
    const int tbase = g * G;
    const size_t gb = (size_t)tbase << 15;
    msg1f_k<<<(G * EE) / 16, 256, 0, stream>>>(PQb, mW1t, tailm + gb * 24,
        rowS + gb, colS + gb, bufA);
    mgemm_k<<<4 * (G * EE / 128), 256, 0, stream>>>(AgDirect{bufA, 512},
        BgDirect{mW2b, 512}, 512, tbase, 2,
        mb2, nullptr, nullptr, bufB, 512, FLAG_SILU, nullptr, nullptr, 0);
    gsum_k<<<G * NN, 256, 0, stream>>>(bufB, offb, deg, tbase, segt);
    // agg += segt @ relW[tbase..tbase+G)^T  (K = G*512, f32 accumulate)
    mgemm_k<<<4 * (NN / 128), 256, 0, stream>>>(AgSegG{segt},
        BgRelG{relWb + ((size_t)tbase << 18)}, G * 512, 0, 2,
        nullptr, agg, agg, nullptr, 512, FLAG_RES, nullptr, nullptr, 0);
    // hid = silu(msg @ cW1[t]^T + cb1[t]) -> fused w-partials into wpart
    mgemm_k<<<4 * (G * EE / 128), 256, 0, stream>>>(AgDirect{bufB, 512},
        BgPerT{cW1b}, 512, tbase, 2,
        cb1, nullptr, nullptr, nullptr, 512, FLAG_SILU | FLAG_WEPI | FLAG_BIAS_T,
        cW2, wpart, G * EE);
    wsum_k<<<(G * EE) / 256, 256, 0, stream>>>(wpart, wsumb + gb * 4, G * EE);
  }

  // fused trans-reduce + x_new (no atomics)
  trxn_k<<<(NN * 12) / 256, 256, 0, stream>>>(coord, cd, wsumb, offb, deg, out_x);

  // -------- node MLP + residual -> h_new --------
  cvt(agg, aggb, NN * 512);
  mgemm_k<<<4 * (NN / 128), 256, 0, stream>>>(AgHcat{h_bf, aggb}, BgDirect{nW1b, 1024}, 1024, 0, 2,
      nb1, nullptr, nullptr, bufA, 512, FLAG_SILU, nullptr, nullptr, 0);
  mgemm_k<<<4 * (NN / 128), 256, 0, stream>>>(AgDirect{bufA, 512}, BgDirect{nW2b, 512}, 512, 0, 2,
      nb2, h, out_h, hn_bf, 512, FLAG_RES, nullptr, nullptr, 0);

  // -------- pass 2: GG = hn @ [eW1a;eW1c]^T + [eb1;0] ; fused m (per-edge) --------
  mgemm_k<<<512, 256, 0, stream>>>(AgDirect{hn_bf, 512}, BgDirect{eGc, 512}, 512, 0, 3,
      ggbias, nullptr, nullptr, GGb, 1024, 0, nullptr, nullptr, 0);
  mout_k<<<TE / 4, 256, 0, stream>>>(GGb, eW2, weab, eb2, eaS, rowS, colS, order, out_m);

  (void)in_sizes; (void)n_in; (void)out_size; (void)ws_size;
}

// Round 12
// 1404.539 us; speedup vs baseline: 1.5019x; 1.0202x over previous
//
#include <hip/hip_runtime.h>
#include <cstdint>

#define NN 8192
#define DD 512
#define CC 4
#define TT 8
#define EE 32768
#define TE (TT*EE)

typedef __attribute__((ext_vector_type(8))) short short8v;
typedef __attribute__((ext_vector_type(4))) float f32x4;
typedef unsigned int uint;

constexpr int FLAG_SILU = 1, FLAG_RES = 2, FLAG_WEPI = 4, FLAG_BIAS_T = 8;

__device__ __forceinline__ float silu_f(float x) { return x / (1.f + __expf(-x)); }

__device__ __forceinline__ unsigned short f2bf(float f) {
  uint u = __builtin_bit_cast(uint, f);
  u += 0x7fffu + ((u >> 16) & 1u);
  return (unsigned short)(u >> 16);
}
__device__ __forceinline__ float bf2f(unsigned short b) {
  uint u = ((uint)b) << 16;
  return __builtin_bit_cast(float, u);
}
__device__ __forceinline__ float bflo(uint u) { return __builtin_bit_cast(float, u << 16); }
__device__ __forceinline__ float bfhi(uint u) { return __builtin_bit_cast(float, u & 0xffff0000u); }
__device__ __forceinline__ uint packbf(float a, float b) {
  return (uint)f2bf(a) | ((uint)f2bf(b) << 16);
}

__device__ __forceinline__ float wave_sum(float v) {
#pragma unroll
  for (int off = 32; off; off >>= 1) v += __shfl_xor(v, off);
  return v;
}

__device__ __forceinline__ void gload16(const void* g, void* l) {
  __builtin_amdgcn_global_load_lds(
      (const __attribute__((address_space(1))) void*)g,
      (__attribute__((address_space(3))) void*)l, 16, 0, 0);
}

// chunked XCD swizzle: logical index from launched blockIdx (nwg % 8 == 0)
__device__ __forceinline__ int xcd_swz(int i, int nwg) {
  return (i & 7) * (nwg >> 3) + (i >> 3);
}

// ---------------- gather functors ----------------
struct AgDirect { const unsigned short* p; int K;
  __device__ const void* ptr(int m, int k, int) const { return p + (size_t)m * K + k; } };

struct AgHcat { const unsigned short* hb; const unsigned short* ab;
  __device__ const void* ptr(int m, int k, int) const {
    return (k < 512) ? (const void*)(hb + ((size_t)m << 9) + k)
                     : (const void*)(ab + ((size_t)m << 9) + (k - 512)); } };

struct AgSegG { const unsigned short* seg;
  __device__ const void* ptr(int m, int k, int) const {
    return seg + (((size_t)(k >> 9) * NN + m) << 9) + (k & 511); } };

struct BgDirect { const unsigned short* p; int K;
  __device__ const void* ptr(int o, int k, int) const { return p + (size_t)o * K + k; } };

struct BgRelG { const unsigned short* w;
  __device__ const void* ptr(int o, int k, int) const {
    return w + (((size_t)(k >> 9) * 512 + o) << 9) + (k & 511); } };

struct BgPerT { const unsigned short* w;
  __device__ const void* ptr(int o, int k, int tt) const {
    return w + (((size_t)tt << 18) + ((size_t)o << 9)) + k; } };

// ------- bf16 MFMA GEMM, 128x128 tile, 4 waves (small/node GEMMs) -------
template<class AG, class BG>
__global__ __launch_bounds__(256)
void mgemm_k(AG ag, BG bg, int K, int tbase, int lognx,
             const float* __restrict__ bias, const float* __restrict__ res,
             float* __restrict__ outF, unsigned short* __restrict__ outB, int ldo, int flags)
{
  __shared__ __align__(16) unsigned short SM[128 * 136];
  unsigned short* As = SM;
  unsigned short* Bs = SM + 128 * 64;
  const int swz = xcd_swz(blockIdx.x, gridDim.x);
  const int xb = swz & ((1 << lognx) - 1), yb = swz >> lognx;
  const int m0 = yb * 128, o0 = xb * 128;
  const int tt = tbase + (m0 >> 15);
  const int tid = threadIdx.x, wave = tid >> 6, lane = tid & 63;
  const int wr = (wave >> 1) * 64, wc = (wave & 1) * 64;
  const int rs = lane >> 3, sl = lane & 7;

  f32x4 acc[4][4];
#pragma unroll
  for (int i = 0; i < 4; ++i)
#pragma unroll
    for (int j = 0; j < 4; ++j) acc[i][j] = (f32x4)0.f;

  for (int k0 = 0; k0 < K; k0 += 64) {
#pragma unroll
    for (int i = 0; i < 4; ++i) {
      int r = i * 32 + wave * 8 + rs;
      int slot = sl ^ (r & 7);
      gload16(ag.ptr(m0 + r, k0 + slot * 8, tt), &As[(i * 32 + wave * 8) * 64]);
    }
#pragma unroll
    for (int i = 0; i < 4; ++i) {
      int r = i * 32 + wave * 8 + rs;
      int slot = sl ^ (r & 7);
      gload16(bg.ptr(o0 + r, k0 + slot * 8, tt), &Bs[(i * 32 + wave * 8) * 64]);
    }
    __syncthreads();
    short8v a[4][2], b[4][2];
#pragma unroll
    for (int mi = 0; mi < 4; ++mi)
#pragma unroll
      for (int s = 0; s < 2; ++s) {
        int row = wr + mi * 16 + (lane & 15);
        int slot = (s * 4 + (lane >> 4)) ^ (row & 7);
        a[mi][s] = *(const short8v*)&As[row * 64 + slot * 8];
      }
#pragma unroll
    for (int ni = 0; ni < 4; ++ni)
#pragma unroll
      for (int s = 0; s < 2; ++s) {
        int row = wc + ni * 16 + (lane & 15);
        int slot = (s * 4 + (lane >> 4)) ^ (row & 7);
        b[ni][s] = *(const short8v*)&Bs[row * 64 + slot * 8];
      }
#pragma unroll
    for (int s = 0; s < 2; ++s)
#pragma unroll
      for (int mi = 0; mi < 4; ++mi)
#pragma unroll
        for (int ni = 0; ni < 4; ++ni)
          acc[mi][ni] = __builtin_amdgcn_mfma_f32_16x16x32_bf16(a[mi][s], b[ni][s], acc[mi][ni], 0, 0, 0);
    __syncthreads();
  }

  const int r4 = (lane >> 4) * 4, cl = lane & 15;
  if (outB && !outF) {
    unsigned short* Ep = SM;
#pragma unroll
    for (int mi = 0; mi < 4; ++mi)
#pragma unroll
      for (int ni = 0; ni < 4; ++ni)
#pragma unroll
        for (int rg = 0; rg < 4; ++rg) {
          int row = wr + mi * 16 + r4 + rg;
          int col = wc + ni * 16 + cl;
          float v = acc[mi][ni][rg];
          if (bias) v += (flags & FLAG_BIAS_T) ? bias[tt * 512 + o0 + col] : bias[o0 + col];
          if (flags & FLAG_SILU) v = silu_f(v);
          Ep[row * 136 + col] = f2bf(v);
        }
    __syncthreads();
#pragma unroll
    for (int p = 0; p < 8; ++p) {
      int idx = p * 256 + tid;
      int row = idx >> 4, ch = idx & 15;
      short8v vv = *(const short8v*)&Ep[row * 136 + ch * 8];
      *(short8v*)(outB + (size_t)(m0 + row) * ldo + o0 + ch * 8) = vv;
    }
    return;
  }
#pragma unroll
  for (int mi = 0; mi < 4; ++mi)
#pragma unroll
    for (int ni = 0; ni < 4; ++ni)
#pragma unroll
      for (int rg = 0; rg < 4; ++rg) {
        int row = m0 + wr + mi * 16 + r4 + rg;
        int col = o0 + wc + ni * 16 + cl;
        float v = acc[mi][ni][rg];
        if (bias) v += (flags & FLAG_BIAS_T) ? bias[tt * 512 + col] : bias[col];
        if (flags & FLAG_SILU) v = silu_f(v);
        if (flags & FLAG_RES) v += res[(size_t)row * ldo + col];
        if (outF) outF[(size_t)row * ldo + col] = v;
        if (outB) outB[(size_t)row * ldo + col] = f2bf(v);
      }
}

// ------- bf16 MFMA GEMM, 256x128 tile, 8 waves (big edge GEMMs; N=512, lognx=2) -------
template<class AG, class BG>
__global__ __launch_bounds__(512)
void mgemm2_k(AG ag, BG bg, int K, int tbase,
              const float* __restrict__ bias,
              unsigned short* __restrict__ outB, int flags,
              const float* __restrict__ cw2, float* __restrict__ wpart, int wstride)
{
  __shared__ __align__(16) unsigned short SM[(256 + 128) * 64];   // A 256x64 | B 128x64 (48KB)
  unsigned short* As = SM;
  unsigned short* Bs = SM + 256 * 64;
  const int swz = xcd_swz(blockIdx.x, gridDim.x);
  const int xb = swz & 3, yb = swz >> 2;
  const int m0 = yb * 256, o0 = xb * 128;
  const int tt = tbase + (m0 >> 15);
  const int tid = threadIdx.x, wave = tid >> 6, lane = tid & 63;
  const int wr = (wave >> 1) * 64, wc = (wave & 1) * 64;   // wr in 0..192, wc in 0..64
  const int rs = lane >> 3, sl = lane & 7;

  f32x4 acc[4][4];
#pragma unroll
  for (int i = 0; i < 4; ++i)
#pragma unroll
    for (int j = 0; j < 4; ++j) acc[i][j] = (f32x4)0.f;

  for (int k0 = 0; k0 < K; k0 += 64) {
#pragma unroll
    for (int i = 0; i < 4; ++i) {                  // A: 256 rows by 8 waves
      int r = i * 64 + wave * 8 + rs;
      int slot = sl ^ (r & 7);
      gload16(ag.ptr(m0 + r, k0 + slot * 8, tt), &As[(i * 64 + wave * 8) * 64]);
    }
#pragma unroll
    for (int i = 0; i < 2; ++i) {                  // B: 128 rows by 8 waves
      int r = i * 64 + wave * 8 + rs;
      int slot = sl ^ (r & 7);
      gload16(bg.ptr(o0 + r, k0 + slot * 8, tt), &Bs[(i * 64 + wave * 8) * 64]);
    }
    __syncthreads();
    short8v a[4][2], b[4][2];
#pragma unroll
    for (int mi = 0; mi < 4; ++mi)
#pragma unroll
      for (int s = 0; s < 2; ++s) {
        int row = wr + mi * 16 + (lane & 15);
        int slot = (s * 4 + (lane >> 4)) ^ (row & 7);
        a[mi][s] = *(const short8v*)&As[row * 64 + slot * 8];
      }
#pragma unroll
    for (int ni = 0; ni < 4; ++ni)
#pragma unroll
      for (int s = 0; s < 2; ++s) {
        int row = wc + ni * 16 + (lane & 15);
        int slot = (s * 4 + (lane >> 4)) ^ (row & 7);
        b[ni][s] = *(const short8v*)&Bs[row * 64 + slot * 8];
      }
#pragma unroll
    for (int s = 0; s < 2; ++s)
#pragma unroll
      for (int mi = 0; mi < 4; ++mi)
#pragma unroll
        for (int ni = 0; ni < 4; ++ni)
          acc[mi][ni] = __builtin_amdgcn_mfma_f32_16x16x32_bf16(a[mi][s], b[ni][s], acc[mi][ni], 0, 0, 0);
    __syncthreads();
  }

  const int r4 = (lane >> 4) * 4, cl = lane & 15;
  if (flags & FLAG_WEPI) {
    const int slice = xb * 2 + (wave & 1);
    const float* cw2t = cw2 + tt * 2048;
    const float* bt = bias + tt * 512;
#pragma unroll
    for (int mi = 0; mi < 4; ++mi) {
      float sc[4][4];
#pragma unroll
      for (int rg = 0; rg < 4; ++rg)
#pragma unroll
        for (int c = 0; c < 4; ++c) sc[rg][c] = 0.f;
#pragma unroll
      for (int ni = 0; ni < 4; ++ni) {
        int col = o0 + wc + ni * 16 + cl;
        float c0 = cw2t[col], c1 = cw2t[512 + col], c2 = cw2t[1024 + col], c3 = cw2t[1536 + col];
        float bb = bt[col];
#pragma unroll
        for (int rg = 0; rg < 4; ++rg) {
          float v = silu_f(acc[mi][ni][rg] + bb);
          sc[rg][0] += v * c0; sc[rg][1] += v * c1; sc[rg][2] += v * c2; sc[rg][3] += v * c3;
        }
      }
#pragma unroll
      for (int rg = 0; rg < 4; ++rg)
#pragma unroll
        for (int c = 0; c < 4; ++c) {
          float s = sc[rg][c];
          s += __shfl_xor(s, 1); s += __shfl_xor(s, 2);
          s += __shfl_xor(s, 4); s += __shfl_xor(s, 8);
          sc[rg][c] = s;
        }
      if (cl == 0) {
        int p = m0 + wr + mi * 16 + r4;
#pragma unroll
        for (int rg = 0; rg < 4; ++rg) {
          float4 o = make_float4(sc[rg][0], sc[rg][1], sc[rg][2], sc[rg][3]);
          *(float4*)&wpart[(((size_t)slice * wstride) + p + rg) * 4] = o;
        }
      }
    }
    return;
  }
  // bf16 vectorized epilogue in two 128-row halves (reuse staging LDS, stride 136)
  unsigned short* Ep = SM;
#pragma unroll
  for (int hh = 0; hh < 2; ++hh) {
    if ((wr >> 7) == hh) {
#pragma unroll
      for (int mi = 0; mi < 4; ++mi)
#pragma unroll
        for (int ni = 0; ni < 4; ++ni)
#pragma unroll
          for (int rg = 0; rg < 4; ++rg) {
            int row = (wr & 127) + mi * 16 + r4 + rg;
            int col = wc + ni * 16 + cl;
            float v = acc[mi][ni][rg];
            v += bias[o0 + col];
            if (flags & FLAG_SILU) v = silu_f(v);
            Ep[row * 136 + col] = f2bf(v);
          }
    }
    __syncthreads();
#pragma unroll
    for (int p = 0; p < 4; ++p) {
      int idx = p * 512 + tid;
      int row = idx >> 4, ch = idx & 15;
      short8v vv = *(const short8v*)&Ep[row * 136 + ch * 8];
      *(short8v*)(outB + (size_t)(m0 + hh * 128 + row) * 512 + o0 + ch * 8) = vv;
    }
    __syncthreads();
  }
}

// ---------------- prep kernels ----------------
__global__ __launch_bounds__(256)
void cvtall_k(const float* h, const float* mW2, const float* nW1, const float* nW2,
              const float* relW, const float* cW1,
              unsigned short* hb, unsigned short* mW2b, unsigned short* nW1b,
              unsigned short* nW2b, unsigned short* relWb, unsigned short* cW1b)
{
  int i = blockIdx.x * 256 + threadIdx.x;    // < 9437184
  if (i < 4194304) { hb[i] = f2bf(h[i]); return; }
  i -= 4194304;
  if (i < 262144) { mW2b[i] = f2bf(mW2[i]); return; }
  i -= 262144;
  if (i < 524288) { nW1b[i] = f2bf(nW1[i]); return; }
  i -= 524288;
  if (i < 262144) { nW2b[i] = f2bf(nW2[i]); return; }
  i -= 262144;
  if (i < 2097152) { relWb[i] = f2bf(relW[i]); return; }
  i -= 2097152;
  cW1b[i] = f2bf(cW1[i]);
}

__global__ __launch_bounds__(256)
void cvt_k(const float* __restrict__ in, unsigned short* __restrict__ out, int n) {
  int i = blockIdx.x * 256 + threadIdx.x;
  if (i < n) out[i] = f2bf(in[i]);
}

__global__ __launch_bounds__(256)
void slicew_k(const float* __restrict__ w, unsigned short* __restrict__ o, int Kin, int col0) {
  int i = blockIdx.x * 256 + threadIdx.x;
  int r = i >> 9, k = i & 511;
  o[i] = f2bf(w[(size_t)r * Kin + col0 + k]);
}

__global__ __launch_bounds__(256)
void tailw_k(const float* __restrict__ mW1, unsigned short* __restrict__ o) {
  int i = blockIdx.x * 256 + threadIdx.x;
  if (i >= 17 * 512) return;
  int j = i >> 9, c = i & 511;
  o[i] = f2bf(mW1[(size_t)c * 1041 + 1024 + j]);
}

__global__ __launch_bounds__(256)
void weaw_k(const float* __restrict__ eW1, float* __restrict__ wea) {
  int i = blockIdx.x * 256 + threadIdx.x;
  if (i < 512) wea[i] = eW1[(size_t)i * 1025 + 512];
}

__global__ __launch_bounds__(256)
void biasb_k(const float* __restrict__ mb1, const float* __restrict__ eb1,
             float* __restrict__ pqb, float* __restrict__ ggb) {
  int i = blockIdx.x * 256 + threadIdx.x;
  if (i < 1024) {
    pqb[i] = (i < 512) ? mb1[i] : 0.f;
    ggb[i] = (i < 512) ? eb1[i] : 0.f;
  }
}

// ---------------- counting sort ----------------
__global__ __launch_bounds__(256)
void hist_k(const int* __restrict__ eidx, int* __restrict__ deg) {
  int id = blockIdx.x * 256 + threadIdx.x;
  int t = id >> 15, e = id & (EE - 1);
  atomicAdd(&deg[(t << 13) + eidx[(t << 16) + e]], 1);
}

__global__ __launch_bounds__(256)
void scan_k(const int* __restrict__ deg, int* __restrict__ off, int* __restrict__ cursor) {
  int t = blockIdx.x, tid = threadIdx.x;
  __shared__ int lds[256];
  int base = 0;
  for (int ch = 0; ch < 32; ++ch) {
    int i = ch * 256 + tid;
    int v = deg[(t << 13) + i];
    __syncthreads();
    lds[tid] = v;
    __syncthreads();
    for (int s = 1; s < 256; s <<= 1) {
      int x = (tid >= s) ? lds[tid - s] : 0;
      __syncthreads();
      if (tid >= s) lds[tid] += x;
      __syncthreads();
    }
    int excl = base + lds[tid] - v;
    off[(t << 13) + i] = excl;
    cursor[(t << 13) + i] = excl;
    base += lds[255];
  }
}

// ------ merged scatter + cd/radial at sorted positions + per-block sq partials ------
__global__ __launch_bounds__(256)
void scatcd_k(const int* __restrict__ eidx, const float* __restrict__ ea,
              const float* __restrict__ coord, int* __restrict__ cursor,
              int* __restrict__ order, int* __restrict__ rowS, int* __restrict__ colS,
              float* __restrict__ eaS, float* __restrict__ cd,
              float* __restrict__ radial, float* __restrict__ pnrm)
{
  int m = blockIdx.x * 256 + threadIdx.x;          // < TE (original order)
  int t = m >> 15, e = m & (EE - 1);
  int r = eidx[(t << 16) + e], c = eidx[(t << 16) + EE + e];
  int pos = atomicAdd(&cursor[(t << 13) + r], 1);
  size_t s = ((size_t)t << 15) + pos;
  order[s] = e; rowS[s] = r; colS[s] = c; eaS[s] = ea[m];
  const float4* cv4 = (const float4*)coord;
  float4 A0 = cv4[r * 3], A1 = cv4[r * 3 + 1], A2 = cv4[r * 3 + 2];
  float4 B0 = cv4[c * 3], B1 = cv4[c * 3 + 1], B2 = cv4[c * 3 + 2];
  float d[12] = {A0.x-B0.x, A0.y-B0.y, A0.z-B0.z, A0.w-B0.w,
                 A1.x-B1.x, A1.y-B1.y, A1.z-B1.z, A1.w-B1.w,
                 A2.x-B2.x, A2.y-B2.y, A2.z-B2.z, A2.w-B2.w};
  float4* cdv = (float4*)cd;
  cdv[s*3+0] = make_float4(d[0],d[1],d[2],d[3]);
  cdv[s*3+1] = make_float4(d[4],d[5],d[6],d[7]);
  cdv[s*3+2] = make_float4(d[8],d[9],d[10],d[11]);
  float rad[16], sq[16];
#pragma unroll
  for (int ci = 0; ci < 4; ++ci)
#pragma unroll
    for (int di = 0; di < 4; ++di) {
      float v = d[ci*3]*d[di*3] + d[ci*3+1]*d[di*3+1] + d[ci*3+2]*d[di*3+2];
      rad[ci*4+di] = v; sq[ci*4+di] = v * v;
    }
  float4* rv = (float4*)radial;
#pragma unroll
  for (int i = 0; i < 4; ++i)
    rv[s*4+i] = make_float4(rad[i*4], rad[i*4+1], rad[i*4+2], rad[i*4+3]);
#pragma unroll
  for (int i = 0; i < 16; ++i) sq[i] = wave_sum(sq[i]);
  __shared__ float red[4][16];
  int wv = threadIdx.x >> 6, lane = threadIdx.x & 63;
  if (lane == 0) {
#pragma unroll
    for (int i = 0; i < 16; ++i) red[wv][i] = sq[i];
  }
  __syncthreads();
  if (threadIdx.x < 16)
    pnrm[blockIdx.x * 16 + threadIdx.x] =
        red[0][threadIdx.x] + red[1][threadIdx.x] + red[2][threadIdx.x] + red[3][threadIdx.x];
}

__global__ __launch_bounds__(128)
void nrmred_k(const float* __restrict__ pnrm, float* __restrict__ nrm) {
  int t = threadIdx.x >> 4, j = threadIdx.x & 15;
  float s = 0.f;
  for (int b = 0; b < 128; ++b) s += pnrm[((t * 128 + b) << 4) + j];
  nrm[(t << 4) + j] = s;
}

__global__ __launch_bounds__(256)
void tails_k(const float* __restrict__ radial, const float* __restrict__ nrm,
             const float* __restrict__ eaS, unsigned short* __restrict__ tailm)
{
  int m = blockIdx.x * 256 + threadIdx.x;
  int t = m >> 15;
  unsigned short tmp[24];
#pragma unroll
  for (int j = 0; j < 16; ++j) {
    float r = radial[(size_t)m * 16 + j] / fmaxf(sqrtf(nrm[(t << 4) + j]), 1e-12f);
    tmp[j] = f2bf(r);
  }
  tmp[16] = f2bf(eaS[m]);
#pragma unroll
  for (int j = 17; j < 24; ++j) tmp[j] = 0;
  uint4* dst = (uint4*)(tailm + (size_t)m * 24);
  dst[0] = ((const uint4*)tmp)[0];
  dst[1] = ((const uint4*)tmp)[1];
  dst[2] = ((const uint4*)tmp)[2];
}

// ---------------- fused msg1 (sorted, XCD-swizzled) ----------------
__global__ __launch_bounds__(256)
void msg1f_k(const unsigned short* __restrict__ PQ, const unsigned short* __restrict__ Wt,
             const unsigned short* __restrict__ tailm_g,
             const int* __restrict__ rowS_g, const int* __restrict__ colS_g,
             unsigned short* __restrict__ out)
{
  int tid = threadIdx.x;
  int e0 = xcd_swz(blockIdx.x, gridDim.x) * 16;
  uint wreg[17];
#pragma unroll
  for (int j = 0; j < 17; ++j) wreg[j] = *(const uint*)(Wt + j * 512 + tid * 2);
  for (int i = 0; i < 16; ++i) {
    int p = e0 + i;
    int r = rowS_g[p], c = colS_g[p];
    uint pv = *(const uint*)(PQ + ((size_t)r << 10) + tid * 2);
    uint qv = *(const uint*)(PQ + ((size_t)c << 10) + 512 + tid * 2);
    uint4 t0 = *(const uint4*)(tailm_g + (size_t)p * 24);
    uint4 t1 = *(const uint4*)(tailm_g + (size_t)p * 24 + 8);
    uint  t2 = *(const uint*)(tailm_g + (size_t)p * 24 + 16);
    float tl[17] = {bflo(t0.x), bfhi(t0.x), bflo(t0.y), bfhi(t0.y),
                    bflo(t0.z), bfhi(t0.z), bflo(t0.w), bfhi(t0.w),
                    bflo(t1.x), bfhi(t1.x), bflo(t1.y), bfhi(t1.y),
                    bflo(t1.z), bfhi(t1.z), bflo(t1.w), bfhi(t1.w),
                    bflo(t2)};
    float s0 = bflo(pv) + bflo(qv);
    float s1 = bfhi(pv) + bfhi(qv);
#pragma unroll
    for (int j = 0; j < 17; ++j) {
      s0 += tl[j] * bflo(wreg[j]); s1 += tl[j] * bfhi(wreg[j]);
    }
    *(uint*)(out + ((size_t)p << 9) + tid * 2) = packbf(silu_f(s0), silu_f(s1));
  }
}

// gather-sum (sorted, sequential, XCD-swizzled)
__global__ __launch_bounds__(256)
void gsum_k(const unsigned short* __restrict__ msg, const int* __restrict__ offb,
            const int* __restrict__ deg, int tbase, unsigned short* __restrict__ segt)
{
  int l = xcd_swz(blockIdx.x, gridDim.x);
  int tloc = l >> 13, n = l & (NN - 1), tid = threadIdx.x;
  int t = tbase + tloc;
  int start = offb[(t << 13) + n], d = deg[(t << 13) + n];
  float s0 = 0.f, s1 = 0.f;
  const unsigned short* base = msg + (((size_t)tloc << 15) << 9);
  for (int j = 0; j < d; ++j) {
    uint v = *(const uint*)(base + ((size_t)(start + j) << 9) + tid * 2);
    s0 += bflo(v); s1 += bfhi(v);
  }
  *(uint*)(segt + (((size_t)tloc * NN + n) << 9) + tid * 2) = packbf(s0, s1);
}

__global__ __launch_bounds__(256)
void wsum_k(const float* __restrict__ wpart, float* __restrict__ wsum_out, int wstride) {
  int id = xcd_swz(blockIdx.x, gridDim.x) * 256 + threadIdx.x;
  float4 a = (float4){0.f, 0.f, 0.f, 0.f};
#pragma unroll
  for (int s = 0; s < 8; ++s) {
    float4 v = *(const float4*)&wpart[(((size_t)s * wstride) + id) * 4];
    a.x += v.x; a.y += v.y; a.z += v.z; a.w += v.w;
  }
  *(float4*)&wsum_out[(size_t)id * 4] = a;
}

__global__ __launch_bounds__(256)
void trxn_k(const float* __restrict__ coord, const float* __restrict__ cd,
            const float* __restrict__ wsum, const int* __restrict__ offb,
            const int* __restrict__ deg, float* __restrict__ xout)
{
  int id = blockIdx.x * 256 + threadIdx.x;
  int n = id / 12, j = id - n * 12, ci = j / 3;
  float s = 0.f; int cnt = 0;
#pragma unroll
  for (int t = 0; t < 8; ++t) {
    int o = offb[(t << 13) + n], d = deg[(t << 13) + n];
    size_t p = ((size_t)t << 15) + o;
    for (int k = 0; k < d; ++k)
      s += cd[(p + k) * 12 + j] * wsum[(p + k) * 4 + ci];
    cnt += d;
  }
  xout[id] = coord[id] + s / fmaxf((float)cnt, 1.f);
}

// ------ batched m output (sorted, per-edge wave, XCD-swizzled) ------
__global__ __launch_bounds__(256)
void mout_k(const unsigned short* __restrict__ GG,
            const float* __restrict__ eW2, const float* __restrict__ wea,
            const float* __restrict__ eb2, const float* __restrict__ eaS,
            const int* __restrict__ rowS, const int* __restrict__ colS,
            const int* __restrict__ order, float* __restrict__ out_m)
{
  int wid = xcd_swz(blockIdx.x, gridDim.x) * 4 + (threadIdx.x >> 6);
  int lane = threadIdx.x & 63;
  int t = wid >> 15;
  int r = rowS[wid], c = colS[wid];
  float eav = eaS[wid];
  short8v gv  = *(const short8v*)(GG + ((size_t)r << 10) + lane * 8);
  short8v gcv = *(const short8v*)(GG + ((size_t)c << 10) + 512 + lane * 8);
  const float4* w4 = (const float4*)(eW2 + lane * 8);
  const float4* a4 = (const float4*)(wea + lane * 8);
  float4 w0 = w4[0], w1 = w4[1], a0 = a4[0], a1 = a4[1];
  float wv8[8] = {w0.x,w0.y,w0.z,w0.w,w1.x,w1.y,w1.z,w1.w};
  float av8[8] = {a0.x,a0.y,a0.z,a0.w,a1.x,a1.y,a1.z,a1.w};
  float s = 0.f;
#pragma unroll
  for (int j = 0; j < 8; ++j)
    s += wv8[j] * silu_f(bf2f((unsigned short)gv[j]) + bf2f((unsigned short)gcv[j]) + eav * av8[j]);
  s = wave_sum(s);
  if (lane == 0) out_m[((size_t)t << 15) + order[wid]] = s + eb2[0];
}

// ---------------- launch ----------------
extern "C" void kernel_launch(void* const* d_in, const int* in_sizes, int n_in,
                              void* d_out, int out_size, void* d_ws, size_t ws_size,
                              hipStream_t stream)
{
  const float* h     = (const float*)d_in[0];
  const float* coord = (const float*)d_in[1];
  const float* ea    = (const float*)d_in[2];
  const int*   eidx  = (const int*)  d_in[3];
  const float* mW1   = (const float*)d_in[4];
  const float* mb1   = (const float*)d_in[5];
  const float* mW2   = (const float*)d_in[6];
  const float* mb2   = (const float*)d_in[7];
  const float* nW1   = (const float*)d_in[8];
  const float* nb1   = (const float*)d_in[9];
  const float* nW2   = (const float*)d_in[10];
  const float* nb2   = (const float*)d_in[11];
  const float* eW1   = (const float*)d_in[12];
  const float* eb1   = (const float*)d_in[13];
  const float* eW2   = (const float*)d_in[14];
  const float* eb2   = (const float*)d_in[15];
  const float* relW  = (const float*)d_in[16];
  const float* cW1   = (const float*)d_in[17];
  const float* cb1   = (const float*)d_in[18];
  const float* cW2   = (const float*)d_in[19];

  float* out   = (float*)d_out;
  float* out_h = out;
  float* out_x = out + (size_t)NN * DD;
  float* out_m = out_x + (size_t)NN * CC * 3;

  char* ws = (char*)d_ws;
  size_t off = 0;
  auto alloc = [&](size_t bytes) -> void* {
    void* p = ws + off; off += (bytes + 255) & ~(size_t)255; return p;
  };
  float* cd     = (float*)alloc((size_t)TE * 12 * 4);
  unsigned short* tailm = (unsigned short*)alloc((size_t)TE * 24 * 2);
  float* agg    = (float*)alloc((size_t)NN * 512 * 4);
  unsigned short* h_bf  = (unsigned short*)alloc((size_t)NN * 512 * 2);
  unsigned short* hn_bf = (unsigned short*)alloc((size_t)NN * 512 * 2);
  unsigned short* PQb   = (unsigned short*)alloc((size_t)NN * 1024 * 2);
  unsigned short* GGb   = PQb;
  unsigned short* mW1pq = (unsigned short*)alloc((size_t)1024 * 512 * 2);
  unsigned short* mW1t  = (unsigned short*)alloc((size_t)17 * 512 * 2);
  unsigned short* mW2b  = (unsigned short*)alloc((size_t)512 * 512 * 2);
  unsigned short* nW1b  = (unsigned short*)alloc((size_t)512 * 1024 * 2);
  unsigned short* nW2b  = (unsigned short*)alloc((size_t)512 * 512 * 2);
  unsigned short* eGc   = (unsigned short*)alloc((size_t)1024 * 512 * 2);
  float* weab   = (float*)alloc(512 * 4);
  float* pqbias = (float*)alloc(1024 * 4);
  float* ggbias = (float*)alloc(1024 * 4);
  unsigned short* relWb = (unsigned short*)alloc((size_t)TT * 512 * 512 * 2);
  unsigned short* cW1b  = (unsigned short*)alloc((size_t)TT * 512 * 512 * 2);
  int* deg     = (int*)alloc((size_t)TT * NN * 4);
  int* offb    = (int*)alloc((size_t)TT * NN * 4);
  int* cursor  = (int*)alloc((size_t)TT * NN * 4);
  int* order   = (int*)alloc((size_t)TE * 4);
  int* rowS    = (int*)alloc((size_t)TE * 4);
  int* colS    = (int*)alloc((size_t)TE * 4);
  float* eaS   = (float*)alloc((size_t)TE * 4);
  float* wsumb = (float*)alloc((size_t)TE * 4 * 4);
  float* pnrm  = (float*)alloc((size_t)(TE / 256) * 16 * 4);
  float* nrm   = (float*)alloc((size_t)TT * 16 * 4);

  const size_t perG = (size_t)EE * 512 * 2 * 2 + (size_t)NN * 512 * 2 + (size_t)8 * EE * 16;
  int G = 4;
  while (G > 1 && off + (size_t)G * perG + (1 << 20) > ws_size) G >>= 1;
  unsigned short* bufA = (unsigned short*)alloc((size_t)G * EE * 512 * 2);
  unsigned short* bufB = (unsigned short*)alloc((size_t)G * EE * 512 * 2);
  unsigned short* segt = (unsigned short*)alloc((size_t)G * NN * 512 * 2);
  float* wpart = (float*)alloc((size_t)8 * G * EE * 4 * 4);
  unsigned short* aggb = segt;
  float* radial = (float*)bufA;

  hipMemsetAsync(deg, 0, (size_t)TT * NN * 4, stream);
  hipMemsetAsync(agg, 0, (size_t)NN * 512 * 4, stream);

  // prep (batched cvt + weight slices)
  cvtall_k<<<9437184 / 256, 256, 0, stream>>>(h, mW2, nW1, nW2, relW, cW1,
      h_bf, mW2b, nW1b, nW2b, relWb, cW1b);
  slicew_k<<<1024, 256, 0, stream>>>(mW1, mW1pq, 1041, 0);
  slicew_k<<<1024, 256, 0, stream>>>(mW1, mW1pq + 512 * 512, 1041, 512);
  tailw_k<<<34, 256, 0, stream>>>(mW1, mW1t);
  slicew_k<<<1024, 256, 0, stream>>>(eW1, eGc, 1025, 0);
  slicew_k<<<1024, 256, 0, stream>>>(eW1, eGc + 512 * 512, 1025, 513);
  weaw_k<<<2, 256, 0, stream>>>(eW1, weab);
  biasb_k<<<4, 256, 0, stream>>>(mb1, eb1, pqbias, ggbias);

  // sort + geometry (merged scatter+cd)
  hist_k<<<TE / 256, 256, 0, stream>>>(eidx, deg);
  scan_k<<<TT, 256, 0, stream>>>(deg, offb, cursor);
  scatcd_k<<<TE / 256, 256, 0, stream>>>(eidx, ea, coord, cursor,
      order, rowS, colS, eaS, cd, radial, pnrm);
  nrmred_k<<<1, 128, 0, stream>>>(pnrm, nrm);
  tails_k<<<TE / 256, 256, 0, stream>>>(radial, nrm, eaS, tailm);

  // PQ = h @ [mW1a;mW1q]^T + [mb1;0]
  mgemm_k<<<512, 256, 0, stream>>>(AgDirect{h_bf, 512}, BgDirect{mW1pq, 512}, 512, 0, 3,
      pqbias, nullptr, nullptr, PQb, 1024, 0);

  // -------- pass 1: batched groups of G relations --------
  for (int g = 0; g < TT / G; ++g) {
    const int tbase = g * G;
    const size_t gb = (size_t)tbase << 15;
    msg1f_k<<<(G * EE) / 16, 256, 0, stream>>>(PQb, mW1t, tailm + gb * 24,
        rowS + gb, colS + gb, bufA);
    mgemm2_k<<<4 * (G * EE / 256), 512, 0, stream>>>(AgDirect{bufA, 512},
        BgDirect{mW2b, 512}, 512, tbase,
        mb2, bufB, FLAG_SILU, nullptr, nullptr, 0);
    gsum_k<<<G * NN, 256, 0, stream>>>(bufB, offb, deg, tbase, segt);
    mgemm_k<<<4 * (NN / 128), 256, 0, stream>>>(AgSegG{segt},
        BgRelG{relWb + ((size_t)tbase << 18)}, G * 512, 0, 2,
        nullptr, agg, agg, nullptr, 512, FLAG_RES);
    mgemm2_k<<<4 * (G * EE / 256), 512, 0, stream>>>(AgDirect{bufB, 512},
        BgPerT{cW1b}, 512, tbase,
        cb1, nullptr, FLAG_SILU | FLAG_WEPI | FLAG_BIAS_T, cW2, wpart, G * EE);
    wsum_k<<<(G * EE) / 256, 256, 0, stream>>>(wpart, wsumb + gb * 4, G * EE);
  }

  trxn_k<<<(NN * 12) / 256, 256, 0, stream>>>(coord, cd, wsumb, offb, deg, out_x);

  // -------- node MLP + residual -> h_new --------
  cvt_k<<<(NN * 512) / 256, 256, 0, stream>>>(agg, aggb, NN * 512);
  mgemm_k<<<4 * (NN / 128), 256, 0, stream>>>(AgHcat{h_bf, aggb}, BgDirect{nW1b, 1024}, 1024, 0, 2,
      nb1, nullptr, nullptr, bufA, 512, FLAG_SILU);
  mgemm_k<<<4 * (NN / 128), 256, 0, stream>>>(AgDirect{bufA, 512}, BgDirect{nW2b, 512}, 512, 0, 2,
      nb2, h, out_h, hn_bf, 512, FLAG_RES);

  // -------- pass 2: GG = hn @ [eW1a;eW1c]^T + [eb1;0] ; fused m --------
  mgemm_k<<<512, 256, 0, stream>>>(AgDirect{hn_bf, 512}, BgDirect{eGc, 512}, 512, 0, 3,
      ggbias, nullptr, nullptr, GGb, 1024, 0);
  mout_k<<<TE / 4, 256, 0, stream>>>(GGb, eW2, weab, eb2, eaS, rowS, colS, order, out_m);

  (void)in_sizes; (void)n_in; (void)out_size; (void)ws_size;
}

// Round 13
// 1296.753 us; speedup vs baseline: 1.6267x; 1.0831x over previous
//
#include <hip/hip_runtime.h>
#include <cstdint>

#define NN 8192
#define DD 512
#define CC 4
#define TT 8
#define EE 32768
#define TE (TT*EE)

typedef __attribute__((ext_vector_type(8))) short short8v;
typedef __attribute__((ext_vector_type(4))) float f32x4;
typedef unsigned int uint;

constexpr int FLAG_SILU = 1, FLAG_RES = 2, FLAG_WEPI = 4, FLAG_BIAS_T = 8;

__device__ __forceinline__ float silu_f(float x) {
  return x * __builtin_amdgcn_rcpf(1.f + __expf(-x));
}

__device__ __forceinline__ unsigned short f2bf(float f) {
  uint u = __builtin_bit_cast(uint, f);
  u += 0x7fffu + ((u >> 16) & 1u);
  return (unsigned short)(u >> 16);
}
__device__ __forceinline__ float bf2f(unsigned short b) {
  uint u = ((uint)b) << 16;
  return __builtin_bit_cast(float, u);
}
__device__ __forceinline__ float bflo(uint u) { return __builtin_bit_cast(float, u << 16); }
__device__ __forceinline__ float bfhi(uint u) { return __builtin_bit_cast(float, u & 0xffff0000u); }
__device__ __forceinline__ uint packbf(float a, float b) {
  return (uint)f2bf(a) | ((uint)f2bf(b) << 16);
}

__device__ __forceinline__ float wave_sum(float v) {
#pragma unroll
  for (int off = 32; off; off >>= 1) v += __shfl_xor(v, off);
  return v;
}

__device__ __forceinline__ void gload16(const void* g, void* l) {
  __builtin_amdgcn_global_load_lds(
      (const __attribute__((address_space(1))) void*)g,
      (__attribute__((address_space(3))) void*)l, 16, 0, 0);
}

// chunked XCD swizzle: logical index from launched blockIdx (nwg % 8 == 0)
__device__ __forceinline__ int xcd_swz(int i, int nwg) {
  return (i & 7) * (nwg >> 3) + (i >> 3);
}

// ---------------- gather functors ----------------
struct AgDirect { const unsigned short* p; int K;
  __device__ const void* ptr(int m, int k, int) const { return p + (size_t)m * K + k; } };

struct AgHcat { const unsigned short* hb; const unsigned short* ab;
  __device__ const void* ptr(int m, int k, int) const {
    return (k < 512) ? (const void*)(hb + ((size_t)m << 9) + k)
                     : (const void*)(ab + ((size_t)m << 9) + (k - 512)); } };

struct AgSegG { const unsigned short* seg;
  __device__ const void* ptr(int m, int k, int) const {
    return seg + (((size_t)(k >> 9) * NN + m) << 9) + (k & 511); } };

struct BgDirect { const unsigned short* p; int K;
  __device__ const void* ptr(int o, int k, int) const { return p + (size_t)o * K + k; } };

struct BgRelG { const unsigned short* w;
  __device__ const void* ptr(int o, int k, int) const {
    return w + (((size_t)(k >> 9) * 512 + o) << 9) + (k & 511); } };

struct BgPerT { const unsigned short* w;
  __device__ const void* ptr(int o, int k, int tt) const {
    return w + (((size_t)tt << 18) + ((size_t)o << 9)) + k; } };

// ------- bf16 MFMA GEMM, 128x128 tile, 4 waves (small/node GEMMs) -------
template<class AG, class BG>
__global__ __launch_bounds__(256)
void mgemm_k(AG ag, BG bg, int K, int tbase, int lognx,
             const float* __restrict__ bias, const float* __restrict__ res,
             float* __restrict__ outF, unsigned short* __restrict__ outB, int ldo, int flags)
{
  __shared__ __align__(16) unsigned short SM[128 * 136];
  unsigned short* As = SM;
  unsigned short* Bs = SM + 128 * 64;
  const int swz = xcd_swz(blockIdx.x, gridDim.x);
  const int xb = swz & ((1 << lognx) - 1), yb = swz >> lognx;
  const int m0 = yb * 128, o0 = xb * 128;
  const int tt = tbase + (m0 >> 15);
  const int tid = threadIdx.x, wave = tid >> 6, lane = tid & 63;
  const int wr = (wave >> 1) * 64, wc = (wave & 1) * 64;
  const int rs = lane >> 3, sl = lane & 7;

  f32x4 acc[4][4];
#pragma unroll
  for (int i = 0; i < 4; ++i)
#pragma unroll
    for (int j = 0; j < 4; ++j) acc[i][j] = (f32x4)0.f;

  for (int k0 = 0; k0 < K; k0 += 64) {
#pragma unroll
    for (int i = 0; i < 4; ++i) {
      int r = i * 32 + wave * 8 + rs;
      int slot = sl ^ (r & 7);
      gload16(ag.ptr(m0 + r, k0 + slot * 8, tt), &As[(i * 32 + wave * 8) * 64]);
    }
#pragma unroll
    for (int i = 0; i < 4; ++i) {
      int r = i * 32 + wave * 8 + rs;
      int slot = sl ^ (r & 7);
      gload16(bg.ptr(o0 + r, k0 + slot * 8, tt), &Bs[(i * 32 + wave * 8) * 64]);
    }
    __syncthreads();
    short8v a[4][2], b[4][2];
#pragma unroll
    for (int mi = 0; mi < 4; ++mi)
#pragma unroll
      for (int s = 0; s < 2; ++s) {
        int row = wr + mi * 16 + (lane & 15);
        int slot = (s * 4 + (lane >> 4)) ^ (row & 7);
        a[mi][s] = *(const short8v*)&As[row * 64 + slot * 8];
      }
#pragma unroll
    for (int ni = 0; ni < 4; ++ni)
#pragma unroll
      for (int s = 0; s < 2; ++s) {
        int row = wc + ni * 16 + (lane & 15);
        int slot = (s * 4 + (lane >> 4)) ^ (row & 7);
        b[ni][s] = *(const short8v*)&Bs[row * 64 + slot * 8];
      }
#pragma unroll
    for (int s = 0; s < 2; ++s)
#pragma unroll
      for (int mi = 0; mi < 4; ++mi)
#pragma unroll
        for (int ni = 0; ni < 4; ++ni)
          acc[mi][ni] = __builtin_amdgcn_mfma_f32_16x16x32_bf16(a[mi][s], b[ni][s], acc[mi][ni], 0, 0, 0);
    __syncthreads();
  }

  const int r4 = (lane >> 4) * 4, cl = lane & 15;
  if (outB && !outF) {
    unsigned short* Ep = SM;
#pragma unroll
    for (int mi = 0; mi < 4; ++mi)
#pragma unroll
      for (int ni = 0; ni < 4; ++ni)
#pragma unroll
        for (int rg = 0; rg < 4; ++rg) {
          int row = wr + mi * 16 + r4 + rg;
          int col = wc + ni * 16 + cl;
          float v = acc[mi][ni][rg];
          if (bias) v += (flags & FLAG_BIAS_T) ? bias[tt * 512 + o0 + col] : bias[o0 + col];
          if (flags & FLAG_SILU) v = silu_f(v);
          Ep[row * 136 + col] = f2bf(v);
        }
    __syncthreads();
#pragma unroll
    for (int p = 0; p < 8; ++p) {
      int idx = p * 256 + tid;
      int row = idx >> 4, ch = idx & 15;
      short8v vv = *(const short8v*)&Ep[row * 136 + ch * 8];
      *(short8v*)(outB + (size_t)(m0 + row) * ldo + o0 + ch * 8) = vv;
    }
    return;
  }
#pragma unroll
  for (int mi = 0; mi < 4; ++mi)
#pragma unroll
    for (int ni = 0; ni < 4; ++ni)
#pragma unroll
      for (int rg = 0; rg < 4; ++rg) {
        int row = m0 + wr + mi * 16 + r4 + rg;
        int col = o0 + wc + ni * 16 + cl;
        float v = acc[mi][ni][rg];
        if (bias) v += (flags & FLAG_BIAS_T) ? bias[tt * 512 + col] : bias[col];
        if (flags & FLAG_SILU) v = silu_f(v);
        if (flags & FLAG_RES) v += res[(size_t)row * ldo + col];
        if (outF) outF[(size_t)row * ldo + col] = v;
        if (outB) outB[(size_t)row * ldo + col] = f2bf(v);
      }
}

// ------- bf16 MFMA GEMM, 256x128 tile, 8 waves (big edge GEMMs; N=512, lognx=2) -------
template<class AG, class BG>
__global__ __launch_bounds__(512)
void mgemm2_k(AG ag, BG bg, int K, int tbase,
              const float* __restrict__ bias,
              unsigned short* __restrict__ outB, int flags,
              const float* __restrict__ cw2, float* __restrict__ wpart, int wstride)
{
  __shared__ __align__(16) unsigned short SM[(256 + 128) * 64];   // 48KB
  unsigned short* As = SM;
  unsigned short* Bs = SM + 256 * 64;
  const int swz = xcd_swz(blockIdx.x, gridDim.x);
  const int xb = swz & 3, yb = swz >> 2;
  const int m0 = yb * 256, o0 = xb * 128;
  const int tt = tbase + (m0 >> 15);
  const int tid = threadIdx.x, wave = tid >> 6, lane = tid & 63;
  const int wr = (wave >> 1) * 64, wc = (wave & 1) * 64;
  const int rs = lane >> 3, sl = lane & 7;

  f32x4 acc[4][4];
#pragma unroll
  for (int i = 0; i < 4; ++i)
#pragma unroll
    for (int j = 0; j < 4; ++j) acc[i][j] = (f32x4)0.f;

  for (int k0 = 0; k0 < K; k0 += 64) {
#pragma unroll
    for (int i = 0; i < 4; ++i) {
      int r = i * 64 + wave * 8 + rs;
      int slot = sl ^ (r & 7);
      gload16(ag.ptr(m0 + r, k0 + slot * 8, tt), &As[(i * 64 + wave * 8) * 64]);
    }
#pragma unroll
    for (int i = 0; i < 2; ++i) {
      int r = i * 64 + wave * 8 + rs;
      int slot = sl ^ (r & 7);
      gload16(bg.ptr(o0 + r, k0 + slot * 8, tt), &Bs[(i * 64 + wave * 8) * 64]);
    }
    __syncthreads();
    short8v a[4][2], b[4][2];
#pragma unroll
    for (int mi = 0; mi < 4; ++mi)
#pragma unroll
      for (int s = 0; s < 2; ++s) {
        int row = wr + mi * 16 + (lane & 15);
        int slot = (s * 4 + (lane >> 4)) ^ (row & 7);
        a[mi][s] = *(const short8v*)&As[row * 64 + slot * 8];
      }
#pragma unroll
    for (int ni = 0; ni < 4; ++ni)
#pragma unroll
      for (int s = 0; s < 2; ++s) {
        int row = wc + ni * 16 + (lane & 15);
        int slot = (s * 4 + (lane >> 4)) ^ (row & 7);
        b[ni][s] = *(const short8v*)&Bs[row * 64 + slot * 8];
      }
#pragma unroll
    for (int s = 0; s < 2; ++s)
#pragma unroll
      for (int mi = 0; mi < 4; ++mi)
#pragma unroll
        for (int ni = 0; ni < 4; ++ni)
          acc[mi][ni] = __builtin_amdgcn_mfma_f32_16x16x32_bf16(a[mi][s], b[ni][s], acc[mi][ni], 0, 0, 0);
    __syncthreads();
  }

  const int r4 = (lane >> 4) * 4, cl = lane & 15;
  if (flags & FLAG_WEPI) {
    const int slice = xb * 2 + (wave & 1);
    const float* cw2t = cw2 + tt * 2048;
    const float* bt = bias + tt * 512;
#pragma unroll
    for (int mi = 0; mi < 4; ++mi) {
      float sc[4][4];
#pragma unroll
      for (int rg = 0; rg < 4; ++rg)
#pragma unroll
        for (int c = 0; c < 4; ++c) sc[rg][c] = 0.f;
#pragma unroll
      for (int ni = 0; ni < 4; ++ni) {
        int col = o0 + wc + ni * 16 + cl;
        float c0 = cw2t[col], c1 = cw2t[512 + col], c2 = cw2t[1024 + col], c3 = cw2t[1536 + col];
        float bb = bt[col];
#pragma unroll
        for (int rg = 0; rg < 4; ++rg) {
          float v = silu_f(acc[mi][ni][rg] + bb);
          sc[rg][0] += v * c0; sc[rg][1] += v * c1; sc[rg][2] += v * c2; sc[rg][3] += v * c3;
        }
      }
#pragma unroll
      for (int rg = 0; rg < 4; ++rg)
#pragma unroll
        for (int c = 0; c < 4; ++c) {
          float s = sc[rg][c];
          s += __shfl_xor(s, 1); s += __shfl_xor(s, 2);
          s += __shfl_xor(s, 4); s += __shfl_xor(s, 8);
          sc[rg][c] = s;
        }
      if (cl == 0) {
        int p = m0 + wr + mi * 16 + r4;
#pragma unroll
        for (int rg = 0; rg < 4; ++rg) {
          float4 o = make_float4(sc[rg][0], sc[rg][1], sc[rg][2], sc[rg][3]);
          *(float4*)&wpart[(((size_t)slice * wstride) + p + rg) * 4] = o;
        }
      }
    }
    return;
  }
  unsigned short* Ep = SM;
#pragma unroll
  for (int hh = 0; hh < 2; ++hh) {
    if ((wr >> 7) == hh) {
#pragma unroll
      for (int mi = 0; mi < 4; ++mi)
#pragma unroll
        for (int ni = 0; ni < 4; ++ni)
#pragma unroll
          for (int rg = 0; rg < 4; ++rg) {
            int row = (wr & 127) + mi * 16 + r4 + rg;
            int col = wc + ni * 16 + cl;
            float v = acc[mi][ni][rg];
            v += bias[o0 + col];
            if (flags & FLAG_SILU) v = silu_f(v);
            Ep[row * 136 + col] = f2bf(v);
          }
    }
    __syncthreads();
#pragma unroll
    for (int p = 0; p < 4; ++p) {
      int idx = p * 512 + tid;
      int row = idx >> 4, ch = idx & 15;
      short8v vv = *(const short8v*)&Ep[row * 136 + ch * 8];
      *(short8v*)(outB + (size_t)(m0 + hh * 128 + row) * 512 + o0 + ch * 8) = vv;
    }
    __syncthreads();
  }
}

// ---------------- mega prep kernel: all cvt + slices + tail + wea + biases ----------------
__global__ __launch_bounds__(256)
void prep_k(const float* h, const float* mW2, const float* nW1, const float* nW2,
            const float* relW, const float* cW1, const float* mW1, const float* eW1,
            const float* mb1, const float* eb1,
            unsigned short* hb, unsigned short* mW2b, unsigned short* nW1b,
            unsigned short* nW2b, unsigned short* relWb, unsigned short* cW1b,
            unsigned short* mW1pq, unsigned short* eGc, unsigned short* mW1t,
            float* wea, float* pqb, float* ggb)
{
  int i = blockIdx.x * 256 + threadIdx.x;    // < 10496000
  if (i < 4194304) { hb[i] = f2bf(h[i]); return; }
  i -= 4194304;
  if (i < 262144) { mW2b[i] = f2bf(mW2[i]); return; }
  i -= 262144;
  if (i < 524288) { nW1b[i] = f2bf(nW1[i]); return; }
  i -= 524288;
  if (i < 262144) { nW2b[i] = f2bf(nW2[i]); return; }
  i -= 262144;
  if (i < 2097152) { relWb[i] = f2bf(relW[i]); return; }
  i -= 2097152;
  if (i < 2097152) { cW1b[i] = f2bf(cW1[i]); return; }
  i -= 2097152;
  if (i < 262144) { int r = i >> 9, k = i & 511; mW1pq[i] = f2bf(mW1[(size_t)r * 1041 + k]); return; }
  i -= 262144;
  if (i < 262144) { int r = i >> 9, k = i & 511; mW1pq[262144 + i] = f2bf(mW1[(size_t)r * 1041 + 512 + k]); return; }
  i -= 262144;
  if (i < 262144) { int r = i >> 9, k = i & 511; eGc[i] = f2bf(eW1[(size_t)r * 1025 + k]); return; }
  i -= 262144;
  if (i < 262144) { int r = i >> 9, k = i & 511; eGc[262144 + i] = f2bf(eW1[(size_t)r * 1025 + 513 + k]); return; }
  i -= 262144;
  if (i < 8704) { int j = i >> 9, c = i & 511; mW1t[i] = f2bf(mW1[(size_t)c * 1041 + 1024 + j]); return; }
  i -= 8704;
  if (i < 512) { wea[i] = eW1[(size_t)i * 1025 + 512]; return; }
  i -= 512;
  if (i < 1024) {
    pqb[i] = (i < 512) ? mb1[i] : 0.f;
    ggb[i] = (i < 512) ? eb1[i] : 0.f;
  }
}

__global__ __launch_bounds__(256)
void hist_k(const int* __restrict__ eidx, int* __restrict__ deg) {
  int id = blockIdx.x * 256 + threadIdx.x;
  int t = id >> 15, e = id & (EE - 1);
  atomicAdd(&deg[(t << 13) + eidx[(t << 16) + e]], 1);
}

__global__ __launch_bounds__(256)
void scan_k(const int* __restrict__ deg, int* __restrict__ off, int* __restrict__ cursor) {
  int t = blockIdx.x, tid = threadIdx.x;
  __shared__ int lds[256];
  int base = 0;
  for (int ch = 0; ch < 32; ++ch) {
    int i = ch * 256 + tid;
    int v = deg[(t << 13) + i];
    __syncthreads();
    lds[tid] = v;
    __syncthreads();
    for (int s = 1; s < 256; s <<= 1) {
      int x = (tid >= s) ? lds[tid - s] : 0;
      __syncthreads();
      if (tid >= s) lds[tid] += x;
      __syncthreads();
    }
    int excl = base + lds[tid] - v;
    off[(t << 13) + i] = excl;
    cursor[(t << 13) + i] = excl;
    base += lds[255];
  }
}

// ------ merged scatter + cd/radial at sorted positions + per-block sq partials ------
__global__ __launch_bounds__(256)
void scatcd_k(const int* __restrict__ eidx, const float* __restrict__ ea,
              const float* __restrict__ coord, int* __restrict__ cursor,
              int* __restrict__ order, int* __restrict__ rowS, int* __restrict__ colS,
              float* __restrict__ eaS, float* __restrict__ cd,
              float* __restrict__ radial, float* __restrict__ pnrm)
{
  int m = blockIdx.x * 256 + threadIdx.x;
  int t = m >> 15, e = m & (EE - 1);
  int r = eidx[(t << 16) + e], c = eidx[(t << 16) + EE + e];
  int pos = atomicAdd(&cursor[(t << 13) + r], 1);
  size_t s = ((size_t)t << 15) + pos;
  order[s] = e; rowS[s] = r; colS[s] = c; eaS[s] = ea[m];
  const float4* cv4 = (const float4*)coord;
  float4 A0 = cv4[r * 3], A1 = cv4[r * 3 + 1], A2 = cv4[r * 3 + 2];
  float4 B0 = cv4[c * 3], B1 = cv4[c * 3 + 1], B2 = cv4[c * 3 + 2];
  float d[12] = {A0.x-B0.x, A0.y-B0.y, A0.z-B0.z, A0.w-B0.w,
                 A1.x-B1.x, A1.y-B1.y, A1.z-B1.z, A1.w-B1.w,
                 A2.x-B2.x, A2.y-B2.y, A2.z-B2.z, A2.w-B2.w};
  float4* cdv = (float4*)cd;
  cdv[s*3+0] = make_float4(d[0],d[1],d[2],d[3]);
  cdv[s*3+1] = make_float4(d[4],d[5],d[6],d[7]);
  cdv[s*3+2] = make_float4(d[8],d[9],d[10],d[11]);
  float rad[16], sq[16];
#pragma unroll
  for (int ci = 0; ci < 4; ++ci)
#pragma unroll
    for (int di = 0; di < 4; ++di) {
      float v = d[ci*3]*d[di*3] + d[ci*3+1]*d[di*3+1] + d[ci*3+2]*d[di*3+2];
      rad[ci*4+di] = v; sq[ci*4+di] = v * v;
    }
  float4* rv = (float4*)radial;
#pragma unroll
  for (int i = 0; i < 4; ++i)
    rv[s*4+i] = make_float4(rad[i*4], rad[i*4+1], rad[i*4+2], rad[i*4+3]);
#pragma unroll
  for (int i = 0; i < 16; ++i) sq[i] = wave_sum(sq[i]);
  __shared__ float red[4][16];
  int wv = threadIdx.x >> 6, lane = threadIdx.x & 63;
  if (lane == 0) {
#pragma unroll
    for (int i = 0; i < 16; ++i) red[wv][i] = sq[i];
  }
  __syncthreads();
  if (threadIdx.x < 16)
    pnrm[blockIdx.x * 16 + threadIdx.x] =
        red[0][threadIdx.x] + red[1][threadIdx.x] + red[2][threadIdx.x] + red[3][threadIdx.x];
}

__global__ __launch_bounds__(128)
void nrmred_k(const float* __restrict__ pnrm, float* __restrict__ nrm) {
  int t = threadIdx.x >> 4, j = threadIdx.x & 15;
  float s = 0.f;
  for (int b = 0; b < 128; ++b) s += pnrm[((t * 128 + b) << 4) + j];
  nrm[(t << 4) + j] = s;
}

__global__ __launch_bounds__(256)
void tails_k(const float* __restrict__ radial, const float* __restrict__ nrm,
             const float* __restrict__ eaS, unsigned short* __restrict__ tailm)
{
  int m = blockIdx.x * 256 + threadIdx.x;
  int t = m >> 15;
  unsigned short tmp[24];
#pragma unroll
  for (int j = 0; j < 16; ++j) {
    float r = radial[(size_t)m * 16 + j] / fmaxf(sqrtf(nrm[(t << 4) + j]), 1e-12f);
    tmp[j] = f2bf(r);
  }
  tmp[16] = f2bf(eaS[m]);
#pragma unroll
  for (int j = 17; j < 24; ++j) tmp[j] = 0;
  uint4* dst = (uint4*)(tailm + (size_t)m * 24);
  dst[0] = ((const uint4*)tmp)[0];
  dst[1] = ((const uint4*)tmp)[1];
  dst[2] = ((const uint4*)tmp)[2];
}

__global__ __launch_bounds__(256)
void msg1f_k(const unsigned short* __restrict__ PQ, const unsigned short* __restrict__ Wt,
             const unsigned short* __restrict__ tailm_g,
             const int* __restrict__ rowS_g, const int* __restrict__ colS_g,
             unsigned short* __restrict__ out)
{
  int tid = threadIdx.x;
  int e0 = xcd_swz(blockIdx.x, gridDim.x) * 16;
  uint wreg[17];
#pragma unroll
  for (int j = 0; j < 17; ++j) wreg[j] = *(const uint*)(Wt + j * 512 + tid * 2);
  for (int i = 0; i < 16; ++i) {
    int p = e0 + i;
    int r = rowS_g[p], c = colS_g[p];
    uint pv = *(const uint*)(PQ + ((size_t)r << 10) + tid * 2);
    uint qv = *(const uint*)(PQ + ((size_t)c << 10) + 512 + tid * 2);
    uint4 t0 = *(const uint4*)(tailm_g + (size_t)p * 24);
    uint4 t1 = *(const uint4*)(tailm_g + (size_t)p * 24 + 8);
    uint  t2 = *(const uint*)(tailm_g + (size_t)p * 24 + 16);
    float tl[17] = {bflo(t0.x), bfhi(t0.x), bflo(t0.y), bfhi(t0.y),
                    bflo(t0.z), bfhi(t0.z), bflo(t0.w), bfhi(t0.w),
                    bflo(t1.x), bfhi(t1.x), bflo(t1.y), bfhi(t1.y),
                    bflo(t1.z), bfhi(t1.z), bflo(t1.w), bfhi(t1.w),
                    bflo(t2)};
    float s0 = bflo(pv) + bflo(qv);
    float s1 = bfhi(pv) + bfhi(qv);
#pragma unroll
    for (int j = 0; j < 17; ++j) {
      s0 += tl[j] * bflo(wreg[j]); s1 += tl[j] * bfhi(wreg[j]);
    }
    *(uint*)(out + ((size_t)p << 9) + tid * 2) = packbf(silu_f(s0), silu_f(s1));
  }
}

__global__ __launch_bounds__(256)
void gsum_k(const unsigned short* __restrict__ msg, const int* __restrict__ offb,
            const int* __restrict__ deg, int tbase, unsigned short* __restrict__ segt)
{
  int l = xcd_swz(blockIdx.x, gridDim.x);
  int tloc = l >> 13, n = l & (NN - 1), tid = threadIdx.x;
  int t = tbase + tloc;
  int start = offb[(t << 13) + n], d = deg[(t << 13) + n];
  float s0 = 0.f, s1 = 0.f;
  const unsigned short* base = msg + (((size_t)tloc << 15) << 9);
  for (int j = 0; j < d; ++j) {
    uint v = *(const uint*)(base + ((size_t)(start + j) << 9) + tid * 2);
    s0 += bflo(v); s1 += bfhi(v);
  }
  *(uint*)(segt + (((size_t)tloc * NN + n) << 9) + tid * 2) = packbf(s0, s1);
}

__global__ __launch_bounds__(256)
void wsum_k(const float* __restrict__ wpart, float* __restrict__ wsum_out, int wstride) {
  int id = xcd_swz(blockIdx.x, gridDim.x) * 256 + threadIdx.x;
  float4 a = (float4){0.f, 0.f, 0.f, 0.f};
#pragma unroll
  for (int s = 0; s < 8; ++s) {
    float4 v = *(const float4*)&wpart[(((size_t)s * wstride) + id) * 4];
    a.x += v.x; a.y += v.y; a.z += v.z; a.w += v.w;
  }
  *(float4*)&wsum_out[(size_t)id * 4] = a;
}

__global__ __launch_bounds__(256)
void trxn_k(const float* __restrict__ coord, const float* __restrict__ cd,
            const float* __restrict__ wsum, const int* __restrict__ offb,
            const int* __restrict__ deg, float* __restrict__ xout)
{
  int id = blockIdx.x * 256 + threadIdx.x;
  int n = id / 12, j = id - n * 12, ci = j / 3;
  float s = 0.f; int cnt = 0;
#pragma unroll
  for (int t = 0; t < 8; ++t) {
    int o = offb[(t << 13) + n], d = deg[(t << 13) + n];
    size_t p = ((size_t)t << 15) + o;
    for (int k = 0; k < d; ++k)
      s += cd[(p + k) * 12 + j] * wsum[(p + k) * 4 + ci];
    cnt += d;
  }
  xout[id] = coord[id] + s / fmaxf((float)cnt, 1.f);
}

__global__ __launch_bounds__(256)
void mout_k(const unsigned short* __restrict__ GG,
            const float* __restrict__ eW2, const float* __restrict__ wea,
            const float* __restrict__ eb2, const float* __restrict__ eaS,
            const int* __restrict__ rowS, const int* __restrict__ colS,
            const int* __restrict__ order, float* __restrict__ out_m)
{
  int wid = xcd_swz(blockIdx.x, gridDim.x) * 4 + (threadIdx.x >> 6);
  int lane = threadIdx.x & 63;
  int t = wid >> 15;
  int r = rowS[wid], c = colS[wid];
  float eav = eaS[wid];
  short8v gv  = *(const short8v*)(GG + ((size_t)r << 10) + lane * 8);
  short8v gcv = *(const short8v*)(GG + ((size_t)c << 10) + 512 + lane * 8);
  const float4* w4 = (const float4*)(eW2 + lane * 8);
  const float4* a4 = (const float4*)(wea + lane * 8);
  float4 w0 = w4[0], w1 = w4[1], a0 = a4[0], a1 = a4[1];
  float wv8[8] = {w0.x,w0.y,w0.z,w0.w,w1.x,w1.y,w1.z,w1.w};
  float av8[8] = {a0.x,a0.y,a0.z,a0.w,a1.x,a1.y,a1.z,a1.w};
  float s = 0.f;
#pragma unroll
  for (int j = 0; j < 8; ++j)
    s += wv8[j] * silu_f(bf2f((unsigned short)gv[j]) + bf2f((unsigned short)gcv[j]) + eav * av8[j]);
  s = wave_sum(s);
  if (lane == 0) out_m[((size_t)t << 15) + order[wid]] = s + eb2[0];
}

// ---------------- launch ----------------
extern "C" void kernel_launch(void* const* d_in, const int* in_sizes, int n_in,
                              void* d_out, int out_size, void* d_ws, size_t ws_size,
                              hipStream_t stream)
{
  const float* h     = (const float*)d_in[0];
  const float* coord = (const float*)d_in[1];
  const float* ea    = (const float*)d_in[2];
  const int*   eidx  = (const int*)  d_in[3];
  const float* mW1   = (const float*)d_in[4];
  const float* mb1   = (const float*)d_in[5];
  const float* mW2   = (const float*)d_in[6];
  const float* mb2   = (const float*)d_in[7];
  const float* nW1   = (const float*)d_in[8];
  const float* nb1   = (const float*)d_in[9];
  const float* nW2   = (const float*)d_in[10];
  const float* nb2   = (const float*)d_in[11];
  const float* eW1   = (const float*)d_in[12];
  const float* eb1   = (const float*)d_in[13];
  const float* eW2   = (const float*)d_in[14];
  const float* eb2   = (const float*)d_in[15];
  const float* relW  = (const float*)d_in[16];
  const float* cW1   = (const float*)d_in[17];
  const float* cb1   = (const float*)d_in[18];
  const float* cW2   = (const float*)d_in[19];

  float* out   = (float*)d_out;
  float* out_h = out;
  float* out_x = out + (size_t)NN * DD;
  float* out_m = out_x + (size_t)NN * CC * 3;

  char* ws = (char*)d_ws;
  size_t off = 0;
  auto alloc = [&](size_t bytes) -> void* {
    void* p = ws + off; off += (bytes + 255) & ~(size_t)255; return p;
  };
  float* cd     = (float*)alloc((size_t)TE * 12 * 4);
  unsigned short* tailm = (unsigned short*)alloc((size_t)TE * 24 * 2);
  float* agg    = (float*)alloc((size_t)NN * 512 * 4);
  unsigned short* h_bf  = (unsigned short*)alloc((size_t)NN * 512 * 2);
  unsigned short* hn_bf = (unsigned short*)alloc((size_t)NN * 512 * 2);
  unsigned short* PQb   = (unsigned short*)alloc((size_t)NN * 1024 * 2);
  unsigned short* GGb   = PQb;
  unsigned short* mW1pq = (unsigned short*)alloc((size_t)1024 * 512 * 2);
  unsigned short* mW1t  = (unsigned short*)alloc((size_t)17 * 512 * 2);
  unsigned short* mW2b  = (unsigned short*)alloc((size_t)512 * 512 * 2);
  unsigned short* nW1b  = (unsigned short*)alloc((size_t)512 * 1024 * 2);
  unsigned short* nW2b  = (unsigned short*)alloc((size_t)512 * 512 * 2);
  unsigned short* eGc   = (unsigned short*)alloc((size_t)1024 * 512 * 2);
  float* weab   = (float*)alloc(512 * 4);
  float* pqbias = (float*)alloc(1024 * 4);
  float* ggbias = (float*)alloc(1024 * 4);
  unsigned short* relWb = (unsigned short*)alloc((size_t)TT * 512 * 512 * 2);
  unsigned short* cW1b  = (unsigned short*)alloc((size_t)TT * 512 * 512 * 2);
  int* deg     = (int*)alloc((size_t)TT * NN * 4);
  int* offb    = (int*)alloc((size_t)TT * NN * 4);
  int* cursor  = (int*)alloc((size_t)TT * NN * 4);
  int* order   = (int*)alloc((size_t)TE * 4);
  int* rowS    = (int*)alloc((size_t)TE * 4);
  int* colS    = (int*)alloc((size_t)TE * 4);
  float* eaS   = (float*)alloc((size_t)TE * 4);
  float* wsumb = (float*)alloc((size_t)TE * 4 * 4);
  float* pnrm  = (float*)alloc((size_t)(TE / 256) * 16 * 4);
  float* nrm   = (float*)alloc((size_t)TT * 16 * 4);

  const size_t perG = (size_t)EE * 512 * 2 * 2 + (size_t)NN * 512 * 2 + (size_t)8 * EE * 16;
  int G = 4;
  while (G > 1 && off + (size_t)G * perG + (1 << 20) > ws_size) G >>= 1;
  unsigned short* bufA = (unsigned short*)alloc((size_t)G * EE * 512 * 2);
  unsigned short* bufB = (unsigned short*)alloc((size_t)G * EE * 512 * 2);
  unsigned short* segt = (unsigned short*)alloc((size_t)G * NN * 512 * 2);
  float* wpart = (float*)alloc((size_t)8 * G * EE * 4 * 4);
  unsigned short* aggb = segt;
  float* radial = (float*)bufA;

  hipMemsetAsync(deg, 0, (size_t)TT * NN * 4, stream);
  hipMemsetAsync(agg, 0, (size_t)NN * 512 * 4, stream);

  // mega-prep (all conversions, slices, tails, biases in one dispatch)
  prep_k<<<41000, 256, 0, stream>>>(h, mW2, nW1, nW2, relW, cW1, mW1, eW1, mb1, eb1,
      h_bf, mW2b, nW1b, nW2b, relWb, cW1b, mW1pq, eGc, mW1t, weab, pqbias, ggbias);

  // sort + geometry
  hist_k<<<TE / 256, 256, 0, stream>>>(eidx, deg);
  scan_k<<<TT, 256, 0, stream>>>(deg, offb, cursor);
  scatcd_k<<<TE / 256, 256, 0, stream>>>(eidx, ea, coord, cursor,
      order, rowS, colS, eaS, cd, radial, pnrm);
  nrmred_k<<<1, 128, 0, stream>>>(pnrm, nrm);
  tails_k<<<TE / 256, 256, 0, stream>>>(radial, nrm, eaS, tailm);

  // PQ = h @ [mW1a;mW1q]^T + [mb1;0]
  mgemm_k<<<512, 256, 0, stream>>>(AgDirect{h_bf, 512}, BgDirect{mW1pq, 512}, 512, 0, 3,
      pqbias, nullptr, nullptr, PQb, 1024, 0);

  // -------- pass 1: batched groups of G relations --------
  for (int g = 0; g < TT / G; ++g) {
    const int tbase = g * G;
    const size_t gb = (size_t)tbase << 15;
    msg1f_k<<<(G * EE) / 16, 256, 0, stream>>>(PQb, mW1t, tailm + gb * 24,
        rowS + gb, colS + gb, bufA);
    mgemm2_k<<<4 * (G * EE / 256), 512, 0, stream>>>(AgDirect{bufA, 512},
        BgDirect{mW2b, 512}, 512, tbase,
        mb2, bufB, FLAG_SILU, nullptr, nullptr, 0);
    gsum_k<<<G * NN, 256, 0, stream>>>(bufB, offb, deg, tbase, segt);
    // agg += segt @ relW^T ; on last group also emit bf16 agg
    bool last = (g == TT / G - 1);
    mgemm_k<<<4 * (NN / 128), 256, 0, stream>>>(AgSegG{segt},
        BgRelG{relWb + ((size_t)tbase << 18)}, G * 512, 0, 2,
        nullptr, agg, agg, last ? aggb : nullptr, 512, FLAG_RES);
    mgemm2_k<<<4 * (G * EE / 256), 512, 0, stream>>>(AgDirect{bufB, 512},
        BgPerT{cW1b}, 512, tbase,
        cb1, nullptr, FLAG_SILU | FLAG_WEPI | FLAG_BIAS_T, cW2, wpart, G * EE);
    wsum_k<<<(G * EE) / 256, 256, 0, stream>>>(wpart, wsumb + gb * 4, G * EE);
  }

  trxn_k<<<(NN * 12) / 256, 256, 0, stream>>>(coord, cd, wsumb, offb, deg, out_x);

  // -------- node MLP + residual -> h_new --------
  mgemm_k<<<4 * (NN / 128), 256, 0, stream>>>(AgHcat{h_bf, aggb}, BgDirect{nW1b, 1024}, 1024, 0, 2,
      nb1, nullptr, nullptr, bufA, 512, FLAG_SILU);
  mgemm_k<<<4 * (NN / 128), 256, 0, stream>>>(AgDirect{bufA, 512}, BgDirect{nW2b, 512}, 512, 0, 2,
      nb2, h, out_h, hn_bf, 512, FLAG_RES);

  // -------- pass 2: GG = hn @ [eW1a;eW1c]^T + [eb1;0] ; fused m --------
  mgemm_k<<<512, 256, 0, stream>>>(AgDirect{hn_bf, 512}, BgDirect{eGc, 512}, 512, 0, 3,
      ggbias, nullptr, nullptr, GGb, 1024, 0);
  mout_k<<<TE / 4, 256, 0, stream>>>(GGb, eW2, weab, eb2, eaS, rowS, colS, order, out_m);

  (void)in_sizes; (void)n_in; (void)out_size; (void)ws_size;
}

// Round 14
// 1233.031 us; speedup vs baseline: 1.7108x; 1.0517x over previous
//
#include <hip/hip_runtime.h>
#include <cstdint>

#define NN 8192
#define DD 512
#define CC 4
#define TT 8
#define EE 32768
#define TE (TT*EE)

typedef __attribute__((ext_vector_type(8))) short short8v;
typedef __attribute__((ext_vector_type(4))) float f32x4;
typedef unsigned int uint;

constexpr int FLAG_SILU = 1, FLAG_RES = 2, FLAG_WEPI = 4, FLAG_BIAS_T = 8;

__device__ __forceinline__ float silu_f(float x) {
  return x * __builtin_amdgcn_rcpf(1.f + __expf(-x));
}

__device__ __forceinline__ unsigned short f2bf(float f) {
  uint u = __builtin_bit_cast(uint, f);
  u += 0x7fffu + ((u >> 16) & 1u);
  return (unsigned short)(u >> 16);
}
__device__ __forceinline__ float bf2f(unsigned short b) {
  uint u = ((uint)b) << 16;
  return __builtin_bit_cast(float, u);
}
__device__ __forceinline__ float bflo(uint u) { return __builtin_bit_cast(float, u << 16); }
__device__ __forceinline__ float bfhi(uint u) { return __builtin_bit_cast(float, u & 0xffff0000u); }
__device__ __forceinline__ uint packbf(float a, float b) {
  return (uint)f2bf(a) | ((uint)f2bf(b) << 16);
}

__device__ __forceinline__ float wave_sum(float v) {
#pragma unroll
  for (int off = 32; off; off >>= 1) v += __shfl_xor(v, off);
  return v;
}

__device__ __forceinline__ void gload16(const void* g, void* l) {
  __builtin_amdgcn_global_load_lds(
      (const __attribute__((address_space(1))) void*)g,
      (__attribute__((address_space(3))) void*)l, 16, 0, 0);
}

__device__ __forceinline__ int xcd_swz(int i, int nwg) {
  return (i & 7) * (nwg >> 3) + (i >> 3);
}

// ---------------- gather functors ----------------
struct AgDirect { const unsigned short* p; int K;
  __device__ const void* ptr(int m, int k, int) const { return p + (size_t)m * K + k; } };

struct AgHcat { const unsigned short* hb; const unsigned short* ab;
  __device__ const void* ptr(int m, int k, int) const {
    return (k < 512) ? (const void*)(hb + ((size_t)m << 9) + k)
                     : (const void*)(ab + ((size_t)m << 9) + (k - 512)); } };

struct AgSegG { const unsigned short* seg;
  __device__ const void* ptr(int m, int k, int) const {
    return seg + (((size_t)(k >> 9) * NN + m) << 9) + (k & 511); } };

struct BgDirect { const unsigned short* p; int K;
  __device__ const void* ptr(int o, int k, int) const { return p + (size_t)o * K + k; } };

struct BgRelG { const unsigned short* w;
  __device__ const void* ptr(int o, int k, int) const {
    return w + (((size_t)(k >> 9) * 512 + o) << 9) + (k & 511); } };

struct BgPerT { const unsigned short* w;
  __device__ const void* ptr(int o, int k, int tt) const {
    return w + (((size_t)tt << 18) + ((size_t)o << 9)) + k; } };

// ------- bf16 MFMA GEMM, 128x128 tile, 4 waves (node GEMMs) -------
template<class AG, class BG>
__global__ __launch_bounds__(256)
void mgemm_k(AG ag, BG bg, int K, int tbase, int lognx,
             const float* __restrict__ bias, const float* __restrict__ res,
             float* __restrict__ outF, unsigned short* __restrict__ outB, int ldo, int flags)
{
  __shared__ __align__(16) unsigned short SM[128 * 136];
  unsigned short* As = SM;
  unsigned short* Bs = SM + 128 * 64;
  const int swz = xcd_swz(blockIdx.x, gridDim.x);
  const int xb = swz & ((1 << lognx) - 1), yb = swz >> lognx;
  const int m0 = yb * 128, o0 = xb * 128;
  const int tt = tbase + (m0 >> 15);
  const int tid = threadIdx.x, wave = tid >> 6, lane = tid & 63;
  const int wr = (wave >> 1) * 64, wc = (wave & 1) * 64;
  const int rs = lane >> 3, sl = lane & 7;

  f32x4 acc[4][4];
#pragma unroll
  for (int i = 0; i < 4; ++i)
#pragma unroll
    for (int j = 0; j < 4; ++j) acc[i][j] = (f32x4)0.f;

  for (int k0 = 0; k0 < K; k0 += 64) {
#pragma unroll
    for (int i = 0; i < 4; ++i) {
      int r = i * 32 + wave * 8 + rs;
      int slot = sl ^ (r & 7);
      gload16(ag.ptr(m0 + r, k0 + slot * 8, tt), &As[(i * 32 + wave * 8) * 64]);
    }
#pragma unroll
    for (int i = 0; i < 4; ++i) {
      int r = i * 32 + wave * 8 + rs;
      int slot = sl ^ (r & 7);
      gload16(bg.ptr(o0 + r, k0 + slot * 8, tt), &Bs[(i * 32 + wave * 8) * 64]);
    }
    __syncthreads();
    short8v a[4][2], b[4][2];
#pragma unroll
    for (int mi = 0; mi < 4; ++mi)
#pragma unroll
      for (int s = 0; s < 2; ++s) {
        int row = wr + mi * 16 + (lane & 15);
        int slot = (s * 4 + (lane >> 4)) ^ (row & 7);
        a[mi][s] = *(const short8v*)&As[row * 64 + slot * 8];
      }
#pragma unroll
    for (int ni = 0; ni < 4; ++ni)
#pragma unroll
      for (int s = 0; s < 2; ++s) {
        int row = wc + ni * 16 + (lane & 15);
        int slot = (s * 4 + (lane >> 4)) ^ (row & 7);
        b[ni][s] = *(const short8v*)&Bs[row * 64 + slot * 8];
      }
#pragma unroll
    for (int s = 0; s < 2; ++s)
#pragma unroll
      for (int mi = 0; mi < 4; ++mi)
#pragma unroll
        for (int ni = 0; ni < 4; ++ni)
          acc[mi][ni] = __builtin_amdgcn_mfma_f32_16x16x32_bf16(a[mi][s], b[ni][s], acc[mi][ni], 0, 0, 0);
    __syncthreads();
  }

  const int r4 = (lane >> 4) * 4, cl = lane & 15;
  if (outB && !outF) {
    unsigned short* Ep = SM;
#pragma unroll
    for (int mi = 0; mi < 4; ++mi)
#pragma unroll
      for (int ni = 0; ni < 4; ++ni)
#pragma unroll
        for (int rg = 0; rg < 4; ++rg) {
          int row = wr + mi * 16 + r4 + rg;
          int col = wc + ni * 16 + cl;
          float v = acc[mi][ni][rg];
          if (bias) v += (flags & FLAG_BIAS_T) ? bias[tt * 512 + o0 + col] : bias[o0 + col];
          if (flags & FLAG_SILU) v = silu_f(v);
          Ep[row * 136 + col] = f2bf(v);
        }
    __syncthreads();
#pragma unroll
    for (int p = 0; p < 8; ++p) {
      int idx = p * 256 + tid;
      int row = idx >> 4, ch = idx & 15;
      short8v vv = *(const short8v*)&Ep[row * 136 + ch * 8];
      *(short8v*)(outB + (size_t)(m0 + row) * ldo + o0 + ch * 8) = vv;
    }
    return;
  }
#pragma unroll
  for (int mi = 0; mi < 4; ++mi)
#pragma unroll
    for (int ni = 0; ni < 4; ++ni)
#pragma unroll
      for (int rg = 0; rg < 4; ++rg) {
        int row = m0 + wr + mi * 16 + r4 + rg;
        int col = o0 + wc + ni * 16 + cl;
        float v = acc[mi][ni][rg];
        if (bias) v += (flags & FLAG_BIAS_T) ? bias[tt * 512 + col] : bias[col];
        if (flags & FLAG_SILU) v = silu_f(v);
        if (flags & FLAG_RES) v += res[(size_t)row * ldo + col];
        if (outF) outF[(size_t)row * ldo + col] = v;
        if (outB) outB[(size_t)row * ldo + col] = f2bf(v);
      }
}

// ------- bf16 MFMA GEMM, 128x128 tile, 8 waves (wave tile 32x64) — big edge GEMMs -------
template<class AG, class BG>
__global__ __launch_bounds__(512)
void mgemm2_k(AG ag, BG bg, int K, int tbase,
              const float* __restrict__ bias,
              unsigned short* __restrict__ outB, int flags,
              const float* __restrict__ cw2, float* __restrict__ wpart, int wstride)
{
  __shared__ __align__(16) unsigned short SM[128 * 136];   // staging 32KB; epilogue 34.8KB
  unsigned short* As = SM;
  unsigned short* Bs = SM + 128 * 64;
  const int swz = xcd_swz(blockIdx.x, gridDim.x);
  const int xb = swz & 3, yb = swz >> 2;
  const int m0 = yb * 128, o0 = xb * 128;
  const int tt = tbase + (m0 >> 15);
  const int tid = threadIdx.x, wave = tid >> 6, lane = tid & 63;
  const int wr = (wave >> 1) * 32, wc = (wave & 1) * 64;   // wave tile: 32 rows x 64 cols
  const int rs = lane >> 3, sl = lane & 7;

  f32x4 acc[2][4];
#pragma unroll
  for (int i = 0; i < 2; ++i)
#pragma unroll
    for (int j = 0; j < 4; ++j) acc[i][j] = (f32x4)0.f;

  for (int k0 = 0; k0 < K; k0 += 64) {
#pragma unroll
    for (int i = 0; i < 2; ++i) {                 // A: 128 rows by 8 waves
      int r = i * 64 + wave * 8 + rs;
      int slot = sl ^ (r & 7);
      gload16(ag.ptr(m0 + r, k0 + slot * 8, tt), &As[(i * 64 + wave * 8) * 64]);
    }
#pragma unroll
    for (int i = 0; i < 2; ++i) {                 // B: 128 rows by 8 waves
      int r = i * 64 + wave * 8 + rs;
      int slot = sl ^ (r & 7);
      gload16(bg.ptr(o0 + r, k0 + slot * 8, tt), &Bs[(i * 64 + wave * 8) * 64]);
    }
    __syncthreads();
    short8v a[2][2], b[4][2];
#pragma unroll
    for (int mi = 0; mi < 2; ++mi)
#pragma unroll
      for (int s = 0; s < 2; ++s) {
        int row = wr + mi * 16 + (lane & 15);
        int slot = (s * 4 + (lane >> 4)) ^ (row & 7);
        a[mi][s] = *(const short8v*)&As[row * 64 + slot * 8];
      }
#pragma unroll
    for (int ni = 0; ni < 4; ++ni)
#pragma unroll
      for (int s = 0; s < 2; ++s) {
        int row = wc + ni * 16 + (lane & 15);
        int slot = (s * 4 + (lane >> 4)) ^ (row & 7);
        b[ni][s] = *(const short8v*)&Bs[row * 64 + slot * 8];
      }
#pragma unroll
    for (int s = 0; s < 2; ++s)
#pragma unroll
      for (int mi = 0; mi < 2; ++mi)
#pragma unroll
        for (int ni = 0; ni < 4; ++ni)
          acc[mi][ni] = __builtin_amdgcn_mfma_f32_16x16x32_bf16(a[mi][s], b[ni][s], acc[mi][ni], 0, 0, 0);
    __syncthreads();
  }

  const int r4 = (lane >> 4) * 4, cl = lane & 15;
  if (flags & FLAG_WEPI) {
    const int slice = xb * 2 + (wave & 1);        // 8 slices; cols xb*128 + wc + [0,64)
    const float* cw2t = cw2 + tt * 2048;
    const float* bt = bias + tt * 512;
#pragma unroll
    for (int mi = 0; mi < 2; ++mi) {
      float sc[4][4];
#pragma unroll
      for (int rg = 0; rg < 4; ++rg)
#pragma unroll
        for (int c = 0; c < 4; ++c) sc[rg][c] = 0.f;
#pragma unroll
      for (int ni = 0; ni < 4; ++ni) {
        int col = o0 + wc + ni * 16 + cl;
        float c0 = cw2t[col], c1 = cw2t[512 + col], c2 = cw2t[1024 + col], c3 = cw2t[1536 + col];
        float bb = bt[col];
#pragma unroll
        for (int rg = 0; rg < 4; ++rg) {
          float v = silu_f(acc[mi][ni][rg] + bb);
          sc[rg][0] += v * c0; sc[rg][1] += v * c1; sc[rg][2] += v * c2; sc[rg][3] += v * c3;
        }
      }
#pragma unroll
      for (int rg = 0; rg < 4; ++rg)
#pragma unroll
        for (int c = 0; c < 4; ++c) {
          float s = sc[rg][c];
          s += __shfl_xor(s, 1); s += __shfl_xor(s, 2);
          s += __shfl_xor(s, 4); s += __shfl_xor(s, 8);
          sc[rg][c] = s;
        }
      if (cl == 0) {
        int p = m0 + wr + mi * 16 + r4;
#pragma unroll
        for (int rg = 0; rg < 4; ++rg) {
          float4 o = make_float4(sc[rg][0], sc[rg][1], sc[rg][2], sc[rg][3]);
          *(float4*)&wpart[(((size_t)slice * wstride) + p + rg) * 4] = o;
        }
      }
    }
    return;
  }
  // bf16 vectorized epilogue (full 128x128 tile staged, stride 136)
  unsigned short* Ep = SM;
#pragma unroll
  for (int mi = 0; mi < 2; ++mi)
#pragma unroll
    for (int ni = 0; ni < 4; ++ni)
#pragma unroll
      for (int rg = 0; rg < 4; ++rg) {
        int row = wr + mi * 16 + r4 + rg;
        int col = wc + ni * 16 + cl;
        float v = acc[mi][ni][rg];
        v += bias[o0 + col];
        if (flags & FLAG_SILU) v = silu_f(v);
        Ep[row * 136 + col] = f2bf(v);
      }
  __syncthreads();
#pragma unroll
  for (int p = 0; p < 4; ++p) {
    int idx = p * 512 + tid;
    int row = idx >> 4, ch = idx & 15;
    short8v vv = *(const short8v*)&Ep[row * 136 + ch * 8];
    *(short8v*)(outB + (size_t)(m0 + row) * 512 + o0 + ch * 8) = vv;
  }
}

// ---------------- mega prep kernel ----------------
__global__ __launch_bounds__(256)
void prep_k(const float* h, const float* mW2, const float* nW1, const float* nW2,
            const float* relW, const float* cW1, const float* mW1, const float* eW1,
            const float* mb1, const float* eb1,
            unsigned short* hb, unsigned short* mW2b, unsigned short* nW1b,
            unsigned short* nW2b, unsigned short* relWb, unsigned short* cW1b,
            unsigned short* mW1pq, unsigned short* eGc, unsigned short* mW1t,
            float* wea, float* pqb, float* ggb)
{
  int i = blockIdx.x * 256 + threadIdx.x;
  if (i < 4194304) { hb[i] = f2bf(h[i]); return; }
  i -= 4194304;
  if (i < 262144) { mW2b[i] = f2bf(mW2[i]); return; }
  i -= 262144;
  if (i < 524288) { nW1b[i] = f2bf(nW1[i]); return; }
  i -= 524288;
  if (i < 262144) { nW2b[i] = f2bf(nW2[i]); return; }
  i -= 262144;
  if (i < 2097152) { relWb[i] = f2bf(relW[i]); return; }
  i -= 2097152;
  if (i < 2097152) { cW1b[i] = f2bf(cW1[i]); return; }
  i -= 2097152;
  if (i < 262144) { int r = i >> 9, k = i & 511; mW1pq[i] = f2bf(mW1[(size_t)r * 1041 + k]); return; }
  i -= 262144;
  if (i < 262144) { int r = i >> 9, k = i & 511; mW1pq[262144 + i] = f2bf(mW1[(size_t)r * 1041 + 512 + k]); return; }
  i -= 262144;
  if (i < 262144) { int r = i >> 9, k = i & 511; eGc[i] = f2bf(eW1[(size_t)r * 1025 + k]); return; }
  i -= 262144;
  if (i < 262144) { int r = i >> 9, k = i & 511; eGc[262144 + i] = f2bf(eW1[(size_t)r * 1025 + 513 + k]); return; }
  i -= 262144;
  if (i < 8704) { int j = i >> 9, c = i & 511; mW1t[i] = f2bf(mW1[(size_t)c * 1041 + 1024 + j]); return; }
  i -= 8704;
  if (i < 512) { wea[i] = eW1[(size_t)i * 1025 + 512]; return; }
  i -= 512;
  if (i < 1024) {
    pqb[i] = (i < 512) ? mb1[i] : 0.f;
    ggb[i] = (i < 512) ? eb1[i] : 0.f;
  }
}

__global__ __launch_bounds__(256)
void hist_k(const int* __restrict__ eidx, int* __restrict__ deg) {
  int id = blockIdx.x * 256 + threadIdx.x;
  int t = id >> 15, e = id & (EE - 1);
  atomicAdd(&deg[(t << 13) + eidx[(t << 16) + e]], 1);
}

__global__ __launch_bounds__(256)
void scan_k(const int* __restrict__ deg, int* __restrict__ off, int* __restrict__ cursor) {
  int t = blockIdx.x, tid = threadIdx.x;
  __shared__ int lds[256];
  int base = 0;
  for (int ch = 0; ch < 32; ++ch) {
    int i = ch * 256 + tid;
    int v = deg[(t << 13) + i];
    __syncthreads();
    lds[tid] = v;
    __syncthreads();
    for (int s = 1; s < 256; s <<= 1) {
      int x = (tid >= s) ? lds[tid - s] : 0;
      __syncthreads();
      if (tid >= s) lds[tid] += x;
      __syncthreads();
    }
    int excl = base + lds[tid] - v;
    off[(t << 13) + i] = excl;
    cursor[(t << 13) + i] = excl;
    base += lds[255];
  }
}

__global__ __launch_bounds__(256)
void scatcd_k(const int* __restrict__ eidx, const float* __restrict__ ea,
              const float* __restrict__ coord, int* __restrict__ cursor,
              int* __restrict__ order, int* __restrict__ rowS, int* __restrict__ colS,
              float* __restrict__ eaS, float* __restrict__ cd,
              float* __restrict__ radial, float* __restrict__ pnrm)
{
  int m = blockIdx.x * 256 + threadIdx.x;
  int t = m >> 15, e = m & (EE - 1);
  int r = eidx[(t << 16) + e], c = eidx[(t << 16) + EE + e];
  int pos = atomicAdd(&cursor[(t << 13) + r], 1);
  size_t s = ((size_t)t << 15) + pos;
  order[s] = e; rowS[s] = r; colS[s] = c; eaS[s] = ea[m];
  const float4* cv4 = (const float4*)coord;
  float4 A0 = cv4[r * 3], A1 = cv4[r * 3 + 1], A2 = cv4[r * 3 + 2];
  float4 B0 = cv4[c * 3], B1 = cv4[c * 3 + 1], B2 = cv4[c * 3 + 2];
  float d[12] = {A0.x-B0.x, A0.y-B0.y, A0.z-B0.z, A0.w-B0.w,
                 A1.x-B1.x, A1.y-B1.y, A1.z-B1.z, A1.w-B1.w,
                 A2.x-B2.x, A2.y-B2.y, A2.z-B2.z, A2.w-B2.w};
  float4* cdv = (float4*)cd;
  cdv[s*3+0] = make_float4(d[0],d[1],d[2],d[3]);
  cdv[s*3+1] = make_float4(d[4],d[5],d[6],d[7]);
  cdv[s*3+2] = make_float4(d[8],d[9],d[10],d[11]);
  float rad[16], sq[16];
#pragma unroll
  for (int ci = 0; ci < 4; ++ci)
#pragma unroll
    for (int di = 0; di < 4; ++di) {
      float v = d[ci*3]*d[di*3] + d[ci*3+1]*d[di*3+1] + d[ci*3+2]*d[di*3+2];
      rad[ci*4+di] = v; sq[ci*4+di] = v * v;
    }
  float4* rv = (float4*)radial;
#pragma unroll
  for (int i = 0; i < 4; ++i)
    rv[s*4+i] = make_float4(rad[i*4], rad[i*4+1], rad[i*4+2], rad[i*4+3]);
#pragma unroll
  for (int i = 0; i < 16; ++i) sq[i] = wave_sum(sq[i]);
  __shared__ float red[4][16];
  int wv = threadIdx.x >> 6, lane = threadIdx.x & 63;
  if (lane == 0) {
#pragma unroll
    for (int i = 0; i < 16; ++i) red[wv][i] = sq[i];
  }
  __syncthreads();
  if (threadIdx.x < 16)
    pnrm[blockIdx.x * 16 + threadIdx.x] =
        red[0][threadIdx.x] + red[1][threadIdx.x] + red[2][threadIdx.x] + red[3][threadIdx.x];
}

__global__ __launch_bounds__(128)
void nrmred_k(const float* __restrict__ pnrm, float* __restrict__ nrm) {
  int t = threadIdx.x >> 4, j = threadIdx.x & 15;
  float s = 0.f;
  for (int b = 0; b < 128; ++b) s += pnrm[((t * 128 + b) << 4) + j];
  nrm[(t << 4) + j] = s;
}

__global__ __launch_bounds__(256)
void tails_k(const float* __restrict__ radial, const float* __restrict__ nrm,
             const float* __restrict__ eaS, unsigned short* __restrict__ tailm)
{
  int m = blockIdx.x * 256 + threadIdx.x;
  int t = m >> 15;
  unsigned short tmp[24];
#pragma unroll
  for (int j = 0; j < 16; ++j) {
    float r = radial[(size_t)m * 16 + j] / fmaxf(sqrtf(nrm[(t << 4) + j]), 1e-12f);
    tmp[j] = f2bf(r);
  }
  tmp[16] = f2bf(eaS[m]);
#pragma unroll
  for (int j = 17; j < 24; ++j) tmp[j] = 0;
  uint4* dst = (uint4*)(tailm + (size_t)m * 24);
  dst[0] = ((const uint4*)tmp)[0];
  dst[1] = ((const uint4*)tmp)[1];
  dst[2] = ((const uint4*)tmp)[2];
}

// ---------------- fused msg1 (sorted, XCD-swizzled, 8 edges/block) ----------------
__global__ __launch_bounds__(256)
void msg1f_k(const unsigned short* __restrict__ PQ, const unsigned short* __restrict__ Wt,
             const unsigned short* __restrict__ tailm_g,
             const int* __restrict__ rowS_g, const int* __restrict__ colS_g,
             unsigned short* __restrict__ out)
{
  int tid = threadIdx.x;
  int e0 = xcd_swz(blockIdx.x, gridDim.x) * 8;
  uint wreg[17];
#pragma unroll
  for (int j = 0; j < 17; ++j) wreg[j] = *(const uint*)(Wt + j * 512 + tid * 2);
  for (int i = 0; i < 8; ++i) {
    int p = e0 + i;
    int r = rowS_g[p], c = colS_g[p];
    uint pv = *(const uint*)(PQ + ((size_t)r << 10) + tid * 2);
    uint qv = *(const uint*)(PQ + ((size_t)c << 10) + 512 + tid * 2);
    uint4 t0 = *(const uint4*)(tailm_g + (size_t)p * 24);
    uint4 t1 = *(const uint4*)(tailm_g + (size_t)p * 24 + 8);
    uint  t2 = *(const uint*)(tailm_g + (size_t)p * 24 + 16);
    float tl[17] = {bflo(t0.x), bfhi(t0.x), bflo(t0.y), bfhi(t0.y),
                    bflo(t0.z), bfhi(t0.z), bflo(t0.w), bfhi(t0.w),
                    bflo(t1.x), bfhi(t1.x), bflo(t1.y), bfhi(t1.y),
                    bflo(t1.z), bfhi(t1.z), bflo(t1.w), bfhi(t1.w),
                    bflo(t2)};
    float s0 = bflo(pv) + bflo(qv);
    float s1 = bfhi(pv) + bfhi(qv);
#pragma unroll
    for (int j = 0; j < 17; ++j) {
      s0 += tl[j] * bflo(wreg[j]); s1 += tl[j] * bfhi(wreg[j]);
    }
    *(uint*)(out + ((size_t)p << 9) + tid * 2) = packbf(silu_f(s0), silu_f(s1));
  }
}

__global__ __launch_bounds__(256)
void gsum_k(const unsigned short* __restrict__ msg, const int* __restrict__ offb,
            const int* __restrict__ deg, int tbase, unsigned short* __restrict__ segt)
{
  int l = xcd_swz(blockIdx.x, gridDim.x);
  int tloc = l >> 13, n = l & (NN - 1), tid = threadIdx.x;
  int t = tbase + tloc;
  int start = offb[(t << 13) + n], d = deg[(t << 13) + n];
  float s0 = 0.f, s1 = 0.f;
  const unsigned short* base = msg + (((size_t)tloc << 15) << 9);
  for (int j = 0; j < d; ++j) {
    uint v = *(const uint*)(base + ((size_t)(start + j) << 9) + tid * 2);
    s0 += bflo(v); s1 += bfhi(v);
  }
  *(uint*)(segt + (((size_t)tloc * NN + n) << 9) + tid * 2) = packbf(s0, s1);
}

__global__ __launch_bounds__(256)
void wsum_k(const float* __restrict__ wpart, float* __restrict__ wsum_out, int wstride) {
  int id = xcd_swz(blockIdx.x, gridDim.x) * 256 + threadIdx.x;
  float4 a = (float4){0.f, 0.f, 0.f, 0.f};
#pragma unroll
  for (int s = 0; s < 8; ++s) {
    float4 v = *(const float4*)&wpart[(((size_t)s * wstride) + id) * 4];
    a.x += v.x; a.y += v.y; a.z += v.z; a.w += v.w;
  }
  *(float4*)&wsum_out[(size_t)id * 4] = a;
}

__global__ __launch_bounds__(256)
void trxn_k(const float* __restrict__ coord, const float* __restrict__ cd,
            const float* __restrict__ wsum, const int* __restrict__ offb,
            const int* __restrict__ deg, float* __restrict__ xout)
{
  int id = blockIdx.x * 256 + threadIdx.x;
  int n = id / 12, j = id - n * 12, ci = j / 3;
  float s = 0.f; int cnt = 0;
#pragma unroll
  for (int t = 0; t < 8; ++t) {
    int o = offb[(t << 13) + n], d = deg[(t << 13) + n];
    size_t p = ((size_t)t << 15) + o;
    for (int k = 0; k < d; ++k)
      s += cd[(p + k) * 12 + j] * wsum[(p + k) * 4 + ci];
    cnt += d;
  }
  xout[id] = coord[id] + s / fmaxf((float)cnt, 1.f);
}

__global__ __launch_bounds__(256)
void mout_k(const unsigned short* __restrict__ GG,
            const float* __restrict__ eW2, const float* __restrict__ wea,
            const float* __restrict__ eb2, const float* __restrict__ eaS,
            const int* __restrict__ rowS, const int* __restrict__ colS,
            const int* __restrict__ order, float* __restrict__ out_m)
{
  int wid = xcd_swz(blockIdx.x, gridDim.x) * 4 + (threadIdx.x >> 6);
  int lane = threadIdx.x & 63;
  int t = wid >> 15;
  int r = rowS[wid], c = colS[wid];
  float eav = eaS[wid];
  short8v gv  = *(const short8v*)(GG + ((size_t)r << 10) + lane * 8);
  short8v gcv = *(const short8v*)(GG + ((size_t)c << 10) + 512 + lane * 8);
  const float4* w4 = (const float4*)(eW2 + lane * 8);
  const float4* a4 = (const float4*)(wea + lane * 8);
  float4 w0 = w4[0], w1 = w4[1], a0 = a4[0], a1 = a4[1];
  float wv8[8] = {w0.x,w0.y,w0.z,w0.w,w1.x,w1.y,w1.z,w1.w};
  float av8[8] = {a0.x,a0.y,a0.z,a0.w,a1.x,a1.y,a1.z,a1.w};
  float s = 0.f;
#pragma unroll
  for (int j = 0; j < 8; ++j)
    s += wv8[j] * silu_f(bf2f((unsigned short)gv[j]) + bf2f((unsigned short)gcv[j]) + eav * av8[j]);
  s = wave_sum(s);
  if (lane == 0) out_m[((size_t)t << 15) + order[wid]] = s + eb2[0];
}

// ---------------- launch ----------------
extern "C" void kernel_launch(void* const* d_in, const int* in_sizes, int n_in,
                              void* d_out, int out_size, void* d_ws, size_t ws_size,
                              hipStream_t stream)
{
  const float* h     = (const float*)d_in[0];
  const float* coord = (const float*)d_in[1];
  const float* ea    = (const float*)d_in[2];
  const int*   eidx  = (const int*)  d_in[3];
  const float* mW1   = (const float*)d_in[4];
  const float* mb1   = (const float*)d_in[5];
  const float* mW2   = (const float*)d_in[6];
  const float* mb2   = (const float*)d_in[7];
  const float* nW1   = (const float*)d_in[8];
  const float* nb1   = (const float*)d_in[9];
  const float* nW2   = (const float*)d_in[10];
  const float* nb2   = (const float*)d_in[11];
  const float* eW1   = (const float*)d_in[12];
  const float* eb1   = (const float*)d_in[13];
  const float* eW2   = (const float*)d_in[14];
  const float* eb2   = (const float*)d_in[15];
  const float* relW  = (const float*)d_in[16];
  const float* cW1   = (const float*)d_in[17];
  const float* cb1   = (const float*)d_in[18];
  const float* cW2   = (const float*)d_in[19];

  float* out   = (float*)d_out;
  float* out_h = out;
  float* out_x = out + (size_t)NN * DD;
  float* out_m = out_x + (size_t)NN * CC * 3;

  char* ws = (char*)d_ws;
  size_t off = 0;
  auto alloc = [&](size_t bytes) -> void* {
    void* p = ws + off; off += (bytes + 255) & ~(size_t)255; return p;
  };
  float* cd     = (float*)alloc((size_t)TE * 12 * 4);
  unsigned short* tailm = (unsigned short*)alloc((size_t)TE * 24 * 2);
  float* agg    = (float*)alloc((size_t)NN * 512 * 4);
  unsigned short* h_bf  = (unsigned short*)alloc((size_t)NN * 512 * 2);
  unsigned short* hn_bf = (unsigned short*)alloc((size_t)NN * 512 * 2);
  unsigned short* PQb   = (unsigned short*)alloc((size_t)NN * 1024 * 2);
  unsigned short* GGb   = PQb;
  unsigned short* mW1pq = (unsigned short*)alloc((size_t)1024 * 512 * 2);
  unsigned short* mW1t  = (unsigned short*)alloc((size_t)17 * 512 * 2);
  unsigned short* mW2b  = (unsigned short*)alloc((size_t)512 * 512 * 2);
  unsigned short* nW1b  = (unsigned short*)alloc((size_t)512 * 1024 * 2);
  unsigned short* nW2b  = (unsigned short*)alloc((size_t)512 * 512 * 2);
  unsigned short* eGc   = (unsigned short*)alloc((size_t)1024 * 512 * 2);
  float* weab   = (float*)alloc(512 * 4);
  float* pqbias = (float*)alloc(1024 * 4);
  float* ggbias = (float*)alloc(1024 * 4);
  unsigned short* relWb = (unsigned short*)alloc((size_t)TT * 512 * 512 * 2);
  unsigned short* cW1b  = (unsigned short*)alloc((size_t)TT * 512 * 512 * 2);
  int* deg     = (int*)alloc((size_t)TT * NN * 4);
  int* offb    = (int*)alloc((size_t)TT * NN * 4);
  int* cursor  = (int*)alloc((size_t)TT * NN * 4);
  int* order   = (int*)alloc((size_t)TE * 4);
  int* rowS    = (int*)alloc((size_t)TE * 4);
  int* colS    = (int*)alloc((size_t)TE * 4);
  float* eaS   = (float*)alloc((size_t)TE * 4);
  float* wsumb = (float*)alloc((size_t)TE * 4 * 4);
  float* pnrm  = (float*)alloc((size_t)(TE / 256) * 16 * 4);
  float* nrm   = (float*)alloc((size_t)TT * 16 * 4);

  const size_t perG = (size_t)EE * 512 * 2 * 2 + (size_t)NN * 512 * 2 + (size_t)8 * EE * 16;
  int G = 4;
  while (G > 1 && off + (size_t)G * perG + (1 << 20) > ws_size) G >>= 1;
  unsigned short* bufA = (unsigned short*)alloc((size_t)G * EE * 512 * 2);
  unsigned short* bufB = (unsigned short*)alloc((size_t)G * EE * 512 * 2);
  unsigned short* segt = (unsigned short*)alloc((size_t)G * NN * 512 * 2);
  float* wpart = (float*)alloc((size_t)8 * G * EE * 4 * 4);
  unsigned short* aggb = segt;
  float* radial = (float*)bufA;

  hipMemsetAsync(deg, 0, (size_t)TT * NN * 4, stream);
  hipMemsetAsync(agg, 0, (size_t)NN * 512 * 4, stream);

  prep_k<<<41000, 256, 0, stream>>>(h, mW2, nW1, nW2, relW, cW1, mW1, eW1, mb1, eb1,
      h_bf, mW2b, nW1b, nW2b, relWb, cW1b, mW1pq, eGc, mW1t, weab, pqbias, ggbias);

  hist_k<<<TE / 256, 256, 0, stream>>>(eidx, deg);
  scan_k<<<TT, 256, 0, stream>>>(deg, offb, cursor);
  scatcd_k<<<TE / 256, 256, 0, stream>>>(eidx, ea, coord, cursor,
      order, rowS, colS, eaS, cd, radial, pnrm);
  nrmred_k<<<1, 128, 0, stream>>>(pnrm, nrm);
  tails_k<<<TE / 256, 256, 0, stream>>>(radial, nrm, eaS, tailm);

  // PQ = h @ [mW1a;mW1q]^T + [mb1;0]
  mgemm_k<<<512, 256, 0, stream>>>(AgDirect{h_bf, 512}, BgDirect{mW1pq, 512}, 512, 0, 3,
      pqbias, nullptr, nullptr, PQb, 1024, 0);

  // -------- pass 1: batched groups of G relations --------
  for (int g = 0; g < TT / G; ++g) {
    const int tbase = g * G;
    const size_t gb = (size_t)tbase << 15;
    msg1f_k<<<(G * EE) / 8, 256, 0, stream>>>(PQb, mW1t, tailm + gb * 24,
        rowS + gb, colS + gb, bufA);
    mgemm2_k<<<4 * (G * EE / 128), 512, 0, stream>>>(AgDirect{bufA, 512},
        BgDirect{mW2b, 512}, 512, tbase,
        mb2, bufB, FLAG_SILU, nullptr, nullptr, 0);
    gsum_k<<<G * NN, 256, 0, stream>>>(bufB, offb, deg, tbase, segt);
    bool last = (g == TT / G - 1);
    mgemm_k<<<4 * (NN / 128), 256, 0, stream>>>(AgSegG{segt},
        BgRelG{relWb + ((size_t)tbase << 18)}, G * 512, 0, 2,
        nullptr, agg, agg, last ? aggb : nullptr, 512, FLAG_RES);
    mgemm2_k<<<4 * (G * EE / 128), 512, 0, stream>>>(AgDirect{bufB, 512},
        BgPerT{cW1b}, 512, tbase,
        cb1, nullptr, FLAG_SILU | FLAG_WEPI | FLAG_BIAS_T, cW2, wpart, G * EE);
    wsum_k<<<(G * EE) / 256, 256, 0, stream>>>(wpart, wsumb + gb * 4, G * EE);
  }

  trxn_k<<<(NN * 12) / 256, 256, 0, stream>>>(coord, cd, wsumb, offb, deg, out_x);

  // -------- node MLP + residual -> h_new --------
  mgemm_k<<<4 * (NN / 128), 256, 0, stream>>>(AgHcat{h_bf, aggb}, BgDirect{nW1b, 1024}, 1024, 0, 2,
      nb1, nullptr, nullptr, bufA, 512, FLAG_SILU);
  mgemm_k<<<4 * (NN / 128), 256, 0, stream>>>(AgDirect{bufA, 512}, BgDirect{nW2b, 512}, 512, 0, 2,
      nb2, h, out_h, hn_bf, 512, FLAG_RES);

  // -------- pass 2: GG = hn @ [eW1a;eW1c]^T + [eb1;0] ; fused m --------
  mgemm_k<<<512, 256, 0, stream>>>(AgDirect{hn_bf, 512}, BgDirect{eGc, 512}, 512, 0, 3,
      ggbias, nullptr, nullptr, GGb, 1024, 0);
  mout_k<<<TE / 4, 256, 0, stream>>>(GGb, eW2, weab, eb2, eaS, rowS, colS, order, out_m);

  (void)in_sizes; (void)n_in; (void)out_size; (void)ws_size;
}

// Round 15
// 1188.977 us; speedup vs baseline: 1.7742x; 1.0371x over previous
//
#include <hip/hip_runtime.h>
#include <cstdint>

#define NN 8192
#define DD 512
#define CC 4
#define TT 8
#define EE 32768
#define TE (TT*EE)

typedef __attribute__((ext_vector_type(8))) short short8v;
typedef __attribute__((ext_vector_type(4))) float f32x4;
typedef unsigned int uint;

constexpr int FLAG_SILU = 1, FLAG_RES = 2, FLAG_WEPI = 4, FLAG_BIAS_T = 8;

__device__ __forceinline__ float silu_f(float x) {
  return x * __builtin_amdgcn_rcpf(1.f + __expf(-x));
}

__device__ __forceinline__ unsigned short f2bf(float f) {
  uint u = __builtin_bit_cast(uint, f);
  u += 0x7fffu + ((u >> 16) & 1u);
  return (unsigned short)(u >> 16);
}
__device__ __forceinline__ float bf2f(unsigned short b) {
  uint u = ((uint)b) << 16;
  return __builtin_bit_cast(float, u);
}
__device__ __forceinline__ float bflo(uint u) { return __builtin_bit_cast(float, u << 16); }
__device__ __forceinline__ float bfhi(uint u) { return __builtin_bit_cast(float, u & 0xffff0000u); }
__device__ __forceinline__ uint packbf(float a, float b) {
  return (uint)f2bf(a) | ((uint)f2bf(b) << 16);
}

__device__ __forceinline__ float wave_sum(float v) {
#pragma unroll
  for (int off = 32; off; off >>= 1) v += __shfl_xor(v, off);
  return v;
}

__device__ __forceinline__ void gload16(const void* g, void* l) {
  __builtin_amdgcn_global_load_lds(
      (const __attribute__((address_space(1))) void*)g,
      (__attribute__((address_space(3))) void*)l, 16, 0, 0);
}

__device__ __forceinline__ int xcd_swz(int i, int nwg) {
  return (i & 7) * (nwg >> 3) + (i >> 3);
}

// ---------------- gather functors ----------------
struct AgDirect { const unsigned short* p; int K;
  __device__ const void* ptr(int m, int k, int) const { return p + (size_t)m * K + k; } };

struct AgHcat { const unsigned short* hb; const unsigned short* ab;
  __device__ const void* ptr(int m, int k, int) const {
    return (k < 512) ? (const void*)(hb + ((size_t)m << 9) + k)
                     : (const void*)(ab + ((size_t)m << 9) + (k - 512)); } };

struct AgSegG { const unsigned short* seg;
  __device__ const void* ptr(int m, int k, int) const {
    return seg + (((size_t)(k >> 9) * NN + m) << 9) + (k & 511); } };

struct BgDirect { const unsigned short* p; int K;
  __device__ const void* ptr(int o, int k, int) const { return p + (size_t)o * K + k; } };

struct BgRelG { const unsigned short* w;
  __device__ const void* ptr(int o, int k, int) const {
    return w + (((size_t)(k >> 9) * 512 + o) << 9) + (k & 511); } };

struct BgPerT { const unsigned short* w;
  __device__ const void* ptr(int o, int k, int tt) const {
    return w + (((size_t)tt << 18) + ((size_t)o << 9)) + k; } };

// ------- bf16 MFMA GEMM, 128x128 tile, 4 waves (node GEMMs) -------
template<class AG, class BG>
__global__ __launch_bounds__(256)
void mgemm_k(AG ag, BG bg, int K, int tbase, int lognx,
             const float* __restrict__ bias, const float* __restrict__ res,
             float* __restrict__ outF, unsigned short* __restrict__ outB, int ldo, int flags)
{
  __shared__ __align__(16) unsigned short SM[128 * 136];
  unsigned short* As = SM;
  unsigned short* Bs = SM + 128 * 64;
  const int swz = xcd_swz(blockIdx.x, gridDim.x);
  const int xb = swz & ((1 << lognx) - 1), yb = swz >> lognx;
  const int m0 = yb * 128, o0 = xb * 128;
  const int tt = tbase + (m0 >> 15);
  const int tid = threadIdx.x, wave = tid >> 6, lane = tid & 63;
  const int wr = (wave >> 1) * 64, wc = (wave & 1) * 64;
  const int rs = lane >> 3, sl = lane & 7;

  f32x4 acc[4][4];
#pragma unroll
  for (int i = 0; i < 4; ++i)
#pragma unroll
    for (int j = 0; j < 4; ++j) acc[i][j] = (f32x4)0.f;

  for (int k0 = 0; k0 < K; k0 += 64) {
#pragma unroll
    for (int i = 0; i < 4; ++i) {
      int r = i * 32 + wave * 8 + rs;
      int slot = sl ^ (r & 7);
      gload16(ag.ptr(m0 + r, k0 + slot * 8, tt), &As[(i * 32 + wave * 8) * 64]);
    }
#pragma unroll
    for (int i = 0; i < 4; ++i) {
      int r = i * 32 + wave * 8 + rs;
      int slot = sl ^ (r & 7);
      gload16(bg.ptr(o0 + r, k0 + slot * 8, tt), &Bs[(i * 32 + wave * 8) * 64]);
    }
    __syncthreads();
    short8v a[4][2], b[4][2];
#pragma unroll
    for (int mi = 0; mi < 4; ++mi)
#pragma unroll
      for (int s = 0; s < 2; ++s) {
        int row = wr + mi * 16 + (lane & 15);
        int slot = (s * 4 + (lane >> 4)) ^ (row & 7);
        a[mi][s] = *(const short8v*)&As[row * 64 + slot * 8];
      }
#pragma unroll
    for (int ni = 0; ni < 4; ++ni)
#pragma unroll
      for (int s = 0; s < 2; ++s) {
        int row = wc + ni * 16 + (lane & 15);
        int slot = (s * 4 + (lane >> 4)) ^ (row & 7);
        b[ni][s] = *(const short8v*)&Bs[row * 64 + slot * 8];
      }
#pragma unroll
    for (int s = 0; s < 2; ++s)
#pragma unroll
      for (int mi = 0; mi < 4; ++mi)
#pragma unroll
        for (int ni = 0; ni < 4; ++ni)
          acc[mi][ni] = __builtin_amdgcn_mfma_f32_16x16x32_bf16(a[mi][s], b[ni][s], acc[mi][ni], 0, 0, 0);
    __syncthreads();
  }

  const int r4 = (lane >> 4) * 4, cl = lane & 15;
  if (outB && !outF) {
    unsigned short* Ep = SM;
#pragma unroll
    for (int mi = 0; mi < 4; ++mi)
#pragma unroll
      for (int ni = 0; ni < 4; ++ni)
#pragma unroll
        for (int rg = 0; rg < 4; ++rg) {
          int row = wr + mi * 16 + r4 + rg;
          int col = wc + ni * 16 + cl;
          float v = acc[mi][ni][rg];
          if (bias) v += (flags & FLAG_BIAS_T) ? bias[tt * 512 + o0 + col] : bias[o0 + col];
          if (flags & FLAG_SILU) v = silu_f(v);
          Ep[row * 136 + col] = f2bf(v);
        }
    __syncthreads();
#pragma unroll
    for (int p = 0; p < 8; ++p) {
      int idx = p * 256 + tid;
      int row = idx >> 4, ch = idx & 15;
      short8v vv = *(const short8v*)&Ep[row * 136 + ch * 8];
      *(short8v*)(outB + (size_t)(m0 + row) * ldo + o0 + ch * 8) = vv;
    }
    return;
  }
#pragma unroll
  for (int mi = 0; mi < 4; ++mi)
#pragma unroll
    for (int ni = 0; ni < 4; ++ni)
#pragma unroll
      for (int rg = 0; rg < 4; ++rg) {
        int row = m0 + wr + mi * 16 + r4 + rg;
        int col = o0 + wc + ni * 16 + cl;
        float v = acc[mi][ni][rg];
        if (bias) v += (flags & FLAG_BIAS_T) ? bias[tt * 512 + col] : bias[col];
        if (flags & FLAG_SILU) v = silu_f(v);
        if (flags & FLAG_RES) v += res[(size_t)row * ldo + col];
        if (outF) outF[(size_t)row * ldo + col] = v;
        if (outB) outB[(size_t)row * ldo + col] = f2bf(v);
      }
}

// ------- bf16 MFMA GEMM, 128x128 tile, 8 waves (wave tile 32x64) — big edge GEMMs -------
template<class AG, class BG>
__global__ __launch_bounds__(512)
void mgemm2_k(AG ag, BG bg, int K, int tbase,
              const float* __restrict__ bias,
              unsigned short* __restrict__ outB, int flags,
              const float* __restrict__ cw2, float* __restrict__ wsum_out)
{
  __shared__ __align__(16) unsigned short SM[128 * 136];
  unsigned short* As = SM;
  unsigned short* Bs = SM + 128 * 64;
  const int swz = xcd_swz(blockIdx.x, gridDim.x);
  const int xb = swz & 3, yb = swz >> 2;
  const int m0 = yb * 128, o0 = xb * 128;
  const int tt = tbase + (m0 >> 15);
  const int tid = threadIdx.x, wave = tid >> 6, lane = tid & 63;
  const int wr = (wave >> 1) * 32, wc = (wave & 1) * 64;
  const int rs = lane >> 3, sl = lane & 7;

  f32x4 acc[2][4];
#pragma unroll
  for (int i = 0; i < 2; ++i)
#pragma unroll
    for (int j = 0; j < 4; ++j) acc[i][j] = (f32x4)0.f;

  for (int k0 = 0; k0 < K; k0 += 64) {
#pragma unroll
    for (int i = 0; i < 2; ++i) {
      int r = i * 64 + wave * 8 + rs;
      int slot = sl ^ (r & 7);
      gload16(ag.ptr(m0 + r, k0 + slot * 8, tt), &As[(i * 64 + wave * 8) * 64]);
    }
#pragma unroll
    for (int i = 0; i < 2; ++i) {
      int r = i * 64 + wave * 8 + rs;
      int slot = sl ^ (r & 7);
      gload16(bg.ptr(o0 + r, k0 + slot * 8, tt), &Bs[(i * 64 + wave * 8) * 64]);
    }
    __syncthreads();
    short8v a[2][2], b[4][2];
#pragma unroll
    for (int mi = 0; mi < 2; ++mi)
#pragma unroll
      for (int s = 0; s < 2; ++s) {
        int row = wr + mi * 16 + (lane & 15);
        int slot = (s * 4 + (lane >> 4)) ^ (row & 7);
        a[mi][s] = *(const short8v*)&As[row * 64 + slot * 8];
      }
#pragma unroll
    for (int ni = 0; ni < 4; ++ni)
#pragma unroll
      for (int s = 0; s < 2; ++s) {
        int row = wc + ni * 16 + (lane & 15);
        int slot = (s * 4 + (lane >> 4)) ^ (row & 7);
        b[ni][s] = *(const short8v*)&Bs[row * 64 + slot * 8];
      }
#pragma unroll
    for (int s = 0; s < 2; ++s)
#pragma unroll
      for (int mi = 0; mi < 2; ++mi)
#pragma unroll
        for (int ni = 0; ni < 4; ++ni)
          acc[mi][ni] = __builtin_amdgcn_mfma_f32_16x16x32_bf16(a[mi][s], b[ni][s], acc[mi][ni], 0, 0, 0);
    __syncthreads();
  }

  const int r4 = (lane >> 4) * 4, cl = lane & 15;
  if (flags & FLAG_WEPI) {
    // w-partials: reduce over this block's 64 cols, then 64 parallel atomics/wave
    const float* cw2t = cw2 + tt * 2048;
    const float* bt = bias + tt * 512;
#pragma unroll
    for (int mi = 0; mi < 2; ++mi) {
      float sc[4][4];
#pragma unroll
      for (int rg = 0; rg < 4; ++rg)
#pragma unroll
        for (int c = 0; c < 4; ++c) sc[rg][c] = 0.f;
#pragma unroll
      for (int ni = 0; ni < 4; ++ni) {
        int col = o0 + wc + ni * 16 + cl;
        float c0 = cw2t[col], c1 = cw2t[512 + col], c2 = cw2t[1024 + col], c3 = cw2t[1536 + col];
        float bb = bt[col];
#pragma unroll
        for (int rg = 0; rg < 4; ++rg) {
          float v = silu_f(acc[mi][ni][rg] + bb);
          sc[rg][0] += v * c0; sc[rg][1] += v * c1; sc[rg][2] += v * c2; sc[rg][3] += v * c3;
        }
      }
#pragma unroll
      for (int rg = 0; rg < 4; ++rg)
#pragma unroll
        for (int c = 0; c < 4; ++c) {
          float s = sc[rg][c];
          s += __shfl_xor(s, 1); s += __shfl_xor(s, 2);
          s += __shfl_xor(s, 4); s += __shfl_xor(s, 8);
          sc[rg][c] = s;          // all 16 lanes of the quarter now hold the total
        }
      // lane cl owns (rg = cl>>2, c = cl&3) for its quarter's row group
      size_t gp = ((size_t)tbase << 15) + m0 + wr + mi * 16 + r4 + (cl >> 2);
      atomicAdd(&wsum_out[gp * 4 + (cl & 3)], sc[cl >> 2][cl & 3]);
    }
    return;
  }
  unsigned short* Ep = SM;
#pragma unroll
  for (int mi = 0; mi < 2; ++mi)
#pragma unroll
    for (int ni = 0; ni < 4; ++ni)
#pragma unroll
      for (int rg = 0; rg < 4; ++rg) {
        int row = wr + mi * 16 + r4 + rg;
        int col = wc + ni * 16 + cl;
        float v = acc[mi][ni][rg];
        v += bias[o0 + col];
        if (flags & FLAG_SILU) v = silu_f(v);
        Ep[row * 136 + col] = f2bf(v);
      }
  __syncthreads();
#pragma unroll
  for (int p = 0; p < 4; ++p) {
    int idx = p * 512 + tid;
    int row = idx >> 4, ch = idx & 15;
    short8v vv = *(const short8v*)&Ep[row * 136 + ch * 8];
    *(short8v*)(outB + (size_t)(m0 + row) * 512 + o0 + ch * 8) = vv;
  }
}

// ---------------- mega prep kernel ----------------
__global__ __launch_bounds__(256)
void prep_k(const float* h, const float* mW2, const float* nW1, const float* nW2,
            const float* relW, const float* cW1, const float* mW1, const float* eW1,
            const float* mb1, const float* eb1,
            unsigned short* hb, unsigned short* mW2b, unsigned short* nW1b,
            unsigned short* nW2b, unsigned short* relWb, unsigned short* cW1b,
            unsigned short* mW1pq, unsigned short* eGc, unsigned short* mW1t,
            float* wea, float* pqb, float* ggb)
{
  int i = blockIdx.x * 256 + threadIdx.x;
  if (i < 4194304) { hb[i] = f2bf(h[i]); return; }
  i -= 4194304;
  if (i < 262144) { mW2b[i] = f2bf(mW2[i]); return; }
  i -= 262144;
  if (i < 524288) { nW1b[i] = f2bf(nW1[i]); return; }
  i -= 524288;
  if (i < 262144) { nW2b[i] = f2bf(nW2[i]); return; }
  i -= 262144;
  if (i < 2097152) { relWb[i] = f2bf(relW[i]); return; }
  i -= 2097152;
  if (i < 2097152) { cW1b[i] = f2bf(cW1[i]); return; }
  i -= 2097152;
  if (i < 262144) { int r = i >> 9, k = i & 511; mW1pq[i] = f2bf(mW1[(size_t)r * 1041 + k]); return; }
  i -= 262144;
  if (i < 262144) { int r = i >> 9, k = i & 511; mW1pq[262144 + i] = f2bf(mW1[(size_t)r * 1041 + 512 + k]); return; }
  i -= 262144;
  if (i < 262144) { int r = i >> 9, k = i & 511; eGc[i] = f2bf(eW1[(size_t)r * 1025 + k]); return; }
  i -= 262144;
  if (i < 262144) { int r = i >> 9, k = i & 511; eGc[262144 + i] = f2bf(eW1[(size_t)r * 1025 + 513 + k]); return; }
  i -= 262144;
  if (i < 8704) { int j = i >> 9, c = i & 511; mW1t[i] = f2bf(mW1[(size_t)c * 1041 + 1024 + j]); return; }
  i -= 8704;
  if (i < 512) { wea[i] = eW1[(size_t)i * 1025 + 512]; return; }
  i -= 512;
  if (i < 1024) {
    pqb[i] = (i < 512) ? mb1[i] : 0.f;
    ggb[i] = (i < 512) ? eb1[i] : 0.f;
  }
}

__global__ __launch_bounds__(256)
void hist_k(const int* __restrict__ eidx, int* __restrict__ deg) {
  int id = blockIdx.x * 256 + threadIdx.x;
  int t = id >> 15, e = id & (EE - 1);
  atomicAdd(&deg[(t << 13) + eidx[(t << 16) + e]], 1);
}

// parallel scan: thread-local 32-elem prefix + 256-wide block scan (one block per t)
__global__ __launch_bounds__(256)
void scan_k(const int* __restrict__ deg, int* __restrict__ off, int* __restrict__ cursor) {
  int t = blockIdx.x, tid = threadIdx.x;
  int base = (t << 13) + tid * 32;
  int loc[32]; int s = 0;
#pragma unroll
  for (int i = 0; i < 32; ++i) { loc[i] = deg[base + i]; s += loc[i]; }
  __shared__ int lds[256];
  lds[tid] = s;
  __syncthreads();
  for (int st = 1; st < 256; st <<= 1) {
    int x = (tid >= st) ? lds[tid - st] : 0;
    __syncthreads();
    lds[tid] += x;
    __syncthreads();
  }
  int run = lds[tid] - s;
#pragma unroll
  for (int i = 0; i < 32; ++i) {
    off[base + i] = run; cursor[base + i] = run; run += loc[i];
  }
}

__global__ __launch_bounds__(256)
void scatcd_k(const int* __restrict__ eidx, const float* __restrict__ ea,
              const float* __restrict__ coord, int* __restrict__ cursor,
              int* __restrict__ order, int* __restrict__ rowS, int* __restrict__ colS,
              float* __restrict__ eaS, float* __restrict__ cd,
              float* __restrict__ radial, float* __restrict__ pnrm)
{
  int m = blockIdx.x * 256 + threadIdx.x;
  int t = m >> 15, e = m & (EE - 1);
  int r = eidx[(t << 16) + e], c = eidx[(t << 16) + EE + e];
  int pos = atomicAdd(&cursor[(t << 13) + r], 1);
  size_t s = ((size_t)t << 15) + pos;
  order[s] = e; rowS[s] = r; colS[s] = c; eaS[s] = ea[m];
  const float4* cv4 = (const float4*)coord;
  float4 A0 = cv4[r * 3], A1 = cv4[r * 3 + 1], A2 = cv4[r * 3 + 2];
  float4 B0 = cv4[c * 3], B1 = cv4[c * 3 + 1], B2 = cv4[c * 3 + 2];
  float d[12] = {A0.x-B0.x, A0.y-B0.y, A0.z-B0.z, A0.w-B0.w,
                 A1.x-B1.x, A1.y-B1.y, A1.z-B1.z, A1.w-B1.w,
                 A2.x-B2.x, A2.y-B2.y, A2.z-B2.z, A2.w-B2.w};
  float4* cdv = (float4*)cd;
  cdv[s*3+0] = make_float4(d[0],d[1],d[2],d[3]);
  cdv[s*3+1] = make_float4(d[4],d[5],d[6],d[7]);
  cdv[s*3+2] = make_float4(d[8],d[9],d[10],d[11]);
  float rad[16], sq[16];
#pragma unroll
  for (int ci = 0; ci < 4; ++ci)
#pragma unroll
    for (int di = 0; di < 4; ++di) {
      float v = d[ci*3]*d[di*3] + d[ci*3+1]*d[di*3+1] + d[ci*3+2]*d[di*3+2];
      rad[ci*4+di] = v; sq[ci*4+di] = v * v;
    }
  float4* rv = (float4*)radial;
#pragma unroll
  for (int i = 0; i < 4; ++i)
    rv[s*4+i] = make_float4(rad[i*4], rad[i*4+1], rad[i*4+2], rad[i*4+3]);
#pragma unroll
  for (int i = 0; i < 16; ++i) sq[i] = wave_sum(sq[i]);
  __shared__ float red[4][16];
  int wv = threadIdx.x >> 6, lane = threadIdx.x & 63;
  if (lane == 0) {
#pragma unroll
    for (int i = 0; i < 16; ++i) red[wv][i] = sq[i];
  }
  __syncthreads();
  if (threadIdx.x < 16)
    pnrm[blockIdx.x * 16 + threadIdx.x] =
        red[0][threadIdx.x] + red[1][threadIdx.x] + red[2][threadIdx.x] + red[3][threadIdx.x];
}

__global__ __launch_bounds__(128)
void nrmred_k(const float* __restrict__ pnrm, float* __restrict__ nrm) {
  int t = threadIdx.x >> 4, j = threadIdx.x & 15;
  float s = 0.f;
  for (int b = 0; b < 128; ++b) s += pnrm[((t * 128 + b) << 4) + j];
  nrm[(t << 4) + j] = s;
}

__global__ __launch_bounds__(256)
void tails_k(const float* __restrict__ radial, const float* __restrict__ nrm,
             const float* __restrict__ eaS, unsigned short* __restrict__ tailm)
{
  int m = blockIdx.x * 256 + threadIdx.x;
  int t = m >> 15;
  unsigned short tmp[24];
#pragma unroll
  for (int j = 0; j < 16; ++j) {
    float r = radial[(size_t)m * 16 + j] / fmaxf(sqrtf(nrm[(t << 4) + j]), 1e-12f);
    tmp[j] = f2bf(r);
  }
  tmp[16] = f2bf(eaS[m]);
#pragma unroll
  for (int j = 17; j < 24; ++j) tmp[j] = 0;
  uint4* dst = (uint4*)(tailm + (size_t)m * 24);
  dst[0] = ((const uint4*)tmp)[0];
  dst[1] = ((const uint4*)tmp)[1];
  dst[2] = ((const uint4*)tmp)[2];
}

// ---------------- fused msg1 (sorted, XCD-swizzled, 8 edges/block) ----------------
__global__ __launch_bounds__(256)
void msg1f_k(const unsigned short* __restrict__ PQ, const unsigned short* __restrict__ Wt,
             const unsigned short* __restrict__ tailm_g,
             const int* __restrict__ rowS_g, const int* __restrict__ colS_g,
             unsigned short* __restrict__ out)
{
  int tid = threadIdx.x;
  int e0 = xcd_swz(blockIdx.x, gridDim.x) * 8;
  uint wreg[17];
#pragma unroll
  for (int j = 0; j < 17; ++j) wreg[j] = *(const uint*)(Wt + j * 512 + tid * 2);
  for (int i = 0; i < 8; ++i) {
    int p = e0 + i;
    int r = rowS_g[p], c = colS_g[p];
    uint pv = *(const uint*)(PQ + ((size_t)r << 10) + tid * 2);
    uint qv = *(const uint*)(PQ + ((size_t)c << 10) + 512 + tid * 2);
    uint4 t0 = *(const uint4*)(tailm_g + (size_t)p * 24);
    uint4 t1 = *(const uint4*)(tailm_g + (size_t)p * 24 + 8);
    uint  t2 = *(const uint*)(tailm_g + (size_t)p * 24 + 16);
    float tl[17] = {bflo(t0.x), bfhi(t0.x), bflo(t0.y), bfhi(t0.y),
                    bflo(t0.z), bfhi(t0.z), bflo(t0.w), bfhi(t0.w),
                    bflo(t1.x), bfhi(t1.x), bflo(t1.y), bfhi(t1.y),
                    bflo(t1.z), bfhi(t1.z), bflo(t1.w), bfhi(t1.w),
                    bflo(t2)};
    float s0 = bflo(pv) + bflo(qv);
    float s1 = bfhi(pv) + bfhi(qv);
#pragma unroll
    for (int j = 0; j < 17; ++j) {
      s0 += tl[j] * bflo(wreg[j]); s1 += tl[j] * bfhi(wreg[j]);
    }
    *(uint*)(out + ((size_t)p << 9) + tid * 2) = packbf(silu_f(s0), silu_f(s1));
  }
}

__global__ __launch_bounds__(256)
void gsum_k(const unsigned short* __restrict__ msg, const int* __restrict__ offb,
            const int* __restrict__ deg, int tbase, unsigned short* __restrict__ segt)
{
  int l = xcd_swz(blockIdx.x, gridDim.x);
  int tloc = l >> 13, n = l & (NN - 1), tid = threadIdx.x;
  int t = tbase + tloc;
  int start = offb[(t << 13) + n], d = deg[(t << 13) + n];
  float s0 = 0.f, s1 = 0.f;
  const unsigned short* base = msg + (((size_t)tloc << 15) << 9);
  for (int j = 0; j < d; ++j) {
    uint v = *(const uint*)(base + ((size_t)(start + j) << 9) + tid * 2);
    s0 += bflo(v); s1 += bfhi(v);
  }
  *(uint*)(segt + (((size_t)tloc * NN + n) << 9) + tid * 2) = packbf(s0, s1);
}

__global__ __launch_bounds__(256)
void trxn_k(const float* __restrict__ coord, const float* __restrict__ cd,
            const float* __restrict__ wsum, const int* __restrict__ offb,
            const int* __restrict__ deg, float* __restrict__ xout)
{
  int id = blockIdx.x * 256 + threadIdx.x;
  int n = id / 12, j = id - n * 12, ci = j / 3;
  float s = 0.f; int cnt = 0;
#pragma unroll
  for (int t = 0; t < 8; ++t) {
    int o = offb[(t << 13) + n], d = deg[(t << 13) + n];
    size_t p = ((size_t)t << 15) + o;
    for (int k = 0; k < d; ++k)
      s += cd[(p + k) * 12 + j] * wsum[(p + k) * 4 + ci];
    cnt += d;
  }
  xout[id] = coord[id] + s / fmaxf((float)cnt, 1.f);
}

// ------ m output: 2 edges per wave (loads issued up-front for MLP) ------
__global__ __launch_bounds__(256)
void mout_k(const unsigned short* __restrict__ GG,
            const float* __restrict__ eW2, const float* __restrict__ wea,
            const float* __restrict__ eb2, const float* __restrict__ eaS,
            const int* __restrict__ rowS, const int* __restrict__ colS,
            const int* __restrict__ order, float* __restrict__ out_m)
{
  int wbase = xcd_swz(blockIdx.x, gridDim.x) * 8 + (threadIdx.x >> 6) * 2;
  int lane = threadIdx.x & 63;
  int w0i = wbase, w1i = wbase + 1;
  int r0 = rowS[w0i], c0 = colS[w0i], r1 = rowS[w1i], c1 = colS[w1i];
  float ea0 = eaS[w0i], ea1 = eaS[w1i];
  short8v gv0  = *(const short8v*)(GG + ((size_t)r0 << 10) + lane * 8);
  short8v gcv0 = *(const short8v*)(GG + ((size_t)c0 << 10) + 512 + lane * 8);
  short8v gv1  = *(const short8v*)(GG + ((size_t)r1 << 10) + lane * 8);
  short8v gcv1 = *(const short8v*)(GG + ((size_t)c1 << 10) + 512 + lane * 8);
  const float4* w4 = (const float4*)(eW2 + lane * 8);
  const float4* a4 = (const float4*)(wea + lane * 8);
  float4 w0 = w4[0], w1 = w4[1], a0 = a4[0], a1 = a4[1];
  float wv8[8] = {w0.x,w0.y,w0.z,w0.w,w1.x,w1.y,w1.z,w1.w};
  float av8[8] = {a0.x,a0.y,a0.z,a0.w,a1.x,a1.y,a1.z,a1.w};
  float s0 = 0.f, s1 = 0.f;
#pragma unroll
  for (int j = 0; j < 8; ++j) {
    s0 += wv8[j] * silu_f(bf2f((unsigned short)gv0[j]) + bf2f((unsigned short)gcv0[j]) + ea0 * av8[j]);
    s1 += wv8[j] * silu_f(bf2f((unsigned short)gv1[j]) + bf2f((unsigned short)gcv1[j]) + ea1 * av8[j]);
  }
  s0 = wave_sum(s0);
  s1 = wave_sum(s1);
  if (lane == 0) {
    float eb = eb2[0];
    int t0 = w0i >> 15, t1 = w1i >> 15;
    out_m[((size_t)t0 << 15) + order[w0i]] = s0 + eb;
    out_m[((size_t)t1 << 15) + order[w1i]] = s1 + eb;
  }
}

// ---------------- launch ----------------
extern "C" void kernel_launch(void* const* d_in, const int* in_sizes, int n_in,
                              void* d_out, int out_size, void* d_ws, size_t ws_size,
                              hipStream_t stream)
{
  const float* h     = (const float*)d_in[0];
  const float* coord = (const float*)d_in[1];
  const float* ea    = (const float*)d_in[2];
  const int*   eidx  = (const int*)  d_in[3];
  const float* mW1   = (const float*)d_in[4];
  const float* mb1   = (const float*)d_in[5];
  const float* mW2   = (const float*)d_in[6];
  const float* mb2   = (const float*)d_in[7];
  const float* nW1   = (const float*)d_in[8];
  const float* nb1   = (const float*)d_in[9];
  const float* nW2   = (const float*)d_in[10];
  const float* nb2   = (const float*)d_in[11];
  const float* eW1   = (const float*)d_in[12];
  const float* eb1   = (const float*)d_in[13];
  const float* eW2   = (const float*)d_in[14];
  const float* eb2   = (const float*)d_in[15];
  const float* relW  = (const float*)d_in[16];
  const float* cW1   = (const float*)d_in[17];
  const float* cb1   = (const float*)d_in[18];
  const float* cW2   = (const float*)d_in[19];

  float* out   = (float*)d_out;
  float* out_h = out;
  float* out_x = out + (size_t)NN * DD;
  float* out_m = out_x + (size_t)NN * CC * 3;

  char* ws = (char*)d_ws;
  size_t off = 0;
  auto alloc = [&](size_t bytes) -> void* {
    void* p = ws + off; off += (bytes + 255) & ~(size_t)255; return p;
  };
  float* cd     = (float*)alloc((size_t)TE * 12 * 4);
  unsigned short* tailm = (unsigned short*)alloc((size_t)TE * 24 * 2);
  float* agg    = (float*)alloc((size_t)NN * 512 * 4);
  unsigned short* h_bf  = (unsigned short*)alloc((size_t)NN * 512 * 2);
  unsigned short* hn_bf = (unsigned short*)alloc((size_t)NN * 512 * 2);
  unsigned short* PQb   = (unsigned short*)alloc((size_t)NN * 1024 * 2);
  unsigned short* GGb   = PQb;
  unsigned short* mW1pq = (unsigned short*)alloc((size_t)1024 * 512 * 2);
  unsigned short* mW1t  = (unsigned short*)alloc((size_t)17 * 512 * 2);
  unsigned short* mW2b  = (unsigned short*)alloc((size_t)512 * 512 * 2);
  unsigned short* nW1b  = (unsigned short*)alloc((size_t)512 * 1024 * 2);
  unsigned short* nW2b  = (unsigned short*)alloc((size_t)512 * 512 * 2);
  unsigned short* eGc   = (unsigned short*)alloc((size_t)1024 * 512 * 2);
  float* weab   = (float*)alloc(512 * 4);
  float* pqbias = (float*)alloc(1024 * 4);
  float* ggbias = (float*)alloc(1024 * 4);
  unsigned short* relWb = (unsigned short*)alloc((size_t)TT * 512 * 512 * 2);
  unsigned short* cW1b  = (unsigned short*)alloc((size_t)TT * 512 * 512 * 2);
  int* deg     = (int*)alloc((size_t)TT * NN * 4);
  int* offb    = (int*)alloc((size_t)TT * NN * 4);
  int* cursor  = (int*)alloc((size_t)TT * NN * 4);
  int* order   = (int*)alloc((size_t)TE * 4);
  int* rowS    = (int*)alloc((size_t)TE * 4);
  int* colS    = (int*)alloc((size_t)TE * 4);
  float* eaS   = (float*)alloc((size_t)TE * 4);
  float* wsumb = (float*)alloc((size_t)TE * 4 * 4);
  float* pnrm  = (float*)alloc((size_t)(TE / 256) * 16 * 4);
  float* nrm   = (float*)alloc((size_t)TT * 16 * 4);

  const size_t perG = (size_t)EE * 512 * 2 * 2 + (size_t)NN * 512 * 2;
  int G = 4;
  while (G > 1 && off + (size_t)G * perG + (1 << 20) > ws_size) G >>= 1;
  unsigned short* bufA = (unsigned short*)alloc((size_t)G * EE * 512 * 2);
  unsigned short* bufB = (unsigned short*)alloc((size_t)G * EE * 512 * 2);
  unsigned short* segt = (unsigned short*)alloc((size_t)G * NN * 512 * 2);
  unsigned short* aggb = segt;
  float* radial = (float*)bufA;

  hipMemsetAsync(deg, 0, (size_t)TT * NN * 4, stream);
  hipMemsetAsync(agg, 0, (size_t)NN * 512 * 4, stream);
  hipMemsetAsync(wsumb, 0, (size_t)TE * 4 * 4, stream);

  prep_k<<<41000, 256, 0, stream>>>(h, mW2, nW1, nW2, relW, cW1, mW1, eW1, mb1, eb1,
      h_bf, mW2b, nW1b, nW2b, relWb, cW1b, mW1pq, eGc, mW1t, weab, pqbias, ggbias);

  hist_k<<<TE / 256, 256, 0, stream>>>(eidx, deg);
  scan_k<<<TT, 256, 0, stream>>>(deg, offb, cursor);
  scatcd_k<<<TE / 256, 256, 0, stream>>>(eidx, ea, coord, cursor,
      order, rowS, colS, eaS, cd, radial, pnrm);
  nrmred_k<<<1, 128, 0, stream>>>(pnrm, nrm);
  tails_k<<<TE / 256, 256, 0, stream>>>(radial, nrm, eaS, tailm);

  // PQ = h @ [mW1a;mW1q]^T + [mb1;0]
  mgemm_k<<<512, 256, 0, stream>>>(AgDirect{h_bf, 512}, BgDirect{mW1pq, 512}, 512, 0, 3,
      pqbias, nullptr, nullptr, PQb, 1024, 0);

  // -------- pass 1: batched groups of G relations --------
  for (int g = 0; g < TT / G; ++g) {
    const int tbase = g * G;
    const size_t gb = (size_t)tbase << 15;
    msg1f_k<<<(G * EE) / 8, 256, 0, stream>>>(PQb, mW1t, tailm + gb * 24,
        rowS + gb, colS + gb, bufA);
    mgemm2_k<<<4 * (G * EE / 128), 512, 0, stream>>>(AgDirect{bufA, 512},
        BgDirect{mW2b, 512}, 512, tbase,
        mb2, bufB, FLAG_SILU, nullptr, nullptr);
    gsum_k<<<G * NN, 256, 0, stream>>>(bufB, offb, deg, tbase, segt);
    bool last = (g == TT / G - 1);
    mgemm_k<<<4 * (NN / 128), 256, 0, stream>>>(AgSegG{segt},
        BgRelG{relWb + ((size_t)tbase << 18)}, G * 512, 0, 2,
        nullptr, agg, agg, last ? aggb : nullptr, 512, FLAG_RES);
    mgemm2_k<<<4 * (G * EE / 128), 512, 0, stream>>>(AgDirect{bufB, 512},
        BgPerT{cW1b}, 512, tbase,
        cb1, nullptr, FLAG_SILU | FLAG_WEPI | FLAG_BIAS_T, cW2, wsumb);
  }

  trxn_k<<<(NN * 12) / 256, 256, 0, stream>>>(coord, cd, wsumb, offb, deg, out_x);

  // -------- node MLP + residual -> h_new --------
  mgemm_k<<<4 * (NN / 128), 256, 0, stream>>>(AgHcat{h_bf, aggb}, BgDirect{nW1b, 1024}, 1024, 0, 2,
      nb1, nullptr, nullptr, bufA, 512, FLAG_SILU);
  mgemm_k<<<4 * (NN / 128), 256, 0, stream>>>(AgDirect{bufA, 512}, BgDirect{nW2b, 512}, 512, 0, 2,
      nb2, h, out_h, hn_bf, 512, FLAG_RES);

  // -------- pass 2: GG = hn @ [eW1a;eW1c]^T + [eb1;0] ; fused m --------
  mgemm_k<<<512, 256, 0, stream>>>(AgDirect{hn_bf, 512}, BgDirect{eGc, 512}, 512, 0, 3,
      ggbias, nullptr, nullptr, GGb, 1024, 0);
  mout_k<<<TE / 8, 256, 0, stream>>>(GGb, eW2, weab, eb2, eaS, rowS, colS, order, out_m);

  (void)in_sizes; (void)n_in; (void)out_size; (void)ws_size;
}